// Round 4
// baseline (2843.876 us; speedup 1.0000x reference)
//
#include <hip/hip_runtime.h>

#define NATOMS 400000
#define NEDGES 800000
#define NMOLS  13000
#define AF 133
#define BFdim 14
#define BFD 147

typedef __attribute__((ext_vector_type(8))) short  s16x8;
typedef __attribute__((ext_vector_type(8))) __bf16 b16x8;
typedef __attribute__((ext_vector_type(4))) float  f32x4;

__device__ __forceinline__ float bf2f(unsigned short u){
  union { unsigned int i; float f; } v; v.i = ((unsigned int)u) << 16; return v.f;
}
__device__ __forceinline__ unsigned short f2bf(float f){
  union { float ff; unsigned int i; } v; v.ff = f;
  unsigned int b = v.i + 0x7fffu + ((v.i >> 16) & 1u);
  return (unsigned short)(b >> 16);
}
__device__ __forceinline__ f32x4 mfma16(s16x8 a, s16x8 b, f32x4 c){
  return __builtin_amdgcn_mfma_f32_16x16x32_bf16(
      __builtin_bit_cast(b16x8, a), __builtin_bit_cast(b16x8, b), c, 0, 0, 0);
}
__device__ __forceinline__ void gload_lds16(const void* g, void* lds){
  __builtin_amdgcn_global_load_lds(
      (const __attribute__((address_space(1))) void*)g,
      (__attribute__((address_space(3))) void*)lds, 16, 0, 0);
}

// ---------------- fp32 [rows][Kin] -> bf16 [rows][192] ----------------
__global__ void k_cvt(const float* __restrict__ src, ushort* __restrict__ dst,
                      int total, int Kin){
  int gid = blockIdx.x * 256 + threadIdx.x;
  if (gid >= total) return;
  int row = gid / 48;
  int c0 = (gid - row * 48) * 4;
  const float* sp = src + (size_t)row * Kin + c0;
  ushort4 o;
  o.x = (c0     < Kin) ? f2bf(sp[0]) : 0;
  o.y = (c0 + 1 < Kin) ? f2bf(sp[1]) : 0;
  o.z = (c0 + 2 < Kin) ? f2bf(sp[2]) : 0;
  o.w = (c0 + 3 < Kin) ? f2bf(sp[3]) : 0;
  *(ushort4*)(dst + (size_t)row * 192 + c0) = o;
}

// permuted bond cvt: dst row i = f_bonds[p[i]]
__global__ void k_cvtp(const float* __restrict__ src, const int* __restrict__ p,
                       ushort* __restrict__ dst){
  int gid = blockIdx.x * 256 + threadIdx.x;
  if (gid >= NEDGES * 48) return;
  int row = gid / 48;
  int c0 = (gid - row * 48) * 4;
  const float* sp = src + (size_t)p[row] * BFD + c0;
  ushort4 o;
  o.x = (c0     < BFD) ? f2bf(sp[0]) : 0;
  o.y = (c0 + 1 < BFD) ? f2bf(sp[1]) : 0;
  o.z = (c0 + 2 < BFD) ? f2bf(sp[2]) : 0;
  o.w = (c0 + 3 < BFD) ? f2bf(sp[3]) : 0;
  *(ushort4*)(dst + (size_t)row * 192 + c0) = o;
}

// ---------------- weight prep: fp32 -> bf16 fragment order ----------------
__global__ void k_prep_weights(const float* __restrict__ W_i, const float* __restrict__ W_h,
                               const float* __restrict__ W_o, const float* __restrict__ node_W,
                               const float* __restrict__ edge_W,
                               ushort* __restrict__ Wif, ushort* __restrict__ Wof1,
                               ushort* __restrict__ Whf, ushort* __restrict__ Wof2,
                               ushort* __restrict__ nWf, ushort* __restrict__ eWf){
  int gid = blockIdx.x * 256 + threadIdx.x;
  ushort* dst; const float* src; int KB, Kv, Ns, idx;
  if      (gid <  40960){ idx = gid;          dst = Wif;  src = W_i;          KB = 5; Kv = 147; Ns = 256; }
  else if (gid <  81920){ idx = gid -  40960; dst = Wof1; src = W_o;          KB = 5; Kv = 133; Ns = 256; }
  else if (gid < 147456){ idx = gid -  81920; dst = Whf;  src = W_h;          KB = 8; Kv = 256; Ns = 256; }
  else if (gid < 212992){ idx = gid - 147456; dst = Wof2; src = W_o + 133*256;KB = 8; Kv = 256; Ns = 256; }
  else if (gid < 249856){ idx = gid - 212992; dst = nWf;  src = node_W;       KB = 8; Kv = 256; Ns = 133; }
  else if (gid < 253952){ idx = gid - 249856; dst = eWf;  src = edge_W;       KB = 8; Kv = 256; Ns = 14;  }
  else return;
  int j = idx & 7, lane = (idx >> 3) & 63, fi = idx >> 9;
  int kb = fi % KB, nb = fi / KB;
  int k = kb * 32 + ((lane >> 4) << 3) + j;
  int n = nb * 16 + (lane & 15);
  float v = 0.f;
  if (k < Kv && n < Ns) v = src[(size_t)k * Ns + n];
  dst[idx] = f2bf(v);
}

// ---------------- CSR build over dst ----------------
__global__ void k_hist(const int* __restrict__ dsti, int* __restrict__ deg){
  int e = blockIdx.x * 256 + threadIdx.x;
  if (e < NEDGES) atomicAdd(&deg[dsti[e]], 1);
}
__global__ void k_blocksum(const int* __restrict__ deg, int* __restrict__ bsum){
  __shared__ int s[256];
  int i = blockIdx.x * 256 + threadIdx.x;
  s[threadIdx.x] = (i < NATOMS) ? deg[i] : 0;
  __syncthreads();
  for (int st = 128; st > 0; st >>= 1){
    if (threadIdx.x < st) s[threadIdx.x] += s[threadIdx.x + st];
    __syncthreads();
  }
  if (threadIdx.x == 0) bsum[blockIdx.x] = s[0];
}
#define NBLK 1563
__global__ void k_scanblk(const int* __restrict__ bs, int* __restrict__ bo){
  __shared__ int s[2048];
  int t = threadIdx.x;
  s[2*t]   = (2*t   < NBLK) ? bs[2*t]   : 0;
  s[2*t+1] = (2*t+1 < NBLK) ? bs[2*t+1] : 0;
  int offset = 1;
  for (int d = 1024; d > 0; d >>= 1){
    __syncthreads();
    if (t < d){ int ai = offset*(2*t+1)-1, bi = offset*(2*t+2)-1; s[bi] += s[ai]; }
    offset <<= 1;
  }
  __syncthreads();
  if (t == 0) s[2047] = 0;
  for (int d = 1; d < 2048; d <<= 1){
    offset >>= 1;
    __syncthreads();
    if (t < d){ int ai = offset*(2*t+1)-1, bi = offset*(2*t+2)-1;
                int tmp = s[ai]; s[ai] = s[bi]; s[bi] += tmp; }
  }
  __syncthreads();
  if (2*t   < NBLK) bo[2*t]   = s[2*t];
  if (2*t+1 < NBLK) bo[2*t+1] = s[2*t+1];
}
__global__ void k_offs(const int* __restrict__ deg, const int* __restrict__ bo,
                       int* __restrict__ offs, int* __restrict__ cursor){
  __shared__ int s1[256], s2[256];
  int t = threadIdx.x;
  int i = blockIdx.x * 256 + t;
  int v = (i < NATOMS) ? deg[i] : 0;
  s1[t] = v;
  __syncthreads();
  int* rd = s1; int* wr = s2;
  for (int ofs = 1; ofs < 256; ofs <<= 1){
    wr[t] = rd[t] + ((t >= ofs) ? rd[t - ofs] : 0);
    __syncthreads();
    int* tmp = rd; rd = wr; wr = tmp;
  }
  if (i < NATOMS){
    int excl = rd[t] - v + bo[blockIdx.x];
    offs[i] = excl; cursor[i] = excl;
  }
  if (i == 0) offs[NATOMS] = NEDGES;
}
__global__ void k_fill(const int* __restrict__ dsti, int* __restrict__ cursor,
                       int* __restrict__ elist){
  int e = blockIdx.x * 256 + threadIdx.x;
  if (e < NEDGES){ int pos = atomicAdd(&cursor[dsti[e]], 1); elist[pos] = e; }
}
__global__ void k_pos(const int* __restrict__ elist, int* __restrict__ pos){
  int i = blockIdx.x * 256 + threadIdx.x;
  if (i < NEDGES) pos[elist[i]] = i;
}
__global__ void k_maps(const int* __restrict__ elist, const int* __restrict__ pos,
                       const int* __restrict__ srcarr,
                       int* __restrict__ srcp, int* __restrict__ revp){
  int i = blockIdx.x * 256 + threadIdx.x;
  if (i < NEDGES){
    int e = elist[i];
    srcp[i] = srcarr[e];
    revp[i] = pos[e ^ 1];
  }
}
__global__ void k_molstart(const int* __restrict__ atom_mol, int* __restrict__ molst){
  int m = blockIdx.x * 256 + threadIdx.x;
  if (m > NMOLS) return;
  int lo = 0, hi = NATOMS;
  while (lo < hi){ int mid = (lo + hi) >> 1; if (atom_mol[mid] < m) lo = mid + 1; else hi = mid; }
  molst[m] = lo;
}

// ---------------- K=160 GEMM on padded bf16 rows (pitch 192) ----------------
__global__ __launch_bounds__(256) void k_gemm160(
    const ushort* __restrict__ A16, const ushort* __restrict__ Bf,
    ushort* __restrict__ out){
  __shared__ ushort At[64 * 192];
  const int t = threadIdx.x, w = t >> 6, l = t & 63;
  const long r0 = (long)blockIdx.x * 64;
  const char* Ab = (const char*)(A16 + r0 * 192);
  #pragma unroll
  for (int i = 0; i < 6; i++){
    int dbase = (i * 4 + w) * 1024;
    int d = dbase + l * 16;
    int row = d / 384;
    int sw = (row & 7) << 4;
    gload_lds16(Ab + (d ^ sw), (char*)At + dbase);
  }
  __syncthreads();
  const int lr = l & 15, lg = l >> 4;
  f32x4 acc[4][4] = {};
  for (int kb = 0; kb < 5; kb++){
    s16x8 a[4], b[4];
    #pragma unroll
    for (int m = 0; m < 4; m++){
      int row = m * 16 + lr;
      int cb = (kb * 64 + (lg << 4)) ^ ((row & 7) << 4);
      a[m] = *(const s16x8*)((const char*)At + row * 384 + cb);
    }
    #pragma unroll
    for (int n = 0; n < 4; n++){
      int fi = (w * 4 + n) * 5 + kb;
      b[n] = *(const s16x8*)(Bf + (size_t)(fi * 64 + l) * 8);
    }
    #pragma unroll
    for (int m = 0; m < 4; m++)
      #pragma unroll
      for (int n = 0; n < 4; n++)
        acc[m][n] = mfma16(a[m], b[n], acc[m][n]);
  }
  #pragma unroll
  for (int m = 0; m < 4; m++){
    #pragma unroll
    for (int n = 0; n < 4; n++){
      long base = (r0 + m * 16 + lg * 4) * 256 + (w * 64 + n * 16 + lr);
      #pragma unroll
      for (int r = 0; r < 4; r++)
        out[base + (long)r * 256] = f2bf(acc[m][n][r]);
    }
  }
}

// ---------------- Y0 = relu(inp) @ Whf (reg-staged relu) ----------------
__global__ __launch_bounds__(256) void k_Yrelu(
    const ushort* __restrict__ A, const ushort* __restrict__ Whf,
    ushort* __restrict__ Yout){
  __shared__ ushort At[64 * 256];
  const int t = threadIdx.x, w = t >> 6, l = t & 63;
  const long e0 = (long)blockIdx.x * 64;
  const char* Ab = (const char*)(A + e0 * 256);
  #pragma unroll
  for (int i = 0; i < 8; i++){
    int d = (i * 4 + w) * 1024 + l * 16;
    s16x8 v = *(const s16x8*)(Ab + d);
    #pragma unroll
    for (int j = 0; j < 8; j++){
      ushort u = (ushort)v[j];
      v[j] = (short)((u & 0x8000u) ? 0 : u);
    }
    int sw = ((d >> 9) & 7) << 4;
    *(s16x8*)((char*)At + (d ^ sw)) = v;
  }
  __syncthreads();
  const int lr = l & 15, lg = l >> 4;
  f32x4 acc[4][4] = {};
  for (int kb = 0; kb < 8; kb++){
    s16x8 a[4], b[4];
    #pragma unroll
    for (int m = 0; m < 4; m++){
      int row = m * 16 + lr;
      int cb = (kb * 64 + (lg << 4)) ^ ((row & 7) << 4);
      a[m] = *(const s16x8*)((const char*)At + row * 512 + cb);
    }
    #pragma unroll
    for (int n = 0; n < 4; n++){
      int fi = (w * 4 + n) * 8 + kb;
      b[n] = *(const s16x8*)(Whf + (size_t)(fi * 64 + l) * 8);
    }
    #pragma unroll
    for (int m = 0; m < 4; m++)
      #pragma unroll
      for (int n = 0; n < 4; n++)
        acc[m][n] = mfma16(a[m], b[n], acc[m][n]);
  }
  #pragma unroll
  for (int m = 0; m < 4; m++){
    #pragma unroll
    for (int n = 0; n < 4; n++){
      long base = (e0 + m * 16 + lg * 4) * 256 + (w * 64 + n * 16 + lr);
      #pragma unroll
      for (int r = 0; r < 4; r++)
        Yout[base + (long)r * 256] = f2bf(acc[m][n][r]);
    }
  }
}

// ---------------- streaming segment sum over contiguous runs ----------------
__global__ __launch_bounds__(256) void k_Sseq(
    const ushort* __restrict__ Y, const int* __restrict__ offs,
    ushort* __restrict__ S){
  const int t = threadIdx.x, w = t >> 6, l = t & 63;
  const int a = blockIdx.x * 4 + w;
  const int beg = offs[a], end = offs[a + 1];
  float a0 = 0, a1 = 0, a2 = 0, a3 = 0;
  for (int i = beg; i < end; i++){
    const ushort4 v = *(const ushort4*)(Y + (size_t)i * 256 + l * 4);
    a0 += bf2f(v.x); a1 += bf2f(v.y); a2 += bf2f(v.z); a3 += bf2f(v.w);
  }
  ushort4 o; o.x = f2bf(a0); o.y = f2bf(a1); o.z = f2bf(a2); o.w = f2bf(a3);
  *(ushort4*)(S + (size_t)a * 256 + l * 4) = o;
}

// ---------------- fused combine + GEMM: Yout = relu(inp + S[srcp] - Yprev[revp]) @ Whf ----------------
__global__ __launch_bounds__(256) void k_Yfused(
    const ushort* __restrict__ inp, const ushort* __restrict__ S,
    const ushort* __restrict__ Yprev, const int* __restrict__ srcp,
    const int* __restrict__ revp, const ushort* __restrict__ Whf,
    ushort* __restrict__ Yout){
  __shared__ ushort At[64 * 256];
  const int t = threadIdx.x, w = t >> 6, l = t & 63;
  const long e0 = (long)blockIdx.x * 64;
  {
    const int r = t >> 2, q = t & 3;
    const long i = e0 + r;
    const int sp = srcp[i], rv = revp[i];
    const ushort* pi = inp   + i * 256 + q * 64;
    const ushort* ps = S     + (size_t)sp * 256 + q * 64;
    const ushort* py = Yprev + (size_t)rv * 256 + q * 64;
    #pragma unroll
    for (int k = 0; k < 8; k++){
      s16x8 va = *(const s16x8*)(pi + k * 8);
      s16x8 vs = *(const s16x8*)(ps + k * 8);
      s16x8 vy = *(const s16x8*)(py + k * 8);
      s16x8 res;
      #pragma unroll
      for (int j = 0; j < 8; j++){
        float v = bf2f((ushort)va[j]) + bf2f((ushort)vs[j]) - bf2f((ushort)vy[j]);
        res[j] = (short)f2bf(v > 0.f ? v : 0.f);
      }
      int byte = r * 512 + ((q * 128 + k * 16) ^ ((r & 7) << 4));
      *(s16x8*)((char*)At + byte) = res;
    }
  }
  __syncthreads();
  const int lr = l & 15, lg = l >> 4;
  f32x4 acc[4][4] = {};
  for (int kb = 0; kb < 8; kb++){
    s16x8 a[4], b[4];
    #pragma unroll
    for (int m = 0; m < 4; m++){
      int row = m * 16 + lr;
      int cb = (kb * 64 + (lg << 4)) ^ ((row & 7) << 4);
      a[m] = *(const s16x8*)((const char*)At + row * 512 + cb);
    }
    #pragma unroll
    for (int n = 0; n < 4; n++){
      int fi = (w * 4 + n) * 8 + kb;
      b[n] = *(const s16x8*)(Whf + (size_t)(fi * 64 + l) * 8);
    }
    #pragma unroll
    for (int m = 0; m < 4; m++)
      #pragma unroll
      for (int n = 0; n < 4; n++)
        acc[m][n] = mfma16(a[m], b[n], acc[m][n]);
  }
  #pragma unroll
  for (int m = 0; m < 4; m++){
    #pragma unroll
    for (int n = 0; n < 4; n++){
      long base = (e0 + m * 16 + lg * 4) * 256 + (w * 64 + n * 16 + lr);
      #pragma unroll
      for (int r = 0; r < 4; r++)
        Yout[base + (long)r * 256] = f2bf(acc[m][n][r]);
    }
  }
}

// ---------------- tail: amsg[a] = sum_i relu(inp[i] + S[srcp[i]] - Yprev[revp[i]]) ----------------
__global__ __launch_bounds__(256) void k_tail(
    const ushort* __restrict__ inp, const ushort* __restrict__ S,
    const ushort* __restrict__ Yprev, const int* __restrict__ srcp,
    const int* __restrict__ revp, const int* __restrict__ offs,
    ushort* __restrict__ amsg){
  const int t = threadIdx.x, w = t >> 6, l = t & 63;
  const int a = blockIdx.x * 4 + w;
  const int beg = offs[a], end = offs[a + 1];
  float a0 = 0, a1 = 0, a2 = 0, a3 = 0;
  for (int i = beg; i < end; i++){
    const int sp = srcp[i], rv = revp[i];
    const ushort4 vi = *(const ushort4*)(inp   + (size_t)i * 256 + l * 4);
    const ushort4 vs = *(const ushort4*)(S     + (size_t)sp * 256 + l * 4);
    const ushort4 vy = *(const ushort4*)(Yprev + (size_t)rv * 256 + l * 4);
    float r0 = bf2f(vi.x) + bf2f(vs.x) - bf2f(vy.x); a0 += (r0 > 0.f ? r0 : 0.f);
    float r1 = bf2f(vi.y) + bf2f(vs.y) - bf2f(vy.y); a1 += (r1 > 0.f ? r1 : 0.f);
    float r2 = bf2f(vi.z) + bf2f(vs.z) - bf2f(vy.z); a2 += (r2 > 0.f ? r2 : 0.f);
    float r3 = bf2f(vi.w) + bf2f(vs.w) - bf2f(vy.w); a3 += (r3 > 0.f ? r3 : 0.f);
  }
  ushort4 o; o.x = f2bf(a0); o.y = f2bf(a1); o.z = f2bf(a2); o.w = f2bf(a3);
  *(ushort4*)(amsg + (size_t)a * 256 + l * 4) = o;
}

// ---------------- W_o part B: ah = relu(amsg @ Wo2 + partial + b_o) ----------------
__global__ __launch_bounds__(256) void k_woB(
    const ushort* __restrict__ amsg, const ushort* __restrict__ Wof2,
    const ushort* __restrict__ partial, const float* __restrict__ b_o,
    ushort* __restrict__ ah){
  const int t = threadIdx.x, w = t >> 6, l = t & 63, lr = l & 15, lg = l >> 4;
  const long r0 = (long)blockIdx.x * 64;
  f32x4 acc[4][4] = {};
  for (int kb = 0; kb < 8; kb++){
    s16x8 a[4], b[4];
    #pragma unroll
    for (int m = 0; m < 4; m++)
      a[m] = *(const s16x8*)(amsg + (r0 + m * 16 + lr) * 256 + kb * 32 + lg * 8);
    #pragma unroll
    for (int n = 0; n < 4; n++)
      b[n] = *(const s16x8*)(Wof2 + (size_t)(((w * 4 + n) * 8 + kb) * 64 + l) * 8);
    #pragma unroll
    for (int m = 0; m < 4; m++)
      #pragma unroll
      for (int n = 0; n < 4; n++)
        acc[m][n] = mfma16(a[m], b[n], acc[m][n]);
  }
  #pragma unroll
  for (int m = 0; m < 4; m++){
    #pragma unroll
    for (int n = 0; n < 4; n++){
      int col = w * 64 + n * 16 + lr;
      float bo = b_o[col];
      long base = (r0 + m * 16 + lg * 4) * 256 + col;
      #pragma unroll
      for (int r = 0; r < 4; r++){
        long ad = base + (long)r * 256;
        float v = acc[m][n][r] + bf2f(partial[ad]) + bo;
        ah[ad] = f2bf(v > 0.f ? v : 0.f);
      }
    }
  }
}

// ---------------- node head ----------------
__global__ __launch_bounds__(192) void k_node(
    const ushort* __restrict__ ah, const ushort* __restrict__ nWf,
    const float* __restrict__ node_b, float* __restrict__ out_node){
  const int t = threadIdx.x, w = t >> 6, l = t & 63, lr = l & 15, lg = l >> 4;
  const long r0 = (long)blockIdx.x * 64;
  f32x4 acc[4][3] = {};
  for (int kb = 0; kb < 8; kb++){
    s16x8 a[4], b[3];
    #pragma unroll
    for (int m = 0; m < 4; m++)
      a[m] = *(const s16x8*)(ah + (r0 + m * 16 + lr) * 256 + kb * 32 + lg * 8);
    #pragma unroll
    for (int n = 0; n < 3; n++)
      b[n] = *(const s16x8*)(nWf + (size_t)(((w * 3 + n) * 8 + kb) * 64 + l) * 8);
    #pragma unroll
    for (int m = 0; m < 4; m++)
      #pragma unroll
      for (int n = 0; n < 3; n++)
        acc[m][n] = mfma16(a[m], b[n], acc[m][n]);
  }
  #pragma unroll
  for (int m = 0; m < 4; m++){
    #pragma unroll
    for (int n = 0; n < 3; n++){
      int col = (w * 3 + n) * 16 + lr;
      if (col < AF){
        float nb = node_b[col];
        #pragma unroll
        for (int r = 0; r < 4; r++)
          out_node[(r0 + m * 16 + lg * 4 + r) * AF + col] = acc[m][n][r] + nb;
      }
    }
  }
}

// ---------------- edge projection ----------------
__global__ __launch_bounds__(64) void k_proj(
    const ushort* __restrict__ ah, const ushort* __restrict__ eWf,
    float* __restrict__ proj){
  const int l = threadIdx.x, lr = l & 15, lg = l >> 4;
  const long r0 = (long)blockIdx.x * 64;
  f32x4 acc[4] = {};
  for (int kb = 0; kb < 8; kb++){
    s16x8 b = *(const s16x8*)(eWf + (size_t)(kb * 64 + l) * 8);
    #pragma unroll
    for (int m = 0; m < 4; m++){
      s16x8 a = *(const s16x8*)(ah + (r0 + m * 16 + lr) * 256 + kb * 32 + lg * 8);
      acc[m] = mfma16(a, b, acc[m]);
    }
  }
  #pragma unroll
  for (int m = 0; m < 4; m++)
    #pragma unroll
    for (int r = 0; r < 4; r++)
      proj[(r0 + m * 16 + lg * 4 + r) * 16 + lr] = acc[m][r];
}

__global__ void k_edge_out(const int* __restrict__ edge_index, const float* __restrict__ proj,
                           const float* __restrict__ edge_b, float* __restrict__ out_edge){
  int gid = blockIdx.x * 256 + threadIdx.x;
  int i = gid >> 4, c = gid & 15;
  if (c < BFdim){
    int s = edge_index[2 * i];
    int d = edge_index[NEDGES + 2 * i];
    out_edge[(size_t)i * BFdim + c] =
        0.5f * (proj[(size_t)s * 16 + c] + proj[(size_t)d * 16 + c]) + edge_b[c];
  }
}

// ---------------- molecule pooling ----------------
__global__ __launch_bounds__(256) void k_pool(const ushort* __restrict__ ah,
                                              const int* __restrict__ molst,
                                              float* __restrict__ gemb){
  const int t = threadIdx.x, w = t >> 6, l = t & 63;
  const int m = blockIdx.x * 4 + w;
  const int beg = molst[m], end = molst[m + 1];
  float a0 = 0, a1 = 0, a2 = 0, a3 = 0;
  for (int i = beg; i < end; i++){
    const ushort4 v = *(const ushort4*)(ah + (size_t)i * 256 + l * 4);
    a0 += bf2f(v.x); a1 += bf2f(v.y); a2 += bf2f(v.z); a3 += bf2f(v.w);
  }
  f32x4 o = {a0, a1, a2, a3};
  *(f32x4*)(gemb + (size_t)m * 256 + l * 4) = o;
}

// ---------------- graph head (fp32) ----------------
__global__ __launch_bounds__(256) void k_g1(const float* __restrict__ gemb,
                                            const float* __restrict__ gW1,
                                            const float* __restrict__ gb1,
                                            float* __restrict__ ghid){
  __shared__ float s[16 * 256];
  const int t = threadIdx.x;
  const int r0 = blockIdx.x * 16;
  for (int i = 0; i < 16; i++){
    int r = r0 + i;
    s[i * 256 + t] = (r < NMOLS) ? gemb[(size_t)r * 256 + t] : 0.f;
  }
  __syncthreads();
  float acc[16] = {};
  for (int k = 0; k < 256; k++){
    float wv = gW1[(size_t)k * 256 + t];
    #pragma unroll
    for (int i = 0; i < 16; i++) acc[i] += s[i * 256 + k] * wv;
  }
  float b = gb1[t];
  for (int i = 0; i < 16; i++){
    int r = r0 + i;
    if (r < NMOLS){ float v = acc[i] + b; ghid[(size_t)r * 256 + t] = v > 0.f ? v : 0.f; }
  }
}
__global__ void k_g2(const float* __restrict__ ghid, const float* __restrict__ gW2,
                     const float* __restrict__ gb2, float* __restrict__ outg){
  const int t = threadIdx.x, w = t >> 6, l = t & 63;
  const int m = blockIdx.x * 4 + w;
  f32x4 v = *(const f32x4*)(ghid + (size_t)m * 256 + l * 4);
  const f32x4 wv = *(const f32x4*)(gW2 + l * 4);
  float acc = v[0] * wv[0] + v[1] * wv[1] + v[2] * wv[2] + v[3] * wv[3];
  for (int ofs = 32; ofs; ofs >>= 1) acc += __shfl_down(acc, ofs, 64);
  if (l == 0) outg[m] = acc + gb2[0];
}

extern "C" void kernel_launch(void* const* d_in, const int* in_sizes, int n_in,
                              void* d_out, int out_size, void* d_ws, size_t ws_size,
                              hipStream_t stream){
  const float* f_atoms = (const float*)d_in[0];
  const float* f_bonds = (const float*)d_in[1];
  const float* W_i     = (const float*)d_in[2];
  const float* W_h     = (const float*)d_in[3];
  const float* W_o     = (const float*)d_in[4];
  const float* b_o     = (const float*)d_in[5];
  const float* node_W  = (const float*)d_in[6];
  const float* node_b  = (const float*)d_in[7];
  const float* edge_W  = (const float*)d_in[8];
  const float* edge_b  = (const float*)d_in[9];
  const float* g_W1    = (const float*)d_in[10];
  const float* g_b1    = (const float*)d_in[11];
  const float* g_W2    = (const float*)d_in[12];
  const float* g_b2    = (const float*)d_in[13];
  const int* edge_index = (const int*)d_in[14];
  const int* atom_mol   = (const int*)d_in[16];

  float* out_node  = (float*)d_out;
  float* out_edge  = out_node + (size_t)NATOMS * AF;
  float* out_graph = out_edge + (size_t)(NEDGES / 2) * BFdim;

  char* p = (char*)d_ws;
  auto alloc = [&](size_t b) -> char* { char* r = p; p += (b + 255) & ~(size_t)255; return r; };
  ushort* B1 = (ushort*)alloc((size_t)NEDGES * 256 * 2);  // inp_p -> fa16 -> (free)
  ushort* B2 = (ushort*)alloc((size_t)NEDGES * 256 * 2);  // fb16_p -> Y1 -> partial
  ushort* B3 = (ushort*)alloc((size_t)NEDGES * 256 * 2);  // Y0 -> (free)
  ushort* N1 = (ushort*)alloc((size_t)NATOMS * 256 * 2);  // S0 -> S1 -> ah
  ushort* N2 = (ushort*)alloc((size_t)NATOMS * 256 * 2);  // amsg
  float*  proj  = (float*)alloc((size_t)NATOMS * 16 * 4);
  float*  gemb  = (float*)alloc((size_t)NMOLS * 256 * 4);
  float*  ghid  = (float*)alloc((size_t)NMOLS * 256 * 4);
  ushort* Wif   = (ushort*)alloc(160 * 256 * 2);
  ushort* Wof1  = (ushort*)alloc(160 * 256 * 2);
  ushort* Whf   = (ushort*)alloc(256 * 256 * 2);
  ushort* Wof2  = (ushort*)alloc(256 * 256 * 2);
  ushort* nWf   = (ushort*)alloc(256 * 144 * 2);
  ushort* eWf   = (ushort*)alloc(256 * 16 * 2);
  int* deg    = (int*)alloc(NATOMS * 4);
  int* offs   = (int*)alloc((NATOMS + 1) * 4);
  int* cursor = (int*)alloc(NATOMS * 4);
  int* elist  = (int*)alloc(NEDGES * 4);
  int* pos    = (int*)alloc(NEDGES * 4);
  int* srcp   = (int*)alloc(NEDGES * 4);
  int* revp   = (int*)alloc(NEDGES * 4);
  int* bsum   = (int*)alloc(1568 * 4);
  int* boff   = (int*)alloc(1568 * 4);
  int* molst  = (int*)alloc((NMOLS + 1) * 4);
  if ((size_t)(p - (char*)d_ws) > ws_size) return;

  const int* dsti = edge_index + NEDGES;

  hipMemsetAsync(deg, 0, NATOMS * 4, stream);
  k_prep_weights<<<992, 256, 0, stream>>>(W_i, W_h, W_o, node_W, edge_W,
                                          Wif, Wof1, Whf, Wof2, nWf, eWf);
  // CSR + permutation maps
  k_hist<<<3125, 256, 0, stream>>>(dsti, deg);
  k_blocksum<<<NBLK, 256, 0, stream>>>(deg, bsum);
  k_scanblk<<<1, 1024, 0, stream>>>(bsum, boff);
  k_offs<<<NBLK, 256, 0, stream>>>(deg, boff, offs, cursor);
  k_fill<<<3125, 256, 0, stream>>>(dsti, cursor, elist);
  k_pos<<<3125, 256, 0, stream>>>(elist, pos);
  k_maps<<<3125, 256, 0, stream>>>(elist, pos, edge_index, srcp, revp);
  k_molstart<<<51, 256, 0, stream>>>(atom_mol, molst);

  // fb16_p (CSR-permuted bf16 bond features) -> B2
  k_cvtp<<<150000, 256, 0, stream>>>(f_bonds, elist, B2);
  // inp_p = fb16_p @ W_i -> B1
  k_gemm160<<<12500, 256, 0, stream>>>(B2, Wif, B1);
  // Y0 = relu(inp_p) @ W_h -> B3
  k_Yrelu<<<12500, 256, 0, stream>>>(B1, Whf, B3);
  // S0 = segsum(Y0) -> N1   (streaming: runs are contiguous)
  k_Sseq<<<100000, 256, 0, stream>>>(B3, offs, N1);
  // Y1 = relu(inp + S0[srcp] - Y0[revp]) @ W_h -> B2
  k_Yfused<<<12500, 256, 0, stream>>>(B1, N1, B3, srcp, revp, Whf, B2);
  // S1 = segsum(Y1) -> N1
  k_Sseq<<<100000, 256, 0, stream>>>(B2, offs, N1);
  // amsg = segsum(relu(inp + S1[srcp] - Y1[revp])) -> N2 (msg2 never materialized)
  k_tail<<<100000, 256, 0, stream>>>(B1, N1, B2, srcp, revp, offs, N2);
  // fa16 -> B1 (inp dead)
  k_cvt<<<75000, 256, 0, stream>>>(f_atoms, B1, NATOMS * 48, AF);
  // partial = f_atoms @ Wo1 -> B2 (Y1 dead)
  k_gemm160<<<6250, 256, 0, stream>>>(B1, Wof1, B2);
  // ah = relu(amsg @ Wo2 + partial + b_o) -> N1 (S1 dead)
  k_woB<<<6250, 256, 0, stream>>>(N2, Wof2, B2, b_o, N1);
  // heads
  k_pool<<<3250, 256, 0, stream>>>(N1, molst, gemb);
  k_node<<<6250, 192, 0, stream>>>(N1, nWf, node_b, out_node);
  k_proj<<<6250, 64, 0, stream>>>(N1, eWf, proj);
  k_edge_out<<<25000, 256, 0, stream>>>(edge_index, proj, edge_b, out_edge);
  k_g1<<<813, 256, 0, stream>>>(gemb, g_W1, g_b1, ghid);
  k_g2<<<3250, 256, 0, stream>>>(ghid, g_W2, g_b2, out_graph);
}

// Round 5
// 2752.607 us; speedup vs baseline: 1.0332x; 1.0332x over previous
//
#include <hip/hip_runtime.h>

#define NATOMS 400000
#define NEDGES 800000
#define NMOLS  13000
#define AF 133
#define BFdim 14
#define BFD 147

typedef __attribute__((ext_vector_type(8))) short  s16x8;
typedef __attribute__((ext_vector_type(8))) __bf16 b16x8;
typedef __attribute__((ext_vector_type(4))) float  f32x4;

__device__ __forceinline__ float bf2f(unsigned short u){
  union { unsigned int i; float f; } v; v.i = ((unsigned int)u) << 16; return v.f;
}
__device__ __forceinline__ unsigned short f2bf(float f){
  union { float ff; unsigned int i; } v; v.ff = f;
  unsigned int b = v.i + 0x7fffu + ((v.i >> 16) & 1u);
  return (unsigned short)(b >> 16);
}
__device__ __forceinline__ f32x4 mfma16(s16x8 a, s16x8 b, f32x4 c){
  return __builtin_amdgcn_mfma_f32_16x16x32_bf16(
      __builtin_bit_cast(b16x8, a), __builtin_bit_cast(b16x8, b), c, 0, 0, 0);
}
__device__ __forceinline__ void gload_lds16(const void* g, void* lds){
  __builtin_amdgcn_global_load_lds(
      (const __attribute__((address_space(1))) void*)g,
      (__attribute__((address_space(3))) void*)lds, 16, 0, 0);
}

// ---------------- fp32 [rows][Kin] -> bf16 [rows][192] ----------------
__global__ void k_cvt(const float* __restrict__ src, ushort* __restrict__ dst,
                      int total, int Kin){
  int gid = blockIdx.x * 256 + threadIdx.x;
  if (gid >= total) return;
  int row = gid / 48;
  int c0 = (gid - row * 48) * 4;
  const float* sp = src + (size_t)row * Kin + c0;
  ushort4 o;
  o.x = (c0     < Kin) ? f2bf(sp[0]) : 0;
  o.y = (c0 + 1 < Kin) ? f2bf(sp[1]) : 0;
  o.z = (c0 + 2 < Kin) ? f2bf(sp[2]) : 0;
  o.w = (c0 + 3 < Kin) ? f2bf(sp[3]) : 0;
  *(ushort4*)(dst + (size_t)row * 192 + c0) = o;
}

// permuted bond cvt: dst row i = f_bonds[p[i]]
__global__ void k_cvtp(const float* __restrict__ src, const int* __restrict__ p,
                       ushort* __restrict__ dst){
  int gid = blockIdx.x * 256 + threadIdx.x;
  if (gid >= NEDGES * 48) return;
  int row = gid / 48;
  int c0 = (gid - row * 48) * 4;
  const float* sp = src + (size_t)p[row] * BFD + c0;
  ushort4 o;
  o.x = (c0     < BFD) ? f2bf(sp[0]) : 0;
  o.y = (c0 + 1 < BFD) ? f2bf(sp[1]) : 0;
  o.z = (c0 + 2 < BFD) ? f2bf(sp[2]) : 0;
  o.w = (c0 + 3 < BFD) ? f2bf(sp[3]) : 0;
  *(ushort4*)(dst + (size_t)row * 192 + c0) = o;
}

// ---------------- weight prep: fp32 -> bf16 fragment order ----------------
__global__ void k_prep_weights(const float* __restrict__ W_i, const float* __restrict__ W_h,
                               const float* __restrict__ W_o, const float* __restrict__ node_W,
                               const float* __restrict__ edge_W,
                               ushort* __restrict__ Wif, ushort* __restrict__ Wof1,
                               ushort* __restrict__ Whf, ushort* __restrict__ Wof2,
                               ushort* __restrict__ nWf, ushort* __restrict__ eWf){
  int gid = blockIdx.x * 256 + threadIdx.x;
  ushort* dst; const float* src; int KB, Kv, Ns, idx;
  if      (gid <  40960){ idx = gid;          dst = Wif;  src = W_i;          KB = 5; Kv = 147; Ns = 256; }
  else if (gid <  81920){ idx = gid -  40960; dst = Wof1; src = W_o;          KB = 5; Kv = 133; Ns = 256; }
  else if (gid < 147456){ idx = gid -  81920; dst = Whf;  src = W_h;          KB = 8; Kv = 256; Ns = 256; }
  else if (gid < 212992){ idx = gid - 147456; dst = Wof2; src = W_o + 133*256;KB = 8; Kv = 256; Ns = 256; }
  else if (gid < 249856){ idx = gid - 212992; dst = nWf;  src = node_W;       KB = 8; Kv = 256; Ns = 133; }
  else if (gid < 253952){ idx = gid - 249856; dst = eWf;  src = edge_W;       KB = 8; Kv = 256; Ns = 14;  }
  else return;
  int j = idx & 7, lane = (idx >> 3) & 63, fi = idx >> 9;
  int kb = fi % KB, nb = fi / KB;
  int k = kb * 32 + ((lane >> 4) << 3) + j;
  int n = nb * 16 + (lane & 15);
  float v = 0.f;
  if (k < Kv && n < Ns) v = src[(size_t)k * Ns + n];
  dst[idx] = f2bf(v);
}

// ---------------- CSR build over src ----------------
__global__ void k_hist(const int* __restrict__ key, int* __restrict__ deg){
  int e = blockIdx.x * 256 + threadIdx.x;
  if (e < NEDGES) atomicAdd(&deg[key[e]], 1);
}
__global__ void k_blocksum(const int* __restrict__ deg, int* __restrict__ bsum){
  __shared__ int s[256];
  int i = blockIdx.x * 256 + threadIdx.x;
  s[threadIdx.x] = (i < NATOMS) ? deg[i] : 0;
  __syncthreads();
  for (int st = 128; st > 0; st >>= 1){
    if (threadIdx.x < st) s[threadIdx.x] += s[threadIdx.x + st];
    __syncthreads();
  }
  if (threadIdx.x == 0) bsum[blockIdx.x] = s[0];
}
#define NBLK 1563
__global__ void k_scanblk(const int* __restrict__ bs, int* __restrict__ bo){
  __shared__ int s[2048];
  int t = threadIdx.x;
  s[2*t]   = (2*t   < NBLK) ? bs[2*t]   : 0;
  s[2*t+1] = (2*t+1 < NBLK) ? bs[2*t+1] : 0;
  int offset = 1;
  for (int d = 1024; d > 0; d >>= 1){
    __syncthreads();
    if (t < d){ int ai = offset*(2*t+1)-1, bi = offset*(2*t+2)-1; s[bi] += s[ai]; }
    offset <<= 1;
  }
  __syncthreads();
  if (t == 0) s[2047] = 0;
  for (int d = 1; d < 2048; d <<= 1){
    offset >>= 1;
    __syncthreads();
    if (t < d){ int ai = offset*(2*t+1)-1, bi = offset*(2*t+2)-1;
                int tmp = s[ai]; s[ai] = s[bi]; s[bi] += tmp; }
  }
  __syncthreads();
  if (2*t   < NBLK) bo[2*t]   = s[2*t];
  if (2*t+1 < NBLK) bo[2*t+1] = s[2*t+1];
}
__global__ void k_offs(const int* __restrict__ deg, const int* __restrict__ bo,
                       int* __restrict__ offs, int* __restrict__ cursor){
  __shared__ int s1[256], s2[256];
  int t = threadIdx.x;
  int i = blockIdx.x * 256 + t;
  int v = (i < NATOMS) ? deg[i] : 0;
  s1[t] = v;
  __syncthreads();
  int* rd = s1; int* wr = s2;
  for (int ofs = 1; ofs < 256; ofs <<= 1){
    wr[t] = rd[t] + ((t >= ofs) ? rd[t - ofs] : 0);
    __syncthreads();
    int* tmp = rd; rd = wr; wr = tmp;
  }
  if (i < NATOMS){
    int excl = rd[t] - v + bo[blockIdx.x];
    offs[i] = excl; cursor[i] = excl;
  }
  if (i == 0) offs[NATOMS] = NEDGES;
}
__global__ void k_fill(const int* __restrict__ key, int* __restrict__ cursor,
                       int* __restrict__ elist){
  int e = blockIdx.x * 256 + threadIdx.x;
  if (e < NEDGES){ int pos = atomicAdd(&cursor[key[e]], 1); elist[pos] = e; }
}
__global__ void k_pos(const int* __restrict__ elist, int* __restrict__ pos){
  int i = blockIdx.x * 256 + threadIdx.x;
  if (i < NEDGES) pos[elist[i]] = i;
}
__global__ void k_maps(const int* __restrict__ elist, const int* __restrict__ pos,
                       int* __restrict__ revp){
  int i = blockIdx.x * 256 + threadIdx.x;
  if (i < NEDGES) revp[i] = pos[elist[i] ^ 1];
}
__global__ void k_molstart(const int* __restrict__ atom_mol, int* __restrict__ molst){
  int m = blockIdx.x * 256 + threadIdx.x;
  if (m > NMOLS) return;
  int lo = 0, hi = NATOMS;
  while (lo < hi){ int mid = (lo + hi) >> 1; if (atom_mol[mid] < m) lo = mid + 1; else hi = mid; }
  molst[m] = lo;
}

// ---------------- K=160 GEMM on padded bf16 rows (pitch 192) ----------------
__global__ __launch_bounds__(256) void k_gemm160(
    const ushort* __restrict__ A16, const ushort* __restrict__ Bf,
    ushort* __restrict__ out){
  __shared__ ushort At[64 * 192];
  const int t = threadIdx.x, w = t >> 6, l = t & 63;
  const long r0 = (long)blockIdx.x * 64;
  const char* Ab = (const char*)(A16 + r0 * 192);
  #pragma unroll
  for (int i = 0; i < 6; i++){
    int dbase = (i * 4 + w) * 1024;
    int d = dbase + l * 16;
    int row = d / 384;
    int sw = (row & 7) << 4;
    gload_lds16(Ab + (d ^ sw), (char*)At + dbase);
  }
  __syncthreads();
  const int lr = l & 15, lg = l >> 4;
  f32x4 acc[4][4] = {};
  for (int kb = 0; kb < 5; kb++){
    s16x8 a[4], b[4];
    #pragma unroll
    for (int m = 0; m < 4; m++){
      int row = m * 16 + lr;
      int cb = (kb * 64 + (lg << 4)) ^ ((row & 7) << 4);
      a[m] = *(const s16x8*)((const char*)At + row * 384 + cb);
    }
    #pragma unroll
    for (int n = 0; n < 4; n++){
      int fi = (w * 4 + n) * 5 + kb;
      b[n] = *(const s16x8*)(Bf + (size_t)(fi * 64 + l) * 8);
    }
    #pragma unroll
    for (int m = 0; m < 4; m++)
      #pragma unroll
      for (int n = 0; n < 4; n++)
        acc[m][n] = mfma16(a[m], b[n], acc[m][n]);
  }
  #pragma unroll
  for (int m = 0; m < 4; m++){
    #pragma unroll
    for (int n = 0; n < 4; n++){
      long base = (r0 + m * 16 + lg * 4) * 256 + (w * 64 + n * 16 + lr);
      #pragma unroll
      for (int r = 0; r < 4; r++)
        out[base + (long)r * 256] = f2bf(acc[m][n][r]);
    }
  }
}

// ---------------- dense E-row GEMM: Y = A @ Whf (gload_lds staging) ----------------
__global__ __launch_bounds__(256) void k_Y(
    const ushort* __restrict__ A, const ushort* __restrict__ Whf,
    ushort* __restrict__ Yout){
  __shared__ ushort At[64 * 256];
  const int t = threadIdx.x, w = t >> 6, l = t & 63;
  const long e0 = (long)blockIdx.x * 64;
  const char* Ab = (const char*)(A + e0 * 256);
  #pragma unroll
  for (int i = 0; i < 8; i++){
    int dbase = (i * 4 + w) * 1024;
    int d = dbase + l * 16;
    int sw = ((d >> 9) & 7) << 4;
    gload_lds16(Ab + (d ^ sw), (char*)At + dbase);
  }
  __syncthreads();
  const int lr = l & 15, lg = l >> 4;
  f32x4 acc[4][4] = {};
  for (int kb = 0; kb < 8; kb++){
    s16x8 a[4], b[4];
    #pragma unroll
    for (int m = 0; m < 4; m++){
      int row = m * 16 + lr;
      int cb = (kb * 64 + (lg << 4)) ^ ((row & 7) << 4);
      a[m] = *(const s16x8*)((const char*)At + row * 512 + cb);
    }
    #pragma unroll
    for (int n = 0; n < 4; n++){
      int fi = (w * 4 + n) * 8 + kb;
      b[n] = *(const s16x8*)(Whf + (size_t)(fi * 64 + l) * 8);
    }
    #pragma unroll
    for (int m = 0; m < 4; m++)
      #pragma unroll
      for (int n = 0; n < 4; n++)
        acc[m][n] = mfma16(a[m], b[n], acc[m][n]);
  }
  #pragma unroll
  for (int m = 0; m < 4; m++){
    #pragma unroll
    for (int n = 0; n < 4; n++){
      long base = (e0 + m * 16 + lg * 4) * 256 + (w * 64 + n * 16 + lr);
      #pragma unroll
      for (int r = 0; r < 4; r++)
        Yout[base + (long)r * 256] = f2bf(acc[m][n][r]);
    }
  }
}

// ---------------- Y0 = relu(inp) @ Whf (reg-staged relu, conflict-free lane map) ----------------
__global__ __launch_bounds__(256) void k_Yrelu(
    const ushort* __restrict__ A, const ushort* __restrict__ Whf,
    ushort* __restrict__ Yout){
  __shared__ ushort At[64 * 256];
  const int t = threadIdx.x, w = t >> 6, l = t & 63;
  const long e0 = (long)blockIdx.x * 64;
  const char* Ab = (const char*)(A + e0 * 256);
  {
    // r = (t&7) | ((t>>5)<<3): each 8-lane phase hits 8 distinct bank groups
    const int r = (t & 7) | ((t >> 5) << 3);
    const int q = (t >> 3) & 3;
    #pragma unroll
    for (int k = 0; k < 8; k++){
      int g = r * 512 + q * 128 + k * 16;
      s16x8 v = *(const s16x8*)(Ab + g);
      #pragma unroll
      for (int j = 0; j < 8; j++){
        ushort u = (ushort)v[j];
        v[j] = (short)((u & 0x8000u) ? 0 : u);
      }
      *(s16x8*)((char*)At + (g ^ ((r & 7) << 4))) = v;
    }
  }
  __syncthreads();
  const int lr = l & 15, lg = l >> 4;
  f32x4 acc[4][4] = {};
  for (int kb = 0; kb < 8; kb++){
    s16x8 a[4], b[4];
    #pragma unroll
    for (int m = 0; m < 4; m++){
      int row = m * 16 + lr;
      int cb = (kb * 64 + (lg << 4)) ^ ((row & 7) << 4);
      a[m] = *(const s16x8*)((const char*)At + row * 512 + cb);
    }
    #pragma unroll
    for (int n = 0; n < 4; n++){
      int fi = (w * 4 + n) * 8 + kb;
      b[n] = *(const s16x8*)(Whf + (size_t)(fi * 64 + l) * 8);
    }
    #pragma unroll
    for (int m = 0; m < 4; m++)
      #pragma unroll
      for (int n = 0; n < 4; n++)
        acc[m][n] = mfma16(a[m], b[n], acc[m][n]);
  }
  #pragma unroll
  for (int m = 0; m < 4; m++){
    #pragma unroll
    for (int n = 0; n < 4; n++){
      long base = (e0 + m * 16 + lg * 4) * 256 + (w * 64 + n * 16 + lr);
      #pragma unroll
      for (int r = 0; r < 4; r++)
        Yout[base + (long)r * 256] = f2bf(acc[m][n][r]);
    }
  }
}

// ---------------- fused segsum+combine (src-sorted order) ----------------
// per atom a (one wave), run [beg,end):
//   S = sum_i Y[revp[i]]  (these are exactly the incoming edges of a)
//   M[i] = relu(inp[i] + S - Y[revp[i]])   (inp/M sequential)
__global__ __launch_bounds__(256) void k_fsum(
    const ushort* __restrict__ Y, const ushort* __restrict__ inp,
    const int* __restrict__ revp, const int* __restrict__ offs,
    ushort* __restrict__ M){
  const int t = threadIdx.x, w = t >> 6, l = t & 63;
  const int a = blockIdx.x * 4 + w;
  const int beg = offs[a], end = offs[a + 1];
  float s0 = 0, s1 = 0, s2 = 0, s3 = 0;
  for (int i = beg; i < end; i++){
    int rv = revp[i];
    const ushort4 v = *(const ushort4*)(Y + (size_t)rv * 256 + l * 4);
    s0 += bf2f(v.x); s1 += bf2f(v.y); s2 += bf2f(v.z); s3 += bf2f(v.w);
  }
  for (int i = beg; i < end; i++){
    int rv = revp[i];
    const ushort4 vy = *(const ushort4*)(Y + (size_t)rv * 256 + l * 4);
    const ushort4 vi = *(const ushort4*)(inp + (size_t)i * 256 + l * 4);
    ushort4 o;
    float r0 = bf2f(vi.x) + s0 - bf2f(vy.x); o.x = f2bf(r0 > 0.f ? r0 : 0.f);
    float r1 = bf2f(vi.y) + s1 - bf2f(vy.y); o.y = f2bf(r1 > 0.f ? r1 : 0.f);
    float r2 = bf2f(vi.z) + s2 - bf2f(vy.z); o.z = f2bf(r2 > 0.f ? r2 : 0.f);
    float r3 = bf2f(vi.w) + s3 - bf2f(vy.w); o.w = f2bf(r3 > 0.f ? r3 : 0.f);
    *(ushort4*)(M + (size_t)i * 256 + l * 4) = o;
  }
}

// ---------------- final aggregation: amsg[a] = sum_i M[revp[i]] ----------------
__global__ __launch_bounds__(256) void k_segsum_rev(
    const ushort* __restrict__ M, const int* __restrict__ revp,
    const int* __restrict__ offs, ushort* __restrict__ amsg){
  const int t = threadIdx.x, w = t >> 6, l = t & 63;
  const int a = blockIdx.x * 4 + w;
  const int beg = offs[a], end = offs[a + 1];
  float a0 = 0, a1 = 0, a2 = 0, a3 = 0;
  for (int i = beg; i < end; i++){
    int rv = revp[i];
    const ushort4 v = *(const ushort4*)(M + (size_t)rv * 256 + l * 4);
    a0 += bf2f(v.x); a1 += bf2f(v.y); a2 += bf2f(v.z); a3 += bf2f(v.w);
  }
  ushort4 o; o.x = f2bf(a0); o.y = f2bf(a1); o.z = f2bf(a2); o.w = f2bf(a3);
  *(ushort4*)(amsg + (size_t)a * 256 + l * 4) = o;
}

// ---------------- W_o part B: ah = relu(amsg @ Wo2 + partial + b_o) ----------------
__global__ __launch_bounds__(256) void k_woB(
    const ushort* __restrict__ amsg, const ushort* __restrict__ Wof2,
    const ushort* __restrict__ partial, const float* __restrict__ b_o,
    ushort* __restrict__ ah){
  const int t = threadIdx.x, w = t >> 6, l = t & 63, lr = l & 15, lg = l >> 4;
  const long r0 = (long)blockIdx.x * 64;
  f32x4 acc[4][4] = {};
  for (int kb = 0; kb < 8; kb++){
    s16x8 a[4], b[4];
    #pragma unroll
    for (int m = 0; m < 4; m++)
      a[m] = *(const s16x8*)(amsg + (r0 + m * 16 + lr) * 256 + kb * 32 + lg * 8);
    #pragma unroll
    for (int n = 0; n < 4; n++)
      b[n] = *(const s16x8*)(Wof2 + (size_t)(((w * 4 + n) * 8 + kb) * 64 + l) * 8);
    #pragma unroll
    for (int m = 0; m < 4; m++)
      #pragma unroll
      for (int n = 0; n < 4; n++)
        acc[m][n] = mfma16(a[m], b[n], acc[m][n]);
  }
  #pragma unroll
  for (int m = 0; m < 4; m++){
    #pragma unroll
    for (int n = 0; n < 4; n++){
      int col = w * 64 + n * 16 + lr;
      float bo = b_o[col];
      long base = (r0 + m * 16 + lg * 4) * 256 + col;
      #pragma unroll
      for (int r = 0; r < 4; r++){
        long ad = base + (long)r * 256;
        float v = acc[m][n][r] + bf2f(partial[ad]) + bo;
        ah[ad] = f2bf(v > 0.f ? v : 0.f);
      }
    }
  }
}

// ---------------- node head ----------------
__global__ __launch_bounds__(192) void k_node(
    const ushort* __restrict__ ah, const ushort* __restrict__ nWf,
    const float* __restrict__ node_b, float* __restrict__ out_node){
  const int t = threadIdx.x, w = t >> 6, l = t & 63, lr = l & 15, lg = l >> 4;
  const long r0 = (long)blockIdx.x * 64;
  f32x4 acc[4][3] = {};
  for (int kb = 0; kb < 8; kb++){
    s16x8 a[4], b[3];
    #pragma unroll
    for (int m = 0; m < 4; m++)
      a[m] = *(const s16x8*)(ah + (r0 + m * 16 + lr) * 256 + kb * 32 + lg * 8);
    #pragma unroll
    for (int n = 0; n < 3; n++)
      b[n] = *(const s16x8*)(nWf + (size_t)(((w * 3 + n) * 8 + kb) * 64 + l) * 8);
    #pragma unroll
    for (int m = 0; m < 4; m++)
      #pragma unroll
      for (int n = 0; n < 3; n++)
        acc[m][n] = mfma16(a[m], b[n], acc[m][n]);
  }
  #pragma unroll
  for (int m = 0; m < 4; m++){
    #pragma unroll
    for (int n = 0; n < 3; n++){
      int col = (w * 3 + n) * 16 + lr;
      if (col < AF){
        float nb = node_b[col];
        #pragma unroll
        for (int r = 0; r < 4; r++)
          out_node[(r0 + m * 16 + lg * 4 + r) * AF + col] = acc[m][n][r] + nb;
      }
    }
  }
}

// ---------------- edge projection ----------------
__global__ __launch_bounds__(64) void k_proj(
    const ushort* __restrict__ ah, const ushort* __restrict__ eWf,
    float* __restrict__ proj){
  const int l = threadIdx.x, lr = l & 15, lg = l >> 4;
  const long r0 = (long)blockIdx.x * 64;
  f32x4 acc[4] = {};
  for (int kb = 0; kb < 8; kb++){
    s16x8 b = *(const s16x8*)(eWf + (size_t)(kb * 64 + l) * 8);
    #pragma unroll
    for (int m = 0; m < 4; m++){
      s16x8 a = *(const s16x8*)(ah + (r0 + m * 16 + lr) * 256 + kb * 32 + lg * 8);
      acc[m] = mfma16(a, b, acc[m]);
    }
  }
  #pragma unroll
  for (int m = 0; m < 4; m++)
    #pragma unroll
    for (int r = 0; r < 4; r++)
      proj[(r0 + m * 16 + lg * 4 + r) * 16 + lr] = acc[m][r];
}

__global__ void k_edge_out(const int* __restrict__ edge_index, const float* __restrict__ proj,
                           const float* __restrict__ edge_b, float* __restrict__ out_edge){
  int gid = blockIdx.x * 256 + threadIdx.x;
  int i = gid >> 4, c = gid & 15;
  if (c < BFdim){
    int s = edge_index[2 * i];
    int d = edge_index[NEDGES + 2 * i];
    out_edge[(size_t)i * BFdim + c] =
        0.5f * (proj[(size_t)s * 16 + c] + proj[(size_t)d * 16 + c]) + edge_b[c];
  }
}

// ---------------- molecule pooling ----------------
__global__ __launch_bounds__(256) void k_pool(const ushort* __restrict__ ah,
                                              const int* __restrict__ molst,
                                              float* __restrict__ gemb){
  const int t = threadIdx.x, w = t >> 6, l = t & 63;
  const int m = blockIdx.x * 4 + w;
  const int beg = molst[m], end = molst[m + 1];
  float a0 = 0, a1 = 0, a2 = 0, a3 = 0;
  for (int i = beg; i < end; i++){
    const ushort4 v = *(const ushort4*)(ah + (size_t)i * 256 + l * 4);
    a0 += bf2f(v.x); a1 += bf2f(v.y); a2 += bf2f(v.z); a3 += bf2f(v.w);
  }
  f32x4 o = {a0, a1, a2, a3};
  *(f32x4*)(gemb + (size_t)m * 256 + l * 4) = o;
}

// ---------------- graph head (fp32) ----------------
__global__ __launch_bounds__(256) void k_g1(const float* __restrict__ gemb,
                                            const float* __restrict__ gW1,
                                            const float* __restrict__ gb1,
                                            float* __restrict__ ghid){
  __shared__ float s[16 * 256];
  const int t = threadIdx.x;
  const int r0 = blockIdx.x * 16;
  for (int i = 0; i < 16; i++){
    int r = r0 + i;
    s[i * 256 + t] = (r < NMOLS) ? gemb[(size_t)r * 256 + t] : 0.f;
  }
  __syncthreads();
  float acc[16] = {};
  for (int k = 0; k < 256; k++){
    float wv = gW1[(size_t)k * 256 + t];
    #pragma unroll
    for (int i = 0; i < 16; i++) acc[i] += s[i * 256 + k] * wv;
  }
  float b = gb1[t];
  for (int i = 0; i < 16; i++){
    int r = r0 + i;
    if (r < NMOLS){ float v = acc[i] + b; ghid[(size_t)r * 256 + t] = v > 0.f ? v : 0.f; }
  }
}
__global__ void k_g2(const float* __restrict__ ghid, const float* __restrict__ gW2,
                     const float* __restrict__ gb2, float* __restrict__ outg){
  const int t = threadIdx.x, w = t >> 6, l = t & 63;
  const int m = blockIdx.x * 4 + w;
  f32x4 v = *(const f32x4*)(ghid + (size_t)m * 256 + l * 4);
  const f32x4 wv = *(const f32x4*)(gW2 + l * 4);
  float acc = v[0] * wv[0] + v[1] * wv[1] + v[2] * wv[2] + v[3] * wv[3];
  for (int ofs = 32; ofs; ofs >>= 1) acc += __shfl_down(acc, ofs, 64);
  if (l == 0) outg[m] = acc + gb2[0];
}

extern "C" void kernel_launch(void* const* d_in, const int* in_sizes, int n_in,
                              void* d_out, int out_size, void* d_ws, size_t ws_size,
                              hipStream_t stream){
  const float* f_atoms = (const float*)d_in[0];
  const float* f_bonds = (const float*)d_in[1];
  const float* W_i     = (const float*)d_in[2];
  const float* W_h     = (const float*)d_in[3];
  const float* W_o     = (const float*)d_in[4];
  const float* b_o     = (const float*)d_in[5];
  const float* node_W  = (const float*)d_in[6];
  const float* node_b  = (const float*)d_in[7];
  const float* edge_W  = (const float*)d_in[8];
  const float* edge_b  = (const float*)d_in[9];
  const float* g_W1    = (const float*)d_in[10];
  const float* g_b1    = (const float*)d_in[11];
  const float* g_W2    = (const float*)d_in[12];
  const float* g_b2    = (const float*)d_in[13];
  const int* edge_index = (const int*)d_in[14];
  const int* atom_mol   = (const int*)d_in[16];

  float* out_node  = (float*)d_out;
  float* out_edge  = out_node + (size_t)NATOMS * AF;
  float* out_graph = out_edge + (size_t)(NEDGES / 2) * BFdim;

  char* p = (char*)d_ws;
  auto alloc = [&](size_t b) -> char* { char* r = p; p += (b + 255) & ~(size_t)255; return r; };
  ushort* B1 = (ushort*)alloc((size_t)NEDGES * 256 * 2);  // inp_pi -> fa16
  ushort* B2 = (ushort*)alloc((size_t)NEDGES * 256 * 2);  // fb16_pi -> M1 -> M2
  ushort* B3 = (ushort*)alloc((size_t)NEDGES * 256 * 2);  // Y0 -> Y1 -> partial
  ushort* N1 = (ushort*)alloc((size_t)NATOMS * 256 * 2);  // ah
  ushort* N2 = (ushort*)alloc((size_t)NATOMS * 256 * 2);  // amsg
  float*  proj  = (float*)alloc((size_t)NATOMS * 16 * 4);
  float*  gemb  = (float*)alloc((size_t)NMOLS * 256 * 4);
  float*  ghid  = (float*)alloc((size_t)NMOLS * 256 * 4);
  ushort* Wif   = (ushort*)alloc(160 * 256 * 2);
  ushort* Wof1  = (ushort*)alloc(160 * 256 * 2);
  ushort* Whf   = (ushort*)alloc(256 * 256 * 2);
  ushort* Wof2  = (ushort*)alloc(256 * 256 * 2);
  ushort* nWf   = (ushort*)alloc(256 * 144 * 2);
  ushort* eWf   = (ushort*)alloc(256 * 16 * 2);
  int* deg    = (int*)alloc(NATOMS * 4);
  int* offs   = (int*)alloc((NATOMS + 1) * 4);
  int* cursor = (int*)alloc(NATOMS * 4);
  int* elist  = (int*)alloc(NEDGES * 4);
  int* pos    = (int*)alloc(NEDGES * 4);
  int* revp   = (int*)alloc(NEDGES * 4);
  int* bsum   = (int*)alloc(1568 * 4);
  int* boff   = (int*)alloc(1568 * 4);
  int* molst  = (int*)alloc((NMOLS + 1) * 4);
  if ((size_t)(p - (char*)d_ws) > ws_size) return;

  const int* srci = edge_index;  // CSR over SRC

  hipMemsetAsync(deg, 0, NATOMS * 4, stream);
  k_prep_weights<<<992, 256, 0, stream>>>(W_i, W_h, W_o, node_W, edge_W,
                                          Wif, Wof1, Whf, Wof2, nWf, eWf);
  // src-CSR + permutation maps
  k_hist<<<3125, 256, 0, stream>>>(srci, deg);
  k_blocksum<<<NBLK, 256, 0, stream>>>(deg, bsum);
  k_scanblk<<<1, 1024, 0, stream>>>(bsum, boff);
  k_offs<<<NBLK, 256, 0, stream>>>(deg, boff, offs, cursor);
  k_fill<<<3125, 256, 0, stream>>>(srci, cursor, elist);
  k_pos<<<3125, 256, 0, stream>>>(elist, pos);
  k_maps<<<3125, 256, 0, stream>>>(elist, pos, revp);
  k_molstart<<<51, 256, 0, stream>>>(atom_mol, molst);

  // fb16 in pi (src-sorted) order -> B2
  k_cvtp<<<150000, 256, 0, stream>>>(f_bonds, elist, B2);
  // inp_pi = fb16 @ W_i -> B1
  k_gemm160<<<12500, 256, 0, stream>>>(B2, Wif, B1);
  // Y0 = relu(inp) @ W_h -> B3
  k_Yrelu<<<12500, 256, 0, stream>>>(B1, Whf, B3);
  // M1 = relu(inp + S0 - Y0[revp]) -> B2   (S0 formed in-wave per src-run)
  k_fsum<<<100000, 256, 0, stream>>>(B3, B1, revp, offs, B2);
  // Y1 = M1 @ W_h -> B3 (Y0 dead)
  k_Y<<<12500, 256, 0, stream>>>(B2, Whf, B3);
  // M2 = relu(inp + S1 - Y1[revp]) -> B2 (M1 dead)
  k_fsum<<<100000, 256, 0, stream>>>(B3, B1, revp, offs, B2);
  // amsg = segsum(M2) via revp gather -> N2
  k_segsum_rev<<<100000, 256, 0, stream>>>(B2, revp, offs, N2);
  // fa16 -> B1 (inp dead)
  k_cvt<<<75000, 256, 0, stream>>>(f_atoms, B1, NATOMS * 48, AF);
  // partial = f_atoms @ Wo1 -> B3 (Y1 dead)
  k_gemm160<<<6250, 256, 0, stream>>>(B1, Wof1, B3);
  // ah = relu(amsg @ Wo2 + partial + b_o) -> N1
  k_woB<<<6250, 256, 0, stream>>>(N2, Wof2, B3, b_o, N1);
  // heads
  k_pool<<<3250, 256, 0, stream>>>(N1, molst, gemb);
  k_node<<<6250, 192, 0, stream>>>(N1, nWf, node_b, out_node);
  k_proj<<<6250, 64, 0, stream>>>(N1, eWf, proj);
  k_edge_out<<<25000, 256, 0, stream>>>(edge_index, proj, edge_b, out_edge);
  k_g1<<<813, 256, 0, stream>>>(gemb, g_W1, g_b1, ghid);
  k_g2<<<3250, 256, 0, stream>>>(ghid, g_W2, g_b2, out_graph);
}

// Round 6
// 2502.272 us; speedup vs baseline: 1.1365x; 1.1000x over previous
//
#include <hip/hip_runtime.h>

#define NATOMS 400000
#define NEDGES 800000
#define NMOLS  13000
#define AF 133
#define BFdim 14
#define BFD 147

typedef __attribute__((ext_vector_type(8))) short  s16x8;
typedef __attribute__((ext_vector_type(8))) __bf16 b16x8;
typedef __attribute__((ext_vector_type(4))) float  f32x4;

__device__ __forceinline__ float bf2f(unsigned short u){
  union { unsigned int i; float f; } v; v.i = ((unsigned int)u) << 16; return v.f;
}
__device__ __forceinline__ unsigned short f2bf(float f){
  union { float ff; unsigned int i; } v; v.ff = f;
  unsigned int b = v.i + 0x7fffu + ((v.i >> 16) & 1u);
  return (unsigned short)(b >> 16);
}
__device__ __forceinline__ f32x4 mfma16(s16x8 a, s16x8 b, f32x4 c){
  return __builtin_amdgcn_mfma_f32_16x16x32_bf16(
      __builtin_bit_cast(b16x8, a), __builtin_bit_cast(b16x8, b), c, 0, 0, 0);
}
__device__ __forceinline__ void gload_lds16(const void* g, void* lds){
  __builtin_amdgcn_global_load_lds(
      (const __attribute__((address_space(1))) void*)g,
      (__attribute__((address_space(3))) void*)lds, 16, 0, 0);
}

// ---------------- fp32 [rows][Kin] -> bf16 [rows][192] ----------------
__global__ void k_cvt(const float* __restrict__ src, ushort* __restrict__ dst,
                      int total, int Kin){
  int gid = blockIdx.x * 256 + threadIdx.x;
  if (gid >= total) return;
  int row = gid / 48;
  int c0 = (gid - row * 48) * 4;
  const float* sp = src + (size_t)row * Kin + c0;
  ushort4 o;
  o.x = (c0     < Kin) ? f2bf(sp[0]) : 0;
  o.y = (c0 + 1 < Kin) ? f2bf(sp[1]) : 0;
  o.z = (c0 + 2 < Kin) ? f2bf(sp[2]) : 0;
  o.w = (c0 + 3 < Kin) ? f2bf(sp[3]) : 0;
  *(ushort4*)(dst + (size_t)row * 192 + c0) = o;
}

// permuted bond cvt: dst row i = f_bonds[p[i]]
__global__ void k_cvtp(const float* __restrict__ src, const int* __restrict__ p,
                       ushort* __restrict__ dst){
  int gid = blockIdx.x * 256 + threadIdx.x;
  if (gid >= NEDGES * 48) return;
  int row = gid / 48;
  int c0 = (gid - row * 48) * 4;
  const float* sp = src + (size_t)p[row] * BFD + c0;
  ushort4 o;
  o.x = (c0     < BFD) ? f2bf(sp[0]) : 0;
  o.y = (c0 + 1 < BFD) ? f2bf(sp[1]) : 0;
  o.z = (c0 + 2 < BFD) ? f2bf(sp[2]) : 0;
  o.w = (c0 + 3 < BFD) ? f2bf(sp[3]) : 0;
  *(ushort4*)(dst + (size_t)row * 192 + c0) = o;
}

// ---------------- weight prep: fp32 -> bf16 fragment order ----------------
__global__ void k_prep_weights(const float* __restrict__ W_i, const float* __restrict__ W_h,
                               const float* __restrict__ W_o, const float* __restrict__ node_W,
                               const float* __restrict__ edge_W,
                               ushort* __restrict__ Wif, ushort* __restrict__ Wof1,
                               ushort* __restrict__ Whf, ushort* __restrict__ Wof2,
                               ushort* __restrict__ nWf, ushort* __restrict__ eWf){
  int gid = blockIdx.x * 256 + threadIdx.x;
  ushort* dst; const float* src; int KB, Kv, Ns, idx;
  if      (gid <  40960){ idx = gid;          dst = Wif;  src = W_i;          KB = 5; Kv = 147; Ns = 256; }
  else if (gid <  81920){ idx = gid -  40960; dst = Wof1; src = W_o;          KB = 5; Kv = 133; Ns = 256; }
  else if (gid < 147456){ idx = gid -  81920; dst = Whf;  src = W_h;          KB = 8; Kv = 256; Ns = 256; }
  else if (gid < 212992){ idx = gid - 147456; dst = Wof2; src = W_o + 133*256;KB = 8; Kv = 256; Ns = 256; }
  else if (gid < 249856){ idx = gid - 212992; dst = nWf;  src = node_W;       KB = 8; Kv = 256; Ns = 133; }
  else if (gid < 253952){ idx = gid - 249856; dst = eWf;  src = edge_W;       KB = 8; Kv = 256; Ns = 14;  }
  else return;
  int j = idx & 7, lane = (idx >> 3) & 63, fi = idx >> 9;
  int kb = fi % KB, nb = fi / KB;
  int k = kb * 32 + ((lane >> 4) << 3) + j;
  int n = nb * 16 + (lane & 15);
  float v = 0.f;
  if (k < Kv && n < Ns) v = src[(size_t)k * Ns + n];
  dst[idx] = f2bf(v);
}

// ---------------- CSR build over src ----------------
__global__ void k_hist(const int* __restrict__ key, int* __restrict__ deg){
  int e = blockIdx.x * 256 + threadIdx.x;
  if (e < NEDGES) atomicAdd(&deg[key[e]], 1);
}
__global__ void k_blocksum(const int* __restrict__ deg, int* __restrict__ bsum){
  __shared__ int s[256];
  int i = blockIdx.x * 256 + threadIdx.x;
  s[threadIdx.x] = (i < NATOMS) ? deg[i] : 0;
  __syncthreads();
  for (int st = 128; st > 0; st >>= 1){
    if (threadIdx.x < st) s[threadIdx.x] += s[threadIdx.x + st];
    __syncthreads();
  }
  if (threadIdx.x == 0) bsum[blockIdx.x] = s[0];
}
#define NBLK 1563
__global__ void k_scanblk(const int* __restrict__ bs, int* __restrict__ bo){
  __shared__ int s[2048];
  int t = threadIdx.x;
  s[2*t]   = (2*t   < NBLK) ? bs[2*t]   : 0;
  s[2*t+1] = (2*t+1 < NBLK) ? bs[2*t+1] : 0;
  int offset = 1;
  for (int d = 1024; d > 0; d >>= 1){
    __syncthreads();
    if (t < d){ int ai = offset*(2*t+1)-1, bi = offset*(2*t+2)-1; s[bi] += s[ai]; }
    offset <<= 1;
  }
  __syncthreads();
  if (t == 0) s[2047] = 0;
  for (int d = 1; d < 2048; d <<= 1){
    offset >>= 1;
    __syncthreads();
    if (t < d){ int ai = offset*(2*t+1)-1, bi = offset*(2*t+2)-1;
                int tmp = s[ai]; s[ai] = s[bi]; s[bi] += tmp; }
  }
  __syncthreads();
  if (2*t   < NBLK) bo[2*t]   = s[2*t];
  if (2*t+1 < NBLK) bo[2*t+1] = s[2*t+1];
}
__global__ void k_offs(const int* __restrict__ deg, const int* __restrict__ bo,
                       int* __restrict__ offs, int* __restrict__ cursor){
  __shared__ int s1[256], s2[256];
  int t = threadIdx.x;
  int i = blockIdx.x * 256 + t;
  int v = (i < NATOMS) ? deg[i] : 0;
  s1[t] = v;
  __syncthreads();
  int* rd = s1; int* wr = s2;
  for (int ofs = 1; ofs < 256; ofs <<= 1){
    wr[t] = rd[t] + ((t >= ofs) ? rd[t - ofs] : 0);
    __syncthreads();
    int* tmp = rd; rd = wr; wr = tmp;
  }
  if (i < NATOMS){
    int excl = rd[t] - v + bo[blockIdx.x];
    offs[i] = excl; cursor[i] = excl;
  }
  if (i == 0) offs[NATOMS] = NEDGES;
}
__global__ void k_fill(const int* __restrict__ key, int* __restrict__ cursor,
                       int* __restrict__ elist){
  int e = blockIdx.x * 256 + threadIdx.x;
  if (e < NEDGES){ int pos = atomicAdd(&cursor[key[e]], 1); elist[pos] = e; }
}
__global__ void k_pos(const int* __restrict__ elist, int* __restrict__ pos){
  int i = blockIdx.x * 256 + threadIdx.x;
  if (i < NEDGES) pos[elist[i]] = i;
}
__global__ void k_maps(const int* __restrict__ elist, const int* __restrict__ pos,
                       const int* __restrict__ eidx,
                       int* __restrict__ srcpi, int* __restrict__ dstp,
                       int* __restrict__ revp){
  int i = blockIdx.x * 256 + threadIdx.x;
  if (i < NEDGES){
    int e = elist[i];
    srcpi[i] = eidx[e];
    dstp[i]  = eidx[NEDGES + e];
    revp[i]  = pos[e ^ 1];
  }
}
__global__ void k_molstart(const int* __restrict__ atom_mol, int* __restrict__ molst){
  int m = blockIdx.x * 256 + threadIdx.x;
  if (m > NMOLS) return;
  int lo = 0, hi = NATOMS;
  while (lo < hi){ int mid = (lo + hi) >> 1; if (atom_mol[mid] < m) lo = mid + 1; else hi = mid; }
  molst[m] = lo;
}

// ---------------- K=160 GEMM on padded bf16 rows (pitch 192) ----------------
__global__ __launch_bounds__(256) void k_gemm160(
    const ushort* __restrict__ A16, const ushort* __restrict__ Bf,
    ushort* __restrict__ out){
  __shared__ ushort At[64 * 192];
  const int t = threadIdx.x, w = t >> 6, l = t & 63;
  const long r0 = (long)blockIdx.x * 64;
  const char* Ab = (const char*)(A16 + r0 * 192);
  #pragma unroll
  for (int i = 0; i < 6; i++){
    int dbase = (i * 4 + w) * 1024;
    int d = dbase + l * 16;
    int row = d / 384;
    int sw = (row & 7) << 4;
    gload_lds16(Ab + (d ^ sw), (char*)At + dbase);
  }
  __syncthreads();
  const int lr = l & 15, lg = l >> 4;
  f32x4 acc[4][4] = {};
  for (int kb = 0; kb < 5; kb++){
    s16x8 a[4], b[4];
    #pragma unroll
    for (int m = 0; m < 4; m++){
      int row = m * 16 + lr;
      int cb = (kb * 64 + (lg << 4)) ^ ((row & 7) << 4);
      a[m] = *(const s16x8*)((const char*)At + row * 384 + cb);
    }
    #pragma unroll
    for (int n = 0; n < 4; n++){
      int fi = (w * 4 + n) * 5 + kb;
      b[n] = *(const s16x8*)(Bf + (size_t)(fi * 64 + l) * 8);
    }
    #pragma unroll
    for (int m = 0; m < 4; m++)
      #pragma unroll
      for (int n = 0; n < 4; n++)
        acc[m][n] = mfma16(a[m], b[n], acc[m][n]);
  }
  #pragma unroll
  for (int m = 0; m < 4; m++){
    #pragma unroll
    for (int n = 0; n < 4; n++){
      long base = (r0 + m * 16 + lg * 4) * 256 + (w * 64 + n * 16 + lr);
      #pragma unroll
      for (int r = 0; r < 4; r++)
        out[base + (long)r * 256] = f2bf(acc[m][n][r]);
    }
  }
}

// ---------------- Y0 = relu(inp) @ Whf (reg-staged relu, conflict-free lane map) ----------------
__global__ __launch_bounds__(256) void k_Yrelu(
    const ushort* __restrict__ A, const ushort* __restrict__ Whf,
    ushort* __restrict__ Yout){
  __shared__ ushort At[64 * 256];
  const int t = threadIdx.x, w = t >> 6, l = t & 63;
  const long e0 = (long)blockIdx.x * 64;
  const char* Ab = (const char*)(A + e0 * 256);
  {
    const int r = (t & 7) | ((t >> 5) << 3);
    const int q = (t >> 3) & 3;
    #pragma unroll
    for (int k = 0; k < 8; k++){
      int g = r * 512 + q * 128 + k * 16;
      s16x8 v = *(const s16x8*)(Ab + g);
      #pragma unroll
      for (int j = 0; j < 8; j++){
        ushort u = (ushort)v[j];
        v[j] = (short)((u & 0x8000u) ? 0 : u);
      }
      *(s16x8*)((char*)At + (g ^ ((r & 7) << 4))) = v;
    }
  }
  __syncthreads();
  const int lr = l & 15, lg = l >> 4;
  f32x4 acc[4][4] = {};
  for (int kb = 0; kb < 8; kb++){
    s16x8 a[4], b[4];
    #pragma unroll
    for (int m = 0; m < 4; m++){
      int row = m * 16 + lr;
      int cb = (kb * 64 + (lg << 4)) ^ ((row & 7) << 4);
      a[m] = *(const s16x8*)((const char*)At + row * 512 + cb);
    }
    #pragma unroll
    for (int n = 0; n < 4; n++){
      int fi = (w * 4 + n) * 8 + kb;
      b[n] = *(const s16x8*)(Whf + (size_t)(fi * 64 + l) * 8);
    }
    #pragma unroll
    for (int m = 0; m < 4; m++)
      #pragma unroll
      for (int n = 0; n < 4; n++)
        acc[m][n] = mfma16(a[m], b[n], acc[m][n]);
  }
  #pragma unroll
  for (int m = 0; m < 4; m++){
    #pragma unroll
    for (int n = 0; n < 4; n++){
      long base = (e0 + m * 16 + lg * 4) * 256 + (w * 64 + n * 16 + lr);
      #pragma unroll
      for (int r = 0; r < 4; r++)
        Yout[base + (long)r * 256] = f2bf(acc[m][n][r]);
    }
  }
}

// ---------------- S[a] = sum over run of Y[revp[i]]  (batched gathers, 8 atoms/block) ----------------
__global__ __launch_bounds__(256) void k_Ssum(
    const ushort* __restrict__ Y, const int* __restrict__ revp,
    const int* __restrict__ offs, ushort* __restrict__ S){
  const int t = threadIdx.x, g = t >> 5, h = t & 31;
  const int a = blockIdx.x * 8 + g;
  const int beg = offs[a], end = offs[a + 1];
  float acc[8] = {};
  for (int base = beg; base < end; base += 4){
    int n = end - base; if (n > 4) n = 4;
    int rv[4];
    #pragma unroll
    for (int k = 0; k < 4; k++) if (k < n) rv[k] = revp[base + k];
    s16x8 y[4];
    #pragma unroll
    for (int k = 0; k < 4; k++) if (k < n)
      y[k] = *(const s16x8*)(Y + (size_t)rv[k] * 256 + h * 8);
    #pragma unroll
    for (int k = 0; k < 4; k++) if (k < n){
      #pragma unroll
      for (int j = 0; j < 8; j++) acc[j] += bf2f((ushort)y[k][j]);
    }
  }
  s16x8 ov;
  #pragma unroll
  for (int j = 0; j < 8; j++) ov[j] = (short)f2bf(acc[j]);
  *(s16x8*)(S + (size_t)a * 256 + h * 8) = ov;
}

// ---------------- fused combine+GEMM: Yout = relu(inp + S[srcpi] - Yprev[revp]) @ Whf ----------------
__global__ __launch_bounds__(256) void k_Yfused2(
    const ushort* __restrict__ inp, const ushort* __restrict__ S,
    const ushort* __restrict__ Yprev, const int* __restrict__ srcpi,
    const int* __restrict__ revp, const ushort* __restrict__ Whf,
    ushort* __restrict__ Yout){
  __shared__ ushort At[64 * 256];
  const int t = threadIdx.x, w = t >> 6, l = t & 63;
  const long e0 = (long)blockIdx.x * 64;
  {
    const int r = (t & 7) | ((t >> 5) << 3);  // conflict-free phase map
    const int q = (t >> 3) & 3;
    const long i = e0 + r;
    const int sa = srcpi[i], rv = revp[i];
    const ushort* pi = inp   + i * 256 + q * 64;
    const ushort* ps = S     + (size_t)sa * 256 + q * 64;
    const ushort* py = Yprev + (size_t)rv * 256 + q * 64;
    #pragma unroll
    for (int k = 0; k < 8; k++){
      s16x8 va = *(const s16x8*)(pi + k * 8);
      s16x8 vs = *(const s16x8*)(ps + k * 8);
      s16x8 vy = *(const s16x8*)(py + k * 8);
      s16x8 res;
      #pragma unroll
      for (int j = 0; j < 8; j++){
        float v = bf2f((ushort)va[j]) + bf2f((ushort)vs[j]) - bf2f((ushort)vy[j]);
        res[j] = (short)f2bf(v > 0.f ? v : 0.f);
      }
      int gb = r * 512 + q * 128 + k * 16;
      *(s16x8*)((char*)At + (gb ^ ((r & 7) << 4))) = res;
    }
  }
  __syncthreads();
  const int lr = l & 15, lg = l >> 4;
  f32x4 acc[4][4] = {};
  for (int kb = 0; kb < 8; kb++){
    s16x8 a[4], b[4];
    #pragma unroll
    for (int m = 0; m < 4; m++){
      int row = m * 16 + lr;
      int cb = (kb * 64 + (lg << 4)) ^ ((row & 7) << 4);
      a[m] = *(const s16x8*)((const char*)At + row * 512 + cb);
    }
    #pragma unroll
    for (int n = 0; n < 4; n++){
      int fi = (w * 4 + n) * 8 + kb;
      b[n] = *(const s16x8*)(Whf + (size_t)(fi * 64 + l) * 8);
    }
    #pragma unroll
    for (int m = 0; m < 4; m++)
      #pragma unroll
      for (int n = 0; n < 4; n++)
        acc[m][n] = mfma16(a[m], b[n], acc[m][n]);
  }
  #pragma unroll
  for (int m = 0; m < 4; m++){
    #pragma unroll
    for (int n = 0; n < 4; n++){
      long base = (e0 + m * 16 + lg * 4) * 256 + (w * 64 + n * 16 + lr);
      #pragma unroll
      for (int r = 0; r < 4; r++)
        Yout[base + (long)r * 256] = f2bf(acc[m][n][r]);
    }
  }
}

// ---------------- tail: amsg[a] = sum over run of relu(inp[revp[i]] + S1[dstp[i]] - Y1[i]) ----------------
__global__ __launch_bounds__(256) void k_tail2(
    const ushort* __restrict__ inp, const ushort* __restrict__ S1,
    const ushort* __restrict__ Y1, const int* __restrict__ revp,
    const int* __restrict__ dstp, const int* __restrict__ offs,
    ushort* __restrict__ amsg){
  const int t = threadIdx.x, g = t >> 5, h = t & 31;
  const int a = blockIdx.x * 8 + g;
  const int beg = offs[a], end = offs[a + 1];
  float acc[8] = {};
  for (int base = beg; base < end; base += 4){
    int n = end - base; if (n > 4) n = 4;
    int rv[4], dp[4];
    #pragma unroll
    for (int k = 0; k < 4; k++) if (k < n){ rv[k] = revp[base + k]; dp[k] = dstp[base + k]; }
    s16x8 vy[4], vi[4], vs[4];
    #pragma unroll
    for (int k = 0; k < 4; k++) if (k < n){
      vy[k] = *(const s16x8*)(Y1  + (size_t)(base + k) * 256 + h * 8);
      vi[k] = *(const s16x8*)(inp + (size_t)rv[k] * 256 + h * 8);
      vs[k] = *(const s16x8*)(S1  + (size_t)dp[k] * 256 + h * 8);
    }
    #pragma unroll
    for (int k = 0; k < 4; k++) if (k < n){
      #pragma unroll
      for (int j = 0; j < 8; j++){
        float v = bf2f((ushort)vi[k][j]) + bf2f((ushort)vs[k][j]) - bf2f((ushort)vy[k][j]);
        acc[j] += (v > 0.f ? v : 0.f);
      }
    }
  }
  s16x8 ov;
  #pragma unroll
  for (int j = 0; j < 8; j++) ov[j] = (short)f2bf(acc[j]);
  *(s16x8*)(amsg + (size_t)a * 256 + h * 8) = ov;
}

// ---------------- fused output transform: ah = relu(fa16 @ Wof1 + amsg @ Wof2 + b_o) ----------------
__global__ __launch_bounds__(256) void k_ah(
    const ushort* __restrict__ fa16, const ushort* __restrict__ Wof1,
    const ushort* __restrict__ amsg, const ushort* __restrict__ Wof2,
    const float* __restrict__ b_o, ushort* __restrict__ ah){
  __shared__ ushort At[64 * 192];
  const int t = threadIdx.x, w = t >> 6, l = t & 63;
  const long r0 = (long)blockIdx.x * 64;
  const char* Ab = (const char*)(fa16 + r0 * 192);
  #pragma unroll
  for (int i = 0; i < 6; i++){
    int dbase = (i * 4 + w) * 1024;
    int d = dbase + l * 16;
    int row = d / 384;
    gload_lds16(Ab + (d ^ ((row & 7) << 4)), (char*)At + dbase);
  }
  __syncthreads();
  const int lr = l & 15, lg = l >> 4;
  f32x4 acc[4][4] = {};
  for (int kb = 0; kb < 5; kb++){
    s16x8 a[4], b[4];
    #pragma unroll
    for (int m = 0; m < 4; m++){
      int row = m * 16 + lr;
      int cb = (kb * 64 + (lg << 4)) ^ ((row & 7) << 4);
      a[m] = *(const s16x8*)((const char*)At + row * 384 + cb);
    }
    #pragma unroll
    for (int n = 0; n < 4; n++)
      b[n] = *(const s16x8*)(Wof1 + (size_t)(((w * 4 + n) * 5 + kb) * 64 + l) * 8);
    #pragma unroll
    for (int m = 0; m < 4; m++)
      #pragma unroll
      for (int n = 0; n < 4; n++)
        acc[m][n] = mfma16(a[m], b[n], acc[m][n]);
  }
  for (int kb = 0; kb < 8; kb++){
    s16x8 a[4], b[4];
    #pragma unroll
    for (int m = 0; m < 4; m++)
      a[m] = *(const s16x8*)(amsg + (r0 + m * 16 + lr) * 256 + kb * 32 + lg * 8);
    #pragma unroll
    for (int n = 0; n < 4; n++)
      b[n] = *(const s16x8*)(Wof2 + (size_t)(((w * 4 + n) * 8 + kb) * 64 + l) * 8);
    #pragma unroll
    for (int m = 0; m < 4; m++)
      #pragma unroll
      for (int n = 0; n < 4; n++)
        acc[m][n] = mfma16(a[m], b[n], acc[m][n]);
  }
  #pragma unroll
  for (int m = 0; m < 4; m++){
    #pragma unroll
    for (int n = 0; n < 4; n++){
      int col = w * 64 + n * 16 + lr;
      float bo = b_o[col];
      long base = (r0 + m * 16 + lg * 4) * 256 + col;
      #pragma unroll
      for (int r = 0; r < 4; r++){
        float v = acc[m][n][r] + bo;
        ah[base + (long)r * 256] = f2bf(v > 0.f ? v : 0.f);
      }
    }
  }
}

// ---------------- node head ----------------
__global__ __launch_bounds__(192) void k_node(
    const ushort* __restrict__ ah, const ushort* __restrict__ nWf,
    const float* __restrict__ node_b, float* __restrict__ out_node){
  const int t = threadIdx.x, w = t >> 6, l = t & 63, lr = l & 15, lg = l >> 4;
  const long r0 = (long)blockIdx.x * 64;
  f32x4 acc[4][3] = {};
  for (int kb = 0; kb < 8; kb++){
    s16x8 a[4], b[3];
    #pragma unroll
    for (int m = 0; m < 4; m++)
      a[m] = *(const s16x8*)(ah + (r0 + m * 16 + lr) * 256 + kb * 32 + lg * 8);
    #pragma unroll
    for (int n = 0; n < 3; n++)
      b[n] = *(const s16x8*)(nWf + (size_t)(((w * 3 + n) * 8 + kb) * 64 + l) * 8);
    #pragma unroll
    for (int m = 0; m < 4; m++)
      #pragma unroll
      for (int n = 0; n < 3; n++)
        acc[m][n] = mfma16(a[m], b[n], acc[m][n]);
  }
  #pragma unroll
  for (int m = 0; m < 4; m++){
    #pragma unroll
    for (int n = 0; n < 3; n++){
      int col = (w * 3 + n) * 16 + lr;
      if (col < AF){
        float nb = node_b[col];
        #pragma unroll
        for (int r = 0; r < 4; r++)
          out_node[(r0 + m * 16 + lg * 4 + r) * AF + col] = acc[m][n][r] + nb;
      }
    }
  }
}

// ---------------- edge projection ----------------
__global__ __launch_bounds__(64) void k_proj(
    const ushort* __restrict__ ah, const ushort* __restrict__ eWf,
    float* __restrict__ proj){
  const int l = threadIdx.x, lr = l & 15, lg = l >> 4;
  const long r0 = (long)blockIdx.x * 64;
  f32x4 acc[4] = {};
  for (int kb = 0; kb < 8; kb++){
    s16x8 b = *(const s16x8*)(eWf + (size_t)(kb * 64 + l) * 8);
    #pragma unroll
    for (int m = 0; m < 4; m++){
      s16x8 a = *(const s16x8*)(ah + (r0 + m * 16 + lr) * 256 + kb * 32 + lg * 8);
      acc[m] = mfma16(a, b, acc[m]);
    }
  }
  #pragma unroll
  for (int m = 0; m < 4; m++)
    #pragma unroll
    for (int r = 0; r < 4; r++)
      proj[(r0 + m * 16 + lg * 4 + r) * 16 + lr] = acc[m][r];
}

__global__ void k_edge_out(const int* __restrict__ edge_index, const float* __restrict__ proj,
                           const float* __restrict__ edge_b, float* __restrict__ out_edge){
  int gid = blockIdx.x * 256 + threadIdx.x;
  int i = gid >> 4, c = gid & 15;
  if (c < BFdim){
    int s = edge_index[2 * i];
    int d = edge_index[NEDGES + 2 * i];
    out_edge[(size_t)i * BFdim + c] =
        0.5f * (proj[(size_t)s * 16 + c] + proj[(size_t)d * 16 + c]) + edge_b[c];
  }
}

// ---------------- molecule pooling ----------------
__global__ __launch_bounds__(256) void k_pool(const ushort* __restrict__ ah,
                                              const int* __restrict__ molst,
                                              float* __restrict__ gemb){
  const int t = threadIdx.x, w = t >> 6, l = t & 63;
  const int m = blockIdx.x * 4 + w;
  const int beg = molst[m], end = molst[m + 1];
  float a0 = 0, a1 = 0, a2 = 0, a3 = 0;
  for (int i = beg; i < end; i++){
    const ushort4 v = *(const ushort4*)(ah + (size_t)i * 256 + l * 4);
    a0 += bf2f(v.x); a1 += bf2f(v.y); a2 += bf2f(v.z); a3 += bf2f(v.w);
  }
  f32x4 o = {a0, a1, a2, a3};
  *(f32x4*)(gemb + (size_t)m * 256 + l * 4) = o;
}

// ---------------- graph head (fp32) ----------------
__global__ __launch_bounds__(256) void k_g1(const float* __restrict__ gemb,
                                            const float* __restrict__ gW1,
                                            const float* __restrict__ gb1,
                                            float* __restrict__ ghid){
  __shared__ float s[16 * 256];
  const int t = threadIdx.x;
  const int r0 = blockIdx.x * 16;
  for (int i = 0; i < 16; i++){
    int r = r0 + i;
    s[i * 256 + t] = (r < NMOLS) ? gemb[(size_t)r * 256 + t] : 0.f;
  }
  __syncthreads();
  float acc[16] = {};
  for (int k = 0; k < 256; k++){
    float wv = gW1[(size_t)k * 256 + t];
    #pragma unroll
    for (int i = 0; i < 16; i++) acc[i] += s[i * 256 + k] * wv;
  }
  float b = gb1[t];
  for (int i = 0; i < 16; i++){
    int r = r0 + i;
    if (r < NMOLS){ float v = acc[i] + b; ghid[(size_t)r * 256 + t] = v > 0.f ? v : 0.f; }
  }
}
__global__ void k_g2(const float* __restrict__ ghid, const float* __restrict__ gW2,
                     const float* __restrict__ gb2, float* __restrict__ outg){
  const int t = threadIdx.x, w = t >> 6, l = t & 63;
  const int m = blockIdx.x * 4 + w;
  f32x4 v = *(const f32x4*)(ghid + (size_t)m * 256 + l * 4);
  const f32x4 wv = *(const f32x4*)(gW2 + l * 4);
  float acc = v[0] * wv[0] + v[1] * wv[1] + v[2] * wv[2] + v[3] * wv[3];
  for (int ofs = 32; ofs; ofs >>= 1) acc += __shfl_down(acc, ofs, 64);
  if (l == 0) outg[m] = acc + gb2[0];
}

extern "C" void kernel_launch(void* const* d_in, const int* in_sizes, int n_in,
                              void* d_out, int out_size, void* d_ws, size_t ws_size,
                              hipStream_t stream){
  const float* f_atoms = (const float*)d_in[0];
  const float* f_bonds = (const float*)d_in[1];
  const float* W_i     = (const float*)d_in[2];
  const float* W_h     = (const float*)d_in[3];
  const float* W_o     = (const float*)d_in[4];
  const float* b_o     = (const float*)d_in[5];
  const float* node_W  = (const float*)d_in[6];
  const float* node_b  = (const float*)d_in[7];
  const float* edge_W  = (const float*)d_in[8];
  const float* edge_b  = (const float*)d_in[9];
  const float* g_W1    = (const float*)d_in[10];
  const float* g_b1    = (const float*)d_in[11];
  const float* g_W2    = (const float*)d_in[12];
  const float* g_b2    = (const float*)d_in[13];
  const int* edge_index = (const int*)d_in[14];
  const int* atom_mol   = (const int*)d_in[16];

  float* out_node  = (float*)d_out;
  float* out_edge  = out_node + (size_t)NATOMS * AF;
  float* out_graph = out_edge + (size_t)(NEDGES / 2) * BFdim;

  char* p = (char*)d_ws;
  auto alloc = [&](size_t b) -> char* { char* r = p; p += (b + 255) & ~(size_t)255; return r; };
  ushort* B1 = (ushort*)alloc((size_t)NEDGES * 256 * 2);  // inp -> fa16
  ushort* B2 = (ushort*)alloc((size_t)NEDGES * 256 * 2);  // fb16 -> Y1
  ushort* B3 = (ushort*)alloc((size_t)NEDGES * 256 * 2);  // Y0
  ushort* N1 = (ushort*)alloc((size_t)NATOMS * 256 * 2);  // S0/S1 -> ah
  ushort* N2 = (ushort*)alloc((size_t)NATOMS * 256 * 2);  // amsg
  float*  proj  = (float*)alloc((size_t)NATOMS * 16 * 4);
  float*  gemb  = (float*)alloc((size_t)NMOLS * 256 * 4);
  float*  ghid  = (float*)alloc((size_t)NMOLS * 256 * 4);
  ushort* Wif   = (ushort*)alloc(160 * 256 * 2);
  ushort* Wof1  = (ushort*)alloc(160 * 256 * 2);
  ushort* Whf   = (ushort*)alloc(256 * 256 * 2);
  ushort* Wof2  = (ushort*)alloc(256 * 256 * 2);
  ushort* nWf   = (ushort*)alloc(256 * 144 * 2);
  ushort* eWf   = (ushort*)alloc(256 * 16 * 2);
  int* deg    = (int*)alloc(NATOMS * 4);
  int* offs   = (int*)alloc((NATOMS + 1) * 4);
  int* cursor = (int*)alloc(NATOMS * 4);
  int* elist  = (int*)alloc(NEDGES * 4);
  int* pos    = (int*)alloc(NEDGES * 4);
  int* srcpi  = (int*)alloc(NEDGES * 4);
  int* dstp   = (int*)alloc(NEDGES * 4);
  int* revp   = (int*)alloc(NEDGES * 4);
  int* bsum   = (int*)alloc(1568 * 4);
  int* boff   = (int*)alloc(1568 * 4);
  int* molst  = (int*)alloc((NMOLS + 1) * 4);
  if ((size_t)(p - (char*)d_ws) > ws_size) return;

  const int* srci = edge_index;  // CSR over SRC

  hipMemsetAsync(deg, 0, NATOMS * 4, stream);
  k_prep_weights<<<992, 256, 0, stream>>>(W_i, W_h, W_o, node_W, edge_W,
                                          Wif, Wof1, Whf, Wof2, nWf, eWf);
  // src-CSR + permutation maps
  k_hist<<<3125, 256, 0, stream>>>(srci, deg);
  k_blocksum<<<NBLK, 256, 0, stream>>>(deg, bsum);
  k_scanblk<<<1, 1024, 0, stream>>>(bsum, boff);
  k_offs<<<NBLK, 256, 0, stream>>>(deg, boff, offs, cursor);
  k_fill<<<3125, 256, 0, stream>>>(srci, cursor, elist);
  k_pos<<<3125, 256, 0, stream>>>(elist, pos);
  k_maps<<<3125, 256, 0, stream>>>(elist, pos, edge_index, srcpi, dstp, revp);
  k_molstart<<<51, 256, 0, stream>>>(atom_mol, molst);

  // fb16 in src-sorted order -> B2
  k_cvtp<<<150000, 256, 0, stream>>>(f_bonds, elist, B2);
  // inp = fb16 @ W_i -> B1
  k_gemm160<<<12500, 256, 0, stream>>>(B2, Wif, B1);
  // Y0 = relu(inp) @ W_h -> B3
  k_Yrelu<<<12500, 256, 0, stream>>>(B1, Whf, B3);
  // S0 -> N1
  k_Ssum<<<50000, 256, 0, stream>>>(B3, revp, offs, N1);
  // Y1 = relu(inp + S0[src] - Y0[revp]) @ W_h -> B2 (M1 never materialized)
  k_Yfused2<<<12500, 256, 0, stream>>>(B1, N1, B3, srcpi, revp, Whf, B2);
  // S1 -> N1
  k_Ssum<<<50000, 256, 0, stream>>>(B2, revp, offs, N1);
  // amsg -> N2 (M2 never materialized)
  k_tail2<<<50000, 256, 0, stream>>>(B1, N1, B2, revp, dstp, offs, N2);
  // fa16 -> B1 (inp dead)
  k_cvt<<<75000, 256, 0, stream>>>(f_atoms, B1, NATOMS * 48, AF);
  // ah = relu(fa16 @ Wof1 + amsg @ Wof2 + b_o) -> N1 (S1 dead; partial never materialized)
  k_ah<<<6250, 256, 0, stream>>>(B1, Wof1, N2, Wof2, b_o, N1);
  // heads
  k_pool<<<3250, 256, 0, stream>>>(N1, molst, gemb);
  k_node<<<6250, 192, 0, stream>>>(N1, nWf, node_b, out_node);
  k_proj<<<6250, 64, 0, stream>>>(N1, eWf, proj);
  k_edge_out<<<25000, 256, 0, stream>>>(edge_index, proj, edge_b, out_edge);
  k_g1<<<813, 256, 0, stream>>>(gemb, g_W1, g_b1, ghid);
  k_g2<<<3250, 256, 0, stream>>>(ghid, g_W2, g_b2, out_graph);
}

// Round 7
// 2452.080 us; speedup vs baseline: 1.1598x; 1.0205x over previous
//
#include <hip/hip_runtime.h>

#define NATOMS 400000
#define NEDGES 800000
#define NMOLS  13000
#define AF 133
#define BFdim 14
#define BFD 147

typedef __attribute__((ext_vector_type(8))) short  s16x8;
typedef __attribute__((ext_vector_type(8))) __bf16 b16x8;
typedef __attribute__((ext_vector_type(4))) float  f32x4;

__device__ __forceinline__ float bf2f(unsigned short u){
  union { unsigned int i; float f; } v; v.i = ((unsigned int)u) << 16; return v.f;
}
__device__ __forceinline__ unsigned short f2bf(float f){
  union { float ff; unsigned int i; } v; v.ff = f;
  unsigned int b = v.i + 0x7fffu + ((v.i >> 16) & 1u);
  return (unsigned short)(b >> 16);
}
__device__ __forceinline__ f32x4 mfma16(s16x8 a, s16x8 b, f32x4 c){
  return __builtin_amdgcn_mfma_f32_16x16x32_bf16(
      __builtin_bit_cast(b16x8, a), __builtin_bit_cast(b16x8, b), c, 0, 0, 0);
}
__device__ __forceinline__ void gload_lds16(const void* g, void* lds){
  __builtin_amdgcn_global_load_lds(
      (const __attribute__((address_space(1))) void*)g,
      (__attribute__((address_space(3))) void*)lds, 16, 0, 0);
}

// ---------------- fp32 [rows][Kin] -> bf16 [rows][192] ----------------
__global__ void k_cvt(const float* __restrict__ src, ushort* __restrict__ dst,
                      int total, int Kin){
  int gid = blockIdx.x * 256 + threadIdx.x;
  if (gid >= total) return;
  int row = gid / 48;
  int c0 = (gid - row * 48) * 4;
  const float* sp = src + (size_t)row * Kin + c0;
  ushort4 o;
  o.x = (c0     < Kin) ? f2bf(sp[0]) : 0;
  o.y = (c0 + 1 < Kin) ? f2bf(sp[1]) : 0;
  o.z = (c0 + 2 < Kin) ? f2bf(sp[2]) : 0;
  o.w = (c0 + 3 < Kin) ? f2bf(sp[3]) : 0;
  *(ushort4*)(dst + (size_t)row * 192 + c0) = o;
}

// permuted bond cvt: dst row i = f_bonds[p[i]]
__global__ void k_cvtp(const float* __restrict__ src, const int* __restrict__ p,
                       ushort* __restrict__ dst){
  int gid = blockIdx.x * 256 + threadIdx.x;
  if (gid >= NEDGES * 48) return;
  int row = gid / 48;
  int c0 = (gid - row * 48) * 4;
  const float* sp = src + (size_t)p[row] * BFD + c0;
  ushort4 o;
  o.x = (c0     < BFD) ? f2bf(sp[0]) : 0;
  o.y = (c0 + 1 < BFD) ? f2bf(sp[1]) : 0;
  o.z = (c0 + 2 < BFD) ? f2bf(sp[2]) : 0;
  o.w = (c0 + 3 < BFD) ? f2bf(sp[3]) : 0;
  *(ushort4*)(dst + (size_t)row * 192 + c0) = o;
}

// ---------------- weight prep: fp32 -> bf16 fragment order ----------------
__global__ void k_prep_weights(const float* __restrict__ W_i, const float* __restrict__ W_h,
                               const float* __restrict__ W_o, const float* __restrict__ node_W,
                               const float* __restrict__ edge_W,
                               ushort* __restrict__ Wif, ushort* __restrict__ Wof1,
                               ushort* __restrict__ Whf, ushort* __restrict__ Wof2,
                               ushort* __restrict__ nWf, ushort* __restrict__ eWf){
  int gid = blockIdx.x * 256 + threadIdx.x;
  ushort* dst; const float* src; int KB, Kv, Ns, idx;
  if      (gid <  40960){ idx = gid;          dst = Wif;  src = W_i;          KB = 5; Kv = 147; Ns = 256; }
  else if (gid <  81920){ idx = gid -  40960; dst = Wof1; src = W_o;          KB = 5; Kv = 133; Ns = 256; }
  else if (gid < 147456){ idx = gid -  81920; dst = Whf;  src = W_h;          KB = 8; Kv = 256; Ns = 256; }
  else if (gid < 212992){ idx = gid - 147456; dst = Wof2; src = W_o + 133*256;KB = 8; Kv = 256; Ns = 256; }
  else if (gid < 249856){ idx = gid - 212992; dst = nWf;  src = node_W;       KB = 8; Kv = 256; Ns = 133; }
  else if (gid < 253952){ idx = gid - 249856; dst = eWf;  src = edge_W;       KB = 8; Kv = 256; Ns = 14;  }
  else return;
  int j = idx & 7, lane = (idx >> 3) & 63, fi = idx >> 9;
  int kb = fi % KB, nb = fi / KB;
  int k = kb * 32 + ((lane >> 4) << 3) + j;
  int n = nb * 16 + (lane & 15);
  float v = 0.f;
  if (k < Kv && n < Ns) v = src[(size_t)k * Ns + n];
  dst[idx] = f2bf(v);
}

// ---------------- CSR build over src ----------------
__global__ void k_hist(const int* __restrict__ key, int* __restrict__ deg){
  int e = blockIdx.x * 256 + threadIdx.x;
  if (e < NEDGES) atomicAdd(&deg[key[e]], 1);
}
__global__ void k_blocksum(const int* __restrict__ deg, int* __restrict__ bsum){
  __shared__ int s[256];
  int i = blockIdx.x * 256 + threadIdx.x;
  s[threadIdx.x] = (i < NATOMS) ? deg[i] : 0;
  __syncthreads();
  for (int st = 128; st > 0; st >>= 1){
    if (threadIdx.x < st) s[threadIdx.x] += s[threadIdx.x + st];
    __syncthreads();
  }
  if (threadIdx.x == 0) bsum[blockIdx.x] = s[0];
}
#define NBLK 1563
__global__ void k_scanblk(const int* __restrict__ bs, int* __restrict__ bo){
  __shared__ int s[2048];
  int t = threadIdx.x;
  s[2*t]   = (2*t   < NBLK) ? bs[2*t]   : 0;
  s[2*t+1] = (2*t+1 < NBLK) ? bs[2*t+1] : 0;
  int offset = 1;
  for (int d = 1024; d > 0; d >>= 1){
    __syncthreads();
    if (t < d){ int ai = offset*(2*t+1)-1, bi = offset*(2*t+2)-1; s[bi] += s[ai]; }
    offset <<= 1;
  }
  __syncthreads();
  if (t == 0) s[2047] = 0;
  for (int d = 1; d < 2048; d <<= 1){
    offset >>= 1;
    __syncthreads();
    if (t < d){ int ai = offset*(2*t+1)-1, bi = offset*(2*t+2)-1;
                int tmp = s[ai]; s[ai] = s[bi]; s[bi] += tmp; }
  }
  __syncthreads();
  if (2*t   < NBLK) bo[2*t]   = s[2*t];
  if (2*t+1 < NBLK) bo[2*t+1] = s[2*t+1];
}
__global__ void k_offs(const int* __restrict__ deg, const int* __restrict__ bo,
                       int* __restrict__ offs, int* __restrict__ cursor){
  __shared__ int s1[256], s2[256];
  int t = threadIdx.x;
  int i = blockIdx.x * 256 + t;
  int v = (i < NATOMS) ? deg[i] : 0;
  s1[t] = v;
  __syncthreads();
  int* rd = s1; int* wr = s2;
  for (int ofs = 1; ofs < 256; ofs <<= 1){
    wr[t] = rd[t] + ((t >= ofs) ? rd[t - ofs] : 0);
    __syncthreads();
    int* tmp = rd; rd = wr; wr = tmp;
  }
  if (i < NATOMS){
    int excl = rd[t] - v + bo[blockIdx.x];
    offs[i] = excl; cursor[i] = excl;
  }
  if (i == 0) offs[NATOMS] = NEDGES;
}
__global__ void k_fill(const int* __restrict__ key, int* __restrict__ cursor,
                       int* __restrict__ elist){
  int e = blockIdx.x * 256 + threadIdx.x;
  if (e < NEDGES){ int pos = atomicAdd(&cursor[key[e]], 1); elist[pos] = e; }
}
__global__ void k_pos(const int* __restrict__ elist, int* __restrict__ pos){
  int i = blockIdx.x * 256 + threadIdx.x;
  if (i < NEDGES) pos[elist[i]] = i;
}
__global__ void k_maps(const int* __restrict__ elist, const int* __restrict__ pos,
                       int* __restrict__ revp){
  int i = blockIdx.x * 256 + threadIdx.x;
  if (i < NEDGES) revp[i] = pos[elist[i] ^ 1];
}
__global__ void k_molstart(const int* __restrict__ atom_mol, int* __restrict__ molst){
  int m = blockIdx.x * 256 + threadIdx.x;
  if (m > NMOLS) return;
  int lo = 0, hi = NATOMS;
  while (lo < hi){ int mid = (lo + hi) >> 1; if (atom_mol[mid] < m) lo = mid + 1; else hi = mid; }
  molst[m] = lo;
}

// ---------------- K=160 GEMM on padded bf16 rows (pitch 192) ----------------
__global__ __launch_bounds__(256) void k_gemm160(
    const ushort* __restrict__ A16, const ushort* __restrict__ Bf,
    ushort* __restrict__ out){
  __shared__ ushort At[64 * 192];
  const int t = threadIdx.x, w = t >> 6, l = t & 63;
  const long r0 = (long)blockIdx.x * 64;
  const char* Ab = (const char*)(A16 + r0 * 192);
  #pragma unroll
  for (int i = 0; i < 6; i++){
    int dbase = (i * 4 + w) * 1024;
    int d = dbase + l * 16;
    int row = d / 384;
    int sw = (row & 7) << 4;
    gload_lds16(Ab + (d ^ sw), (char*)At + dbase);
  }
  __syncthreads();
  const int lr = l & 15, lg = l >> 4;
  f32x4 acc[4][4] = {};
  for (int kb = 0; kb < 5; kb++){
    s16x8 a[4], b[4];
    #pragma unroll
    for (int m = 0; m < 4; m++){
      int row = m * 16 + lr;
      int cb = (kb * 64 + (lg << 4)) ^ ((row & 7) << 4);
      a[m] = *(const s16x8*)((const char*)At + row * 384 + cb);
    }
    #pragma unroll
    for (int n = 0; n < 4; n++){
      int fi = (w * 4 + n) * 5 + kb;
      b[n] = *(const s16x8*)(Bf + (size_t)(fi * 64 + l) * 8);
    }
    #pragma unroll
    for (int m = 0; m < 4; m++)
      #pragma unroll
      for (int n = 0; n < 4; n++)
        acc[m][n] = mfma16(a[m], b[n], acc[m][n]);
  }
  #pragma unroll
  for (int m = 0; m < 4; m++){
    #pragma unroll
    for (int n = 0; n < 4; n++){
      long base = (r0 + m * 16 + lg * 4) * 256 + (w * 64 + n * 16 + lr);
      #pragma unroll
      for (int r = 0; r < 4; r++)
        out[base + (long)r * 256] = f2bf(acc[m][n][r]);
    }
  }
}

// ---------------- dense E-row GEMM: Y = A @ Whf (gload_lds staging) ----------------
__global__ __launch_bounds__(256) void k_Y(
    const ushort* __restrict__ A, const ushort* __restrict__ Whf,
    ushort* __restrict__ Yout){
  __shared__ ushort At[64 * 256];
  const int t = threadIdx.x, w = t >> 6, l = t & 63;
  const long e0 = (long)blockIdx.x * 64;
  const char* Ab = (const char*)(A + e0 * 256);
  #pragma unroll
  for (int i = 0; i < 8; i++){
    int dbase = (i * 4 + w) * 1024;
    int d = dbase + l * 16;
    int sw = ((d >> 9) & 7) << 4;
    gload_lds16(Ab + (d ^ sw), (char*)At + dbase);
  }
  __syncthreads();
  const int lr = l & 15, lg = l >> 4;
  f32x4 acc[4][4] = {};
  for (int kb = 0; kb < 8; kb++){
    s16x8 a[4], b[4];
    #pragma unroll
    for (int m = 0; m < 4; m++){
      int row = m * 16 + lr;
      int cb = (kb * 64 + (lg << 4)) ^ ((row & 7) << 4);
      a[m] = *(const s16x8*)((const char*)At + row * 512 + cb);
    }
    #pragma unroll
    for (int n = 0; n < 4; n++){
      int fi = (w * 4 + n) * 8 + kb;
      b[n] = *(const s16x8*)(Whf + (size_t)(fi * 64 + l) * 8);
    }
    #pragma unroll
    for (int m = 0; m < 4; m++)
      #pragma unroll
      for (int n = 0; n < 4; n++)
        acc[m][n] = mfma16(a[m], b[n], acc[m][n]);
  }
  #pragma unroll
  for (int m = 0; m < 4; m++){
    #pragma unroll
    for (int n = 0; n < 4; n++){
      long base = (e0 + m * 16 + lg * 4) * 256 + (w * 64 + n * 16 + lr);
      #pragma unroll
      for (int r = 0; r < 4; r++)
        Yout[base + (long)r * 256] = f2bf(acc[m][n][r]);
    }
  }
}

// ---------------- Y0 = relu(inp) @ Whf (reg-staged relu, conflict-free lane map) ----------------
__global__ __launch_bounds__(256) void k_Yrelu(
    const ushort* __restrict__ A, const ushort* __restrict__ Whf,
    ushort* __restrict__ Yout){
  __shared__ ushort At[64 * 256];
  const int t = threadIdx.x, w = t >> 6, l = t & 63;
  const long e0 = (long)blockIdx.x * 64;
  const char* Ab = (const char*)(A + e0 * 256);
  {
    const int r = (t & 7) | ((t >> 5) << 3);
    const int q = (t >> 3) & 3;
    #pragma unroll
    for (int k = 0; k < 8; k++){
      int g = r * 512 + q * 128 + k * 16;
      s16x8 v = *(const s16x8*)(Ab + g);
      #pragma unroll
      for (int j = 0; j < 8; j++){
        ushort u = (ushort)v[j];
        v[j] = (short)((u & 0x8000u) ? 0 : u);
      }
      *(s16x8*)((char*)At + (g ^ ((r & 7) << 4))) = v;
    }
  }
  __syncthreads();
  const int lr = l & 15, lg = l >> 4;
  f32x4 acc[4][4] = {};
  for (int kb = 0; kb < 8; kb++){
    s16x8 a[4], b[4];
    #pragma unroll
    for (int m = 0; m < 4; m++){
      int row = m * 16 + lr;
      int cb = (kb * 64 + (lg << 4)) ^ ((row & 7) << 4);
      a[m] = *(const s16x8*)((const char*)At + row * 512 + cb);
    }
    #pragma unroll
    for (int n = 0; n < 4; n++){
      int fi = (w * 4 + n) * 8 + kb;
      b[n] = *(const s16x8*)(Whf + (size_t)(fi * 64 + l) * 8);
    }
    #pragma unroll
    for (int m = 0; m < 4; m++)
      #pragma unroll
      for (int n = 0; n < 4; n++)
        acc[m][n] = mfma16(a[m], b[n], acc[m][n]);
  }
  #pragma unroll
  for (int m = 0; m < 4; m++){
    #pragma unroll
    for (int n = 0; n < 4; n++){
      long base = (e0 + m * 16 + lg * 4) * 256 + (w * 64 + n * 16 + lr);
      #pragma unroll
      for (int r = 0; r < 4; r++)
        Yout[base + (long)r * 256] = f2bf(acc[m][n][r]);
    }
  }
}

// ---------------- fused S+combine (batched, 1 random stream) ----------------
// per atom a (32-lane group, 8 atoms/block), src-run [beg,end):
//   pass A: S = sum_i Y[revp[i]]   (batched 4-wide gathers)
//   pass B: M[i] = relu(inp[i] + S - Y[revp[i]])   (Y rows L1-hot, inp/M sequential)
__global__ __launch_bounds__(256) void k_fsum2(
    const ushort* __restrict__ Y, const ushort* __restrict__ inp,
    const int* __restrict__ revp, const int* __restrict__ offs,
    ushort* __restrict__ M){
  const int t = threadIdx.x, g = t >> 5, h = t & 31;
  const int a = blockIdx.x * 8 + g;
  const int beg = offs[a], end = offs[a + 1];
  float acc[8] = {};
  for (int base = beg; base < end; base += 4){
    int n = end - base; if (n > 4) n = 4;
    int rv[4];
    #pragma unroll
    for (int k = 0; k < 4; k++) if (k < n) rv[k] = revp[base + k];
    s16x8 y[4];
    #pragma unroll
    for (int k = 0; k < 4; k++) if (k < n)
      y[k] = *(const s16x8*)(Y + (size_t)rv[k] * 256 + h * 8);
    #pragma unroll
    for (int k = 0; k < 4; k++) if (k < n){
      #pragma unroll
      for (int j = 0; j < 8; j++) acc[j] += bf2f((ushort)y[k][j]);
    }
  }
  for (int base = beg; base < end; base += 4){
    int n = end - base; if (n > 4) n = 4;
    int rv[4];
    #pragma unroll
    for (int k = 0; k < 4; k++) if (k < n) rv[k] = revp[base + k];
    s16x8 y[4], vi[4];
    #pragma unroll
    for (int k = 0; k < 4; k++) if (k < n){
      y[k]  = *(const s16x8*)(Y   + (size_t)rv[k] * 256 + h * 8);
      vi[k] = *(const s16x8*)(inp + (size_t)(base + k) * 256 + h * 8);
    }
    #pragma unroll
    for (int k = 0; k < 4; k++) if (k < n){
      s16x8 o;
      #pragma unroll
      for (int j = 0; j < 8; j++){
        float v = bf2f((ushort)vi[k][j]) + acc[j] - bf2f((ushort)y[k][j]);
        o[j] = (short)f2bf(v > 0.f ? v : 0.f);
      }
      *(s16x8*)(M + (size_t)(base + k) * 256 + h * 8) = o;
    }
  }
}

// ---------------- final aggregation: amsg[a] = sum_i M[revp[i]] (batched) ----------------
__global__ __launch_bounds__(256) void k_segsum_rev(
    const ushort* __restrict__ M, const int* __restrict__ revp,
    const int* __restrict__ offs, ushort* __restrict__ amsg){
  const int t = threadIdx.x, g = t >> 5, h = t & 31;
  const int a = blockIdx.x * 8 + g;
  const int beg = offs[a], end = offs[a + 1];
  float acc[8] = {};
  for (int base = beg; base < end; base += 4){
    int n = end - base; if (n > 4) n = 4;
    int rv[4];
    #pragma unroll
    for (int k = 0; k < 4; k++) if (k < n) rv[k] = revp[base + k];
    s16x8 y[4];
    #pragma unroll
    for (int k = 0; k < 4; k++) if (k < n)
      y[k] = *(const s16x8*)(M + (size_t)rv[k] * 256 + h * 8);
    #pragma unroll
    for (int k = 0; k < 4; k++) if (k < n){
      #pragma unroll
      for (int j = 0; j < 8; j++) acc[j] += bf2f((ushort)y[k][j]);
    }
  }
  s16x8 ov;
  #pragma unroll
  for (int j = 0; j < 8; j++) ov[j] = (short)f2bf(acc[j]);
  *(s16x8*)(amsg + (size_t)a * 256 + h * 8) = ov;
}

// ---------------- fused output transform: ah = relu(fa16 @ Wof1 + amsg @ Wof2 + b_o) ----------------
__global__ __launch_bounds__(256) void k_ah(
    const ushort* __restrict__ fa16, const ushort* __restrict__ Wof1,
    const ushort* __restrict__ amsg, const ushort* __restrict__ Wof2,
    const float* __restrict__ b_o, ushort* __restrict__ ah){
  __shared__ ushort At[64 * 192];
  const int t = threadIdx.x, w = t >> 6, l = t & 63;
  const long r0 = (long)blockIdx.x * 64;
  const char* Ab = (const char*)(fa16 + r0 * 192);
  #pragma unroll
  for (int i = 0; i < 6; i++){
    int dbase = (i * 4 + w) * 1024;
    int d = dbase + l * 16;
    int row = d / 384;
    gload_lds16(Ab + (d ^ ((row & 7) << 4)), (char*)At + dbase);
  }
  __syncthreads();
  const int lr = l & 15, lg = l >> 4;
  f32x4 acc[4][4] = {};
  for (int kb = 0; kb < 5; kb++){
    s16x8 a[4], b[4];
    #pragma unroll
    for (int m = 0; m < 4; m++){
      int row = m * 16 + lr;
      int cb = (kb * 64 + (lg << 4)) ^ ((row & 7) << 4);
      a[m] = *(const s16x8*)((const char*)At + row * 384 + cb);
    }
    #pragma unroll
    for (int n = 0; n < 4; n++)
      b[n] = *(const s16x8*)(Wof1 + (size_t)(((w * 4 + n) * 5 + kb) * 64 + l) * 8);
    #pragma unroll
    for (int m = 0; m < 4; m++)
      #pragma unroll
      for (int n = 0; n < 4; n++)
        acc[m][n] = mfma16(a[m], b[n], acc[m][n]);
  }
  for (int kb = 0; kb < 8; kb++){
    s16x8 a[4], b[4];
    #pragma unroll
    for (int m = 0; m < 4; m++)
      a[m] = *(const s16x8*)(amsg + (r0 + m * 16 + lr) * 256 + kb * 32 + lg * 8);
    #pragma unroll
    for (int n = 0; n < 4; n++)
      b[n] = *(const s16x8*)(Wof2 + (size_t)(((w * 4 + n) * 8 + kb) * 64 + l) * 8);
    #pragma unroll
    for (int m = 0; m < 4; m++)
      #pragma unroll
      for (int n = 0; n < 4; n++)
        acc[m][n] = mfma16(a[m], b[n], acc[m][n]);
  }
  #pragma unroll
  for (int m = 0; m < 4; m++){
    #pragma unroll
    for (int n = 0; n < 4; n++){
      int col = w * 64 + n * 16 + lr;
      float bo = b_o[col];
      long base = (r0 + m * 16 + lg * 4) * 256 + col;
      #pragma unroll
      for (int r = 0; r < 4; r++){
        float v = acc[m][n][r] + bo;
        ah[base + (long)r * 256] = f2bf(v > 0.f ? v : 0.f);
      }
    }
  }
}

// ---------------- node head ----------------
__global__ __launch_bounds__(192) void k_node(
    const ushort* __restrict__ ah, const ushort* __restrict__ nWf,
    const float* __restrict__ node_b, float* __restrict__ out_node){
  const int t = threadIdx.x, w = t >> 6, l = t & 63, lr = l & 15, lg = l >> 4;
  const long r0 = (long)blockIdx.x * 64;
  f32x4 acc[4][3] = {};
  for (int kb = 0; kb < 8; kb++){
    s16x8 a[4], b[3];
    #pragma unroll
    for (int m = 0; m < 4; m++)
      a[m] = *(const s16x8*)(ah + (r0 + m * 16 + lr) * 256 + kb * 32 + lg * 8);
    #pragma unroll
    for (int n = 0; n < 3; n++)
      b[n] = *(const s16x8*)(nWf + (size_t)(((w * 3 + n) * 8 + kb) * 64 + l) * 8);
    #pragma unroll
    for (int m = 0; m < 4; m++)
      #pragma unroll
      for (int n = 0; n < 3; n++)
        acc[m][n] = mfma16(a[m], b[n], acc[m][n]);
  }
  #pragma unroll
  for (int m = 0; m < 4; m++){
    #pragma unroll
    for (int n = 0; n < 3; n++){
      int col = (w * 3 + n) * 16 + lr;
      if (col < AF){
        float nb = node_b[col];
        #pragma unroll
        for (int r = 0; r < 4; r++)
          out_node[(r0 + m * 16 + lg * 4 + r) * AF + col] = acc[m][n][r] + nb;
      }
    }
  }
}

// ---------------- edge projection ----------------
__global__ __launch_bounds__(64) void k_proj(
    const ushort* __restrict__ ah, const ushort* __restrict__ eWf,
    float* __restrict__ proj){
  const int l = threadIdx.x, lr = l & 15, lg = l >> 4;
  const long r0 = (long)blockIdx.x * 64;
  f32x4 acc[4] = {};
  for (int kb = 0; kb < 8; kb++){
    s16x8 b = *(const s16x8*)(eWf + (size_t)(kb * 64 + l) * 8);
    #pragma unroll
    for (int m = 0; m < 4; m++){
      s16x8 a = *(const s16x8*)(ah + (r0 + m * 16 + lr) * 256 + kb * 32 + lg * 8);
      acc[m] = mfma16(a, b, acc[m]);
    }
  }
  #pragma unroll
  for (int m = 0; m < 4; m++)
    #pragma unroll
    for (int r = 0; r < 4; r++)
      proj[(r0 + m * 16 + lg * 4 + r) * 16 + lr] = acc[m][r];
}

__global__ void k_edge_out(const int* __restrict__ edge_index, const float* __restrict__ proj,
                           const float* __restrict__ edge_b, float* __restrict__ out_edge){
  int gid = blockIdx.x * 256 + threadIdx.x;
  int i = gid >> 4, c = gid & 15;
  if (c < BFdim){
    int s = edge_index[2 * i];
    int d = edge_index[NEDGES + 2 * i];
    out_edge[(size_t)i * BFdim + c] =
        0.5f * (proj[(size_t)s * 16 + c] + proj[(size_t)d * 16 + c]) + edge_b[c];
  }
}

// ---------------- molecule pooling ----------------
__global__ __launch_bounds__(256) void k_pool(const ushort* __restrict__ ah,
                                              const int* __restrict__ molst,
                                              float* __restrict__ gemb){
  const int t = threadIdx.x, w = t >> 6, l = t & 63;
  const int m = blockIdx.x * 4 + w;
  const int beg = molst[m], end = molst[m + 1];
  float a0 = 0, a1 = 0, a2 = 0, a3 = 0;
  for (int i = beg; i < end; i++){
    const ushort4 v = *(const ushort4*)(ah + (size_t)i * 256 + l * 4);
    a0 += bf2f(v.x); a1 += bf2f(v.y); a2 += bf2f(v.z); a3 += bf2f(v.w);
  }
  f32x4 o = {a0, a1, a2, a3};
  *(f32x4*)(gemb + (size_t)m * 256 + l * 4) = o;
}

// ---------------- graph head (fp32) ----------------
__global__ __launch_bounds__(256) void k_g1(const float* __restrict__ gemb,
                                            const float* __restrict__ gW1,
                                            const float* __restrict__ gb1,
                                            float* __restrict__ ghid){
  __shared__ float s[16 * 256];
  const int t = threadIdx.x;
  const int r0 = blockIdx.x * 16;
  for (int i = 0; i < 16; i++){
    int r = r0 + i;
    s[i * 256 + t] = (r < NMOLS) ? gemb[(size_t)r * 256 + t] : 0.f;
  }
  __syncthreads();
  float acc[16] = {};
  for (int k = 0; k < 256; k++){
    float wv = gW1[(size_t)k * 256 + t];
    #pragma unroll
    for (int i = 0; i < 16; i++) acc[i] += s[i * 256 + k] * wv;
  }
  float b = gb1[t];
  for (int i = 0; i < 16; i++){
    int r = r0 + i;
    if (r < NMOLS){ float v = acc[i] + b; ghid[(size_t)r * 256 + t] = v > 0.f ? v : 0.f; }
  }
}
__global__ void k_g2(const float* __restrict__ ghid, const float* __restrict__ gW2,
                     const float* __restrict__ gb2, float* __restrict__ outg){
  const int t = threadIdx.x, w = t >> 6, l = t & 63;
  const int m = blockIdx.x * 4 + w;
  f32x4 v = *(const f32x4*)(ghid + (size_t)m * 256 + l * 4);
  const f32x4 wv = *(const f32x4*)(gW2 + l * 4);
  float acc = v[0] * wv[0] + v[1] * wv[1] + v[2] * wv[2] + v[3] * wv[3];
  for (int ofs = 32; ofs; ofs >>= 1) acc += __shfl_down(acc, ofs, 64);
  if (l == 0) outg[m] = acc + gb2[0];
}

extern "C" void kernel_launch(void* const* d_in, const int* in_sizes, int n_in,
                              void* d_out, int out_size, void* d_ws, size_t ws_size,
                              hipStream_t stream){
  const float* f_atoms = (const float*)d_in[0];
  const float* f_bonds = (const float*)d_in[1];
  const float* W_i     = (const float*)d_in[2];
  const float* W_h     = (const float*)d_in[3];
  const float* W_o     = (const float*)d_in[4];
  const float* b_o     = (const float*)d_in[5];
  const float* node_W  = (const float*)d_in[6];
  const float* node_b  = (const float*)d_in[7];
  const float* edge_W  = (const float*)d_in[8];
  const float* edge_b  = (const float*)d_in[9];
  const float* g_W1    = (const float*)d_in[10];
  const float* g_b1    = (const float*)d_in[11];
  const float* g_W2    = (const float*)d_in[12];
  const float* g_b2    = (const float*)d_in[13];
  const int* edge_index = (const int*)d_in[14];
  const int* atom_mol   = (const int*)d_in[16];

  float* out_node  = (float*)d_out;
  float* out_edge  = out_node + (size_t)NATOMS * AF;
  float* out_graph = out_edge + (size_t)(NEDGES / 2) * BFdim;

  char* p = (char*)d_ws;
  auto alloc = [&](size_t b) -> char* { char* r = p; p += (b + 255) & ~(size_t)255; return r; };
  ushort* B1 = (ushort*)alloc((size_t)NEDGES * 256 * 2);  // inp -> fa16
  ushort* B2 = (ushort*)alloc((size_t)NEDGES * 256 * 2);  // fb16 -> M1 -> M2
  ushort* B3 = (ushort*)alloc((size_t)NEDGES * 256 * 2);  // Y0 -> Y1
  ushort* N1 = (ushort*)alloc((size_t)NATOMS * 256 * 2);  // ah
  ushort* N2 = (ushort*)alloc((size_t)NATOMS * 256 * 2);  // amsg
  float*  proj  = (float*)alloc((size_t)NATOMS * 16 * 4);
  float*  gemb  = (float*)alloc((size_t)NMOLS * 256 * 4);
  float*  ghid  = (float*)alloc((size_t)NMOLS * 256 * 4);
  ushort* Wif   = (ushort*)alloc(160 * 256 * 2);
  ushort* Wof1  = (ushort*)alloc(160 * 256 * 2);
  ushort* Whf   = (ushort*)alloc(256 * 256 * 2);
  ushort* Wof2  = (ushort*)alloc(256 * 256 * 2);
  ushort* nWf   = (ushort*)alloc(256 * 144 * 2);
  ushort* eWf   = (ushort*)alloc(256 * 16 * 2);
  int* deg    = (int*)alloc(NATOMS * 4);
  int* offs   = (int*)alloc((NATOMS + 1) * 4);
  int* cursor = (int*)alloc(NATOMS * 4);
  int* elist  = (int*)alloc(NEDGES * 4);
  int* pos    = (int*)alloc(NEDGES * 4);
  int* revp   = (int*)alloc(NEDGES * 4);
  int* bsum   = (int*)alloc(1568 * 4);
  int* boff   = (int*)alloc(1568 * 4);
  int* molst  = (int*)alloc((NMOLS + 1) * 4);
  if ((size_t)(p - (char*)d_ws) > ws_size) return;

  const int* srci = edge_index;  // CSR over SRC

  hipMemsetAsync(deg, 0, NATOMS * 4, stream);
  k_prep_weights<<<992, 256, 0, stream>>>(W_i, W_h, W_o, node_W, edge_W,
                                          Wif, Wof1, Whf, Wof2, nWf, eWf);
  // src-CSR + rev map
  k_hist<<<3125, 256, 0, stream>>>(srci, deg);
  k_blocksum<<<NBLK, 256, 0, stream>>>(deg, bsum);
  k_scanblk<<<1, 1024, 0, stream>>>(bsum, boff);
  k_offs<<<NBLK, 256, 0, stream>>>(deg, boff, offs, cursor);
  k_fill<<<3125, 256, 0, stream>>>(srci, cursor, elist);
  k_pos<<<3125, 256, 0, stream>>>(elist, pos);
  k_maps<<<3125, 256, 0, stream>>>(elist, pos, revp);
  k_molstart<<<51, 256, 0, stream>>>(atom_mol, molst);

  // fb16 in src-sorted order -> B2
  k_cvtp<<<150000, 256, 0, stream>>>(f_bonds, elist, B2);
  // inp = fb16 @ W_i -> B1
  k_gemm160<<<12500, 256, 0, stream>>>(B2, Wif, B1);
  // Y0 = relu(inp) @ W_h -> B3
  k_Yrelu<<<12500, 256, 0, stream>>>(B1, Whf, B3);
  // M1 = relu(inp + S0 - Y0[revp]) -> B2  (S0 in-register only)
  k_fsum2<<<50000, 256, 0, stream>>>(B3, B1, revp, offs, B2);
  // Y1 = M1 @ W_h -> B3 (Y0 dead)
  k_Y<<<12500, 256, 0, stream>>>(B2, Whf, B3);
  // M2 = relu(inp + S1 - Y1[revp]) -> B2 (M1 dead)
  k_fsum2<<<50000, 256, 0, stream>>>(B3, B1, revp, offs, B2);
  // amsg = segsum(M2) via revp gather -> N2
  k_segsum_rev<<<50000, 256, 0, stream>>>(B2, revp, offs, N2);
  // fa16 -> B1 (inp dead)
  k_cvt<<<75000, 256, 0, stream>>>(f_atoms, B1, NATOMS * 48, AF);
  // ah = relu(fa16 @ Wof1 + amsg @ Wof2 + b_o) -> N1
  k_ah<<<6250, 256, 0, stream>>>(B1, Wof1, N2, Wof2, b_o, N1);
  // heads
  k_pool<<<3250, 256, 0, stream>>>(N1, molst, gemb);
  k_node<<<6250, 192, 0, stream>>>(N1, nWf, node_b, out_node);
  k_proj<<<6250, 64, 0, stream>>>(N1, eWf, proj);
  k_edge_out<<<25000, 256, 0, stream>>>(edge_index, proj, edge_b, out_edge);
  k_g1<<<813, 256, 0, stream>>>(gemb, g_W1, g_b1, ghid);
  k_g2<<<3250, 256, 0, stream>>>(ghid, g_W2, g_b2, out_graph);
}

// Round 8
// 2307.646 us; speedup vs baseline: 1.2324x; 1.0626x over previous
//
#include <hip/hip_runtime.h>

#define NATOMS 400000
#define NEDGES 800000
#define NMOLS  13000
#define AF 133
#define BFdim 14
#define BFD 147

typedef __attribute__((ext_vector_type(8))) short  s16x8;
typedef __attribute__((ext_vector_type(8))) __bf16 b16x8;
typedef __attribute__((ext_vector_type(4))) float  f32x4;

__device__ __forceinline__ float bf2f(unsigned short u){
  union { unsigned int i; float f; } v; v.i = ((unsigned int)u) << 16; return v.f;
}
__device__ __forceinline__ unsigned short f2bf(float f){
  union { float ff; unsigned int i; } v; v.ff = f;
  unsigned int b = v.i + 0x7fffu + ((v.i >> 16) & 1u);
  return (unsigned short)(b >> 16);
}
__device__ __forceinline__ unsigned int pk2(float a, float b){
  unsigned int r;
  asm("v_cvt_pk_bf16_f32 %0, %1, %2" : "=v"(r) : "v"(a), "v"(b));
  return r;
}
__device__ __forceinline__ f32x4 mfma16(s16x8 a, s16x8 b, f32x4 c){
  return __builtin_amdgcn_mfma_f32_16x16x32_bf16(
      __builtin_bit_cast(b16x8, a), __builtin_bit_cast(b16x8, b), c, 0, 0, 0);
}
__device__ __forceinline__ void gload_lds16(const void* g, void* lds){
  __builtin_amdgcn_global_load_lds(
      (const __attribute__((address_space(1))) void*)g,
      (__attribute__((address_space(3))) void*)lds, 16, 0, 0);
}

// ---------------- fp32 [rows][Kin] -> bf16 [rows][192] ----------------
__global__ void k_cvt(const float* __restrict__ src, ushort* __restrict__ dst,
                      int total, int Kin){
  int gid = blockIdx.x * 256 + threadIdx.x;
  if (gid >= total) return;
  int row = gid / 48;
  int c0 = (gid - row * 48) * 4;
  const float* sp = src + (size_t)row * Kin + c0;
  ushort4 o;
  o.x = (c0     < Kin) ? f2bf(sp[0]) : 0;
  o.y = (c0 + 1 < Kin) ? f2bf(sp[1]) : 0;
  o.z = (c0 + 2 < Kin) ? f2bf(sp[2]) : 0;
  o.w = (c0 + 3 < Kin) ? f2bf(sp[3]) : 0;
  *(ushort4*)(dst + (size_t)row * 192 + c0) = o;
}

// permuted bond cvt: dst row i = f_bonds[p[i]]
__global__ void k_cvtp(const float* __restrict__ src, const int* __restrict__ p,
                       ushort* __restrict__ dst){
  int gid = blockIdx.x * 256 + threadIdx.x;
  if (gid >= NEDGES * 48) return;
  int row = gid / 48;
  int c0 = (gid - row * 48) * 4;
  const float* sp = src + (size_t)p[row] * BFD + c0;
  ushort4 o;
  o.x = (c0     < BFD) ? f2bf(sp[0]) : 0;
  o.y = (c0 + 1 < BFD) ? f2bf(sp[1]) : 0;
  o.z = (c0 + 2 < BFD) ? f2bf(sp[2]) : 0;
  o.w = (c0 + 3 < BFD) ? f2bf(sp[3]) : 0;
  *(ushort4*)(dst + (size_t)row * 192 + c0) = o;
}

// ---------------- weight prep: fp32 -> bf16 fragment order ----------------
__global__ void k_prep_weights(const float* __restrict__ W_i, const float* __restrict__ W_h,
                               const float* __restrict__ W_o, const float* __restrict__ node_W,
                               const float* __restrict__ edge_W,
                               ushort* __restrict__ Wif, ushort* __restrict__ Wof1,
                               ushort* __restrict__ Whf, ushort* __restrict__ Wof2,
                               ushort* __restrict__ nWf, ushort* __restrict__ eWf){
  int gid = blockIdx.x * 256 + threadIdx.x;
  ushort* dst; const float* src; int KB, Kv, Ns, idx;
  if      (gid <  40960){ idx = gid;          dst = Wif;  src = W_i;          KB = 5; Kv = 147; Ns = 256; }
  else if (gid <  81920){ idx = gid -  40960; dst = Wof1; src = W_o;          KB = 5; Kv = 133; Ns = 256; }
  else if (gid < 147456){ idx = gid -  81920; dst = Whf;  src = W_h;          KB = 8; Kv = 256; Ns = 256; }
  else if (gid < 212992){ idx = gid - 147456; dst = Wof2; src = W_o + 133*256;KB = 8; Kv = 256; Ns = 256; }
  else if (gid < 249856){ idx = gid - 212992; dst = nWf;  src = node_W;       KB = 8; Kv = 256; Ns = 133; }
  else if (gid < 253952){ idx = gid - 249856; dst = eWf;  src = edge_W;       KB = 8; Kv = 256; Ns = 14;  }
  else return;
  int j = idx & 7, lane = (idx >> 3) & 63, fi = idx >> 9;
  int kb = fi % KB, nb = fi / KB;
  int k = kb * 32 + ((lane >> 4) << 3) + j;
  int n = nb * 16 + (lane & 15);
  float v = 0.f;
  if (k < Kv && n < Ns) v = src[(size_t)k * Ns + n];
  dst[idx] = f2bf(v);
}

// ---------------- CSR build over src ----------------
__global__ void k_hist(const int* __restrict__ key, int* __restrict__ deg){
  int e = blockIdx.x * 256 + threadIdx.x;
  if (e < NEDGES) atomicAdd(&deg[key[e]], 1);
}
__global__ void k_blocksum(const int* __restrict__ deg, int* __restrict__ bsum){
  __shared__ int s[256];
  int i = blockIdx.x * 256 + threadIdx.x;
  s[threadIdx.x] = (i < NATOMS) ? deg[i] : 0;
  __syncthreads();
  for (int st = 128; st > 0; st >>= 1){
    if (threadIdx.x < st) s[threadIdx.x] += s[threadIdx.x + st];
    __syncthreads();
  }
  if (threadIdx.x == 0) bsum[blockIdx.x] = s[0];
}
#define NBLK 1563
__global__ void k_scanblk(const int* __restrict__ bs, int* __restrict__ bo){
  __shared__ int s[2048];
  int t = threadIdx.x;
  s[2*t]   = (2*t   < NBLK) ? bs[2*t]   : 0;
  s[2*t+1] = (2*t+1 < NBLK) ? bs[2*t+1] : 0;
  int offset = 1;
  for (int d = 1024; d > 0; d >>= 1){
    __syncthreads();
    if (t < d){ int ai = offset*(2*t+1)-1, bi = offset*(2*t+2)-1; s[bi] += s[ai]; }
    offset <<= 1;
  }
  __syncthreads();
  if (t == 0) s[2047] = 0;
  for (int d = 1; d < 2048; d <<= 1){
    offset >>= 1;
    __syncthreads();
    if (t < d){ int ai = offset*(2*t+1)-1, bi = offset*(2*t+2)-1;
                int tmp = s[ai]; s[ai] = s[bi]; s[bi] += tmp; }
  }
  __syncthreads();
  if (2*t   < NBLK) bo[2*t]   = s[2*t];
  if (2*t+1 < NBLK) bo[2*t+1] = s[2*t+1];
}
__global__ void k_offs(const int* __restrict__ deg, const int* __restrict__ bo,
                       int* __restrict__ offs, int* __restrict__ cursor){
  __shared__ int s1[256], s2[256];
  int t = threadIdx.x;
  int i = blockIdx.x * 256 + t;
  int v = (i < NATOMS) ? deg[i] : 0;
  s1[t] = v;
  __syncthreads();
  int* rd = s1; int* wr = s2;
  for (int ofs = 1; ofs < 256; ofs <<= 1){
    wr[t] = rd[t] + ((t >= ofs) ? rd[t - ofs] : 0);
    __syncthreads();
    int* tmp = rd; rd = wr; wr = tmp;
  }
  if (i < NATOMS){
    int excl = rd[t] - v + bo[blockIdx.x];
    offs[i] = excl; cursor[i] = excl;
  }
  if (i == 0) offs[NATOMS] = NEDGES;
}
__global__ void k_fill(const int* __restrict__ key, int* __restrict__ cursor,
                       int* __restrict__ elist){
  int e = blockIdx.x * 256 + threadIdx.x;
  if (e < NEDGES){ int pos = atomicAdd(&cursor[key[e]], 1); elist[pos] = e; }
}
__global__ void k_pos(const int* __restrict__ elist, int* __restrict__ pos){
  int i = blockIdx.x * 256 + threadIdx.x;
  if (i < NEDGES) pos[elist[i]] = i;
}
__global__ void k_maps(const int* __restrict__ elist, const int* __restrict__ pos,
                       int* __restrict__ revp){
  int i = blockIdx.x * 256 + threadIdx.x;
  if (i < NEDGES) revp[i] = pos[elist[i] ^ 1];
}
__global__ void k_molstart(const int* __restrict__ atom_mol, int* __restrict__ molst){
  int m = blockIdx.x * 256 + threadIdx.x;
  if (m > NMOLS) return;
  int lo = 0, hi = NATOMS;
  while (lo < hi){ int mid = (lo + hi) >> 1; if (atom_mol[mid] < m) lo = mid + 1; else hi = mid; }
  molst[m] = lo;
}

// ---------------- fused: inp = fb16 @ W_i ; Y0 = relu(inp) @ W_h ----------------
__global__ __launch_bounds__(256) void k_fused_inpY(
    const ushort* __restrict__ A16, const ushort* __restrict__ Wif,
    const ushort* __restrict__ Whf, ushort* __restrict__ inp,
    ushort* __restrict__ Yout){
  __shared__ ushort At[64 * 256]; // 32 KB; phase1 uses 24 KB @pitch384, phase2 @pitch512
  const int t = threadIdx.x, w = t >> 6, l = t & 63;
  const long r0 = (long)blockIdx.x * 64;
  const char* Ab = (const char*)(A16 + r0 * 192);
  #pragma unroll
  for (int i = 0; i < 6; i++){
    int dbase = (i * 4 + w) * 1024;
    int d = dbase + l * 16;
    int row = d / 384;
    gload_lds16(Ab + (d ^ ((row & 7) << 4)), (char*)At + dbase);
  }
  __syncthreads();
  const int lr = l & 15, lg = l >> 4;
  f32x4 acc[4][4] = {};
  for (int kb = 0; kb < 5; kb++){
    s16x8 a[4], b[4];
    #pragma unroll
    for (int m = 0; m < 4; m++){
      int row = m * 16 + lr;
      int cb = (kb * 64 + (lg << 4)) ^ ((row & 7) << 4);
      a[m] = *(const s16x8*)((const char*)At + row * 384 + cb);
    }
    #pragma unroll
    for (int n = 0; n < 4; n++)
      b[n] = *(const s16x8*)(Wif + (size_t)(((w * 4 + n) * 5 + kb) * 64 + l) * 8);
    #pragma unroll
    for (int m = 0; m < 4; m++)
      #pragma unroll
      for (int n = 0; n < 4; n++)
        acc[m][n] = mfma16(a[m], b[n], acc[m][n]);
  }
  __syncthreads();  // all phase-1 LDS reads complete before overwrite
  // epilogue 1: write inp (bf16) and stage relu tile into LDS (pitch 512, swizzled)
  #pragma unroll
  for (int m = 0; m < 4; m++){
    #pragma unroll
    for (int n = 0; n < 4; n++){
      int col = w * 64 + n * 16 + lr;
      long base = (r0 + m * 16 + lg * 4) * 256 + col;
      #pragma unroll
      for (int r = 0; r < 4; r++){
        float v = acc[m][n][r];
        inp[base + (long)r * 256] = f2bf(v);
        int row = m * 16 + lg * 4 + r;
        int byte = row * 512 + ((2 * col) ^ ((row & 7) << 4));
        *(ushort*)((char*)At + byte) = f2bf(v > 0.f ? v : 0.f);
      }
    }
  }
  __syncthreads();
  f32x4 acc2[4][4] = {};
  for (int kb = 0; kb < 8; kb++){
    s16x8 a[4], b[4];
    #pragma unroll
    for (int m = 0; m < 4; m++){
      int row = m * 16 + lr;
      int cb = (kb * 64 + (lg << 4)) ^ ((row & 7) << 4);
      a[m] = *(const s16x8*)((const char*)At + row * 512 + cb);
    }
    #pragma unroll
    for (int n = 0; n < 4; n++)
      b[n] = *(const s16x8*)(Whf + (size_t)(((w * 4 + n) * 8 + kb) * 64 + l) * 8);
    #pragma unroll
    for (int m = 0; m < 4; m++)
      #pragma unroll
      for (int n = 0; n < 4; n++)
        acc2[m][n] = mfma16(a[m], b[n], acc2[m][n]);
  }
  #pragma unroll
  for (int m = 0; m < 4; m++){
    #pragma unroll
    for (int n = 0; n < 4; n++){
      long base = (r0 + m * 16 + lg * 4) * 256 + (w * 64 + n * 16 + lr);
      #pragma unroll
      for (int r = 0; r < 4; r++)
        Yout[base + (long)r * 256] = f2bf(acc2[m][n][r]);
    }
  }
}

// ---------------- dense E-row GEMM: Y = A @ Whf (gload_lds staging) ----------------
__global__ __launch_bounds__(256) void k_Y(
    const ushort* __restrict__ A, const ushort* __restrict__ Whf,
    ushort* __restrict__ Yout){
  __shared__ ushort At[64 * 256];
  const int t = threadIdx.x, w = t >> 6, l = t & 63;
  const long e0 = (long)blockIdx.x * 64;
  const char* Ab = (const char*)(A + e0 * 256);
  #pragma unroll
  for (int i = 0; i < 8; i++){
    int dbase = (i * 4 + w) * 1024;
    int d = dbase + l * 16;
    int sw = ((d >> 9) & 7) << 4;
    gload_lds16(Ab + (d ^ sw), (char*)At + dbase);
  }
  __syncthreads();
  const int lr = l & 15, lg = l >> 4;
  f32x4 acc[4][4] = {};
  for (int kb = 0; kb < 8; kb++){
    s16x8 a[4], b[4];
    #pragma unroll
    for (int m = 0; m < 4; m++){
      int row = m * 16 + lr;
      int cb = (kb * 64 + (lg << 4)) ^ ((row & 7) << 4);
      a[m] = *(const s16x8*)((const char*)At + row * 512 + cb);
    }
    #pragma unroll
    for (int n = 0; n < 4; n++){
      int fi = (w * 4 + n) * 8 + kb;
      b[n] = *(const s16x8*)(Whf + (size_t)(fi * 64 + l) * 8);
    }
    #pragma unroll
    for (int m = 0; m < 4; m++)
      #pragma unroll
      for (int n = 0; n < 4; n++)
        acc[m][n] = mfma16(a[m], b[n], acc[m][n]);
  }
  #pragma unroll
  for (int m = 0; m < 4; m++){
    #pragma unroll
    for (int n = 0; n < 4; n++){
      long base = (e0 + m * 16 + lg * 4) * 256 + (w * 64 + n * 16 + lr);
      #pragma unroll
      for (int r = 0; r < 4; r++)
        Yout[base + (long)r * 256] = f2bf(acc[m][n][r]);
    }
  }
}

// ---------------- fused S+combine (batched, 1 random stream) ----------------
__global__ __launch_bounds__(256) void k_fsum2(
    const ushort* __restrict__ Y, const ushort* __restrict__ inp,
    const int* __restrict__ revp, const int* __restrict__ offs,
    ushort* __restrict__ M){
  const int t = threadIdx.x, g = t >> 5, h = t & 31;
  const int a = blockIdx.x * 8 + g;
  const int beg = offs[a], end = offs[a + 1];
  float acc[8] = {};
  for (int base = beg; base < end; base += 4){
    int n = end - base; if (n > 4) n = 4;
    int rv[4];
    #pragma unroll
    for (int k = 0; k < 4; k++) if (k < n) rv[k] = revp[base + k];
    s16x8 y[4];
    #pragma unroll
    for (int k = 0; k < 4; k++) if (k < n)
      y[k] = *(const s16x8*)(Y + (size_t)rv[k] * 256 + h * 8);
    #pragma unroll
    for (int k = 0; k < 4; k++) if (k < n){
      #pragma unroll
      for (int j = 0; j < 8; j++) acc[j] += bf2f((ushort)y[k][j]);
    }
  }
  for (int base = beg; base < end; base += 4){
    int n = end - base; if (n > 4) n = 4;
    int rv[4];
    #pragma unroll
    for (int k = 0; k < 4; k++) if (k < n) rv[k] = revp[base + k];
    s16x8 y[4], vi[4];
    #pragma unroll
    for (int k = 0; k < 4; k++) if (k < n){
      y[k]  = *(const s16x8*)(Y   + (size_t)rv[k] * 256 + h * 8);
      vi[k] = *(const s16x8*)(inp + (size_t)(base + k) * 256 + h * 8);
    }
    #pragma unroll
    for (int k = 0; k < 4; k++) if (k < n){
      float vv[8];
      #pragma unroll
      for (int j = 0; j < 8; j++){
        float v = bf2f((ushort)vi[k][j]) + acc[j] - bf2f((ushort)y[k][j]);
        vv[j] = v > 0.f ? v : 0.f;
      }
      uint4 o;
      o.x = pk2(vv[0], vv[1]); o.y = pk2(vv[2], vv[3]);
      o.z = pk2(vv[4], vv[5]); o.w = pk2(vv[6], vv[7]);
      *(uint4*)(M + (size_t)(base + k) * 256 + h * 8) = o;
    }
  }
}

// ---------------- final aggregation: amsg[a] = sum_i M[revp[i]] (batched) ----------------
__global__ __launch_bounds__(256) void k_segsum_rev(
    const ushort* __restrict__ M, const int* __restrict__ revp,
    const int* __restrict__ offs, ushort* __restrict__ amsg){
  const int t = threadIdx.x, g = t >> 5, h = t & 31;
  const int a = blockIdx.x * 8 + g;
  const int beg = offs[a], end = offs[a + 1];
  float acc[8] = {};
  for (int base = beg; base < end; base += 4){
    int n = end - base; if (n > 4) n = 4;
    int rv[4];
    #pragma unroll
    for (int k = 0; k < 4; k++) if (k < n) rv[k] = revp[base + k];
    s16x8 y[4];
    #pragma unroll
    for (int k = 0; k < 4; k++) if (k < n)
      y[k] = *(const s16x8*)(M + (size_t)rv[k] * 256 + h * 8);
    #pragma unroll
    for (int k = 0; k < 4; k++) if (k < n){
      #pragma unroll
      for (int j = 0; j < 8; j++) acc[j] += bf2f((ushort)y[k][j]);
    }
  }
  uint4 ov;
  ov.x = pk2(acc[0], acc[1]); ov.y = pk2(acc[2], acc[3]);
  ov.z = pk2(acc[4], acc[5]); ov.w = pk2(acc[6], acc[7]);
  *(uint4*)(amsg + (size_t)a * 256 + h * 8) = ov;
}

// ---------------- fused output transform: ah = relu(fa16 @ Wof1 + amsg @ Wof2 + b_o) ----------------
__global__ __launch_bounds__(256) void k_ah(
    const ushort* __restrict__ fa16, const ushort* __restrict__ Wof1,
    const ushort* __restrict__ amsg, const ushort* __restrict__ Wof2,
    const float* __restrict__ b_o, ushort* __restrict__ ah){
  __shared__ ushort At[64 * 192];
  const int t = threadIdx.x, w = t >> 6, l = t & 63;
  const long r0 = (long)blockIdx.x * 64;
  const char* Ab = (const char*)(fa16 + r0 * 192);
  #pragma unroll
  for (int i = 0; i < 6; i++){
    int dbase = (i * 4 + w) * 1024;
    int d = dbase + l * 16;
    int row = d / 384;
    gload_lds16(Ab + (d ^ ((row & 7) << 4)), (char*)At + dbase);
  }
  __syncthreads();
  const int lr = l & 15, lg = l >> 4;
  f32x4 acc[4][4] = {};
  for (int kb = 0; kb < 5; kb++){
    s16x8 a[4], b[4];
    #pragma unroll
    for (int m = 0; m < 4; m++){
      int row = m * 16 + lr;
      int cb = (kb * 64 + (lg << 4)) ^ ((row & 7) << 4);
      a[m] = *(const s16x8*)((const char*)At + row * 384 + cb);
    }
    #pragma unroll
    for (int n = 0; n < 4; n++)
      b[n] = *(const s16x8*)(Wof1 + (size_t)(((w * 4 + n) * 5 + kb) * 64 + l) * 8);
    #pragma unroll
    for (int m = 0; m < 4; m++)
      #pragma unroll
      for (int n = 0; n < 4; n++)
        acc[m][n] = mfma16(a[m], b[n], acc[m][n]);
  }
  for (int kb = 0; kb < 8; kb++){
    s16x8 a[4], b[4];
    #pragma unroll
    for (int m = 0; m < 4; m++)
      a[m] = *(const s16x8*)(amsg + (r0 + m * 16 + lr) * 256 + kb * 32 + lg * 8);
    #pragma unroll
    for (int n = 0; n < 4; n++)
      b[n] = *(const s16x8*)(Wof2 + (size_t)(((w * 4 + n) * 8 + kb) * 64 + l) * 8);
    #pragma unroll
    for (int m = 0; m < 4; m++)
      #pragma unroll
      for (int n = 0; n < 4; n++)
        acc[m][n] = mfma16(a[m], b[n], acc[m][n]);
  }
  #pragma unroll
  for (int m = 0; m < 4; m++){
    #pragma unroll
    for (int n = 0; n < 4; n++){
      int col = w * 64 + n * 16 + lr;
      float bo = b_o[col];
      long base = (r0 + m * 16 + lg * 4) * 256 + col;
      #pragma unroll
      for (int r = 0; r < 4; r++){
        float v = acc[m][n][r] + bo;
        ah[base + (long)r * 256] = f2bf(v > 0.f ? v : 0.f);
      }
    }
  }
}

// ---------------- fused node + edge-proj heads ----------------
// 4 waves; wave w covers n-tiles {w, w+4, w+8}; tile 9 = edge projection.
__global__ __launch_bounds__(256) void k_nodeproj(
    const ushort* __restrict__ ah, const ushort* __restrict__ nWf,
    const ushort* __restrict__ eWf, const float* __restrict__ node_b,
    float* __restrict__ out_node, float* __restrict__ proj){
  const int t = threadIdx.x, w = t >> 6, l = t & 63, lr = l & 15, lg = l >> 4;
  const long r0 = (long)blockIdx.x * 64;
  f32x4 acc[4][3] = {};
  for (int kb = 0; kb < 8; kb++){
    s16x8 a[4];
    #pragma unroll
    for (int m = 0; m < 4; m++)
      a[m] = *(const s16x8*)(ah + (r0 + m * 16 + lr) * 256 + kb * 32 + lg * 8);
    s16x8 b[3];
    #pragma unroll
    for (int j = 0; j < 3; j++){
      int nt = w + 4 * j;
      int ntc = (nt <= 9) ? nt : 0;   // clamp (results discarded in epilogue)
      if (ntc == 9)
        b[j] = *(const s16x8*)(eWf + (size_t)(kb * 64 + l) * 8);
      else
        b[j] = *(const s16x8*)(nWf + (size_t)((ntc * 8 + kb) * 64 + l) * 8);
    }
    #pragma unroll
    for (int m = 0; m < 4; m++)
      #pragma unroll
      for (int j = 0; j < 3; j++)
        acc[m][j] = mfma16(a[m], b[j], acc[m][j]);
  }
  #pragma unroll
  for (int j = 0; j < 3; j++){
    int nt = w + 4 * j;
    if (nt > 9) continue;
    if (nt == 9){
      #pragma unroll
      for (int m = 0; m < 4; m++)
        #pragma unroll
        for (int r = 0; r < 4; r++)
          proj[(r0 + m * 16 + lg * 4 + r) * 16 + lr] = acc[m][j][r];
    } else {
      int col = nt * 16 + lr;
      if (col < AF){
        float nb = node_b[col];
        #pragma unroll
        for (int m = 0; m < 4; m++)
          #pragma unroll
          for (int r = 0; r < 4; r++)
            out_node[(r0 + m * 16 + lg * 4 + r) * AF + col] = acc[m][j][r] + nb;
      }
    }
  }
}

__global__ void k_edge_out(const int* __restrict__ edge_index, const float* __restrict__ proj,
                           const float* __restrict__ edge_b, float* __restrict__ out_edge){
  int gid = blockIdx.x * 256 + threadIdx.x;
  int i = gid >> 4, c = gid & 15;
  if (c < BFdim){
    int s = edge_index[2 * i];
    int d = edge_index[NEDGES + 2 * i];
    out_edge[(size_t)i * BFdim + c] =
        0.5f * (proj[(size_t)s * 16 + c] + proj[(size_t)d * 16 + c]) + edge_b[c];
  }
}

// ---------------- molecule pooling ----------------
__global__ __launch_bounds__(256) void k_pool(const ushort* __restrict__ ah,
                                              const int* __restrict__ molst,
                                              float* __restrict__ gemb){
  const int t = threadIdx.x, w = t >> 6, l = t & 63;
  const int m = blockIdx.x * 4 + w;
  const int beg = molst[m], end = molst[m + 1];
  float a0 = 0, a1 = 0, a2 = 0, a3 = 0;
  for (int i = beg; i < end; i++){
    const ushort4 v = *(const ushort4*)(ah + (size_t)i * 256 + l * 4);
    a0 += bf2f(v.x); a1 += bf2f(v.y); a2 += bf2f(v.z); a3 += bf2f(v.w);
  }
  f32x4 o = {a0, a1, a2, a3};
  *(f32x4*)(gemb + (size_t)m * 256 + l * 4) = o;
}

// ---------------- graph head (fp32) ----------------
__global__ __launch_bounds__(256) void k_g1(const float* __restrict__ gemb,
                                            const float* __restrict__ gW1,
                                            const float* __restrict__ gb1,
                                            float* __restrict__ ghid){
  __shared__ float s[16 * 256];
  const int t = threadIdx.x;
  const int r0 = blockIdx.x * 16;
  for (int i = 0; i < 16; i++){
    int r = r0 + i;
    s[i * 256 + t] = (r < NMOLS) ? gemb[(size_t)r * 256 + t] : 0.f;
  }
  __syncthreads();
  float acc[16] = {};
  for (int k = 0; k < 256; k++){
    float wv = gW1[(size_t)k * 256 + t];
    #pragma unroll
    for (int i = 0; i < 16; i++) acc[i] += s[i * 256 + k] * wv;
  }
  float b = gb1[t];
  for (int i = 0; i < 16; i++){
    int r = r0 + i;
    if (r < NMOLS){ float v = acc[i] + b; ghid[(size_t)r * 256 + t] = v > 0.f ? v : 0.f; }
  }
}
__global__ void k_g2(const float* __restrict__ ghid, const float* __restrict__ gW2,
                     const float* __restrict__ gb2, float* __restrict__ outg){
  const int t = threadIdx.x, w = t >> 6, l = t & 63;
  const int m = blockIdx.x * 4 + w;
  f32x4 v = *(const f32x4*)(ghid + (size_t)m * 256 + l * 4);
  const f32x4 wv = *(const f32x4*)(gW2 + l * 4);
  float acc = v[0] * wv[0] + v[1] * wv[1] + v[2] * wv[2] + v[3] * wv[3];
  for (int ofs = 32; ofs; ofs >>= 1) acc += __shfl_down(acc, ofs, 64);
  if (l == 0) outg[m] = acc + gb2[0];
}

extern "C" void kernel_launch(void* const* d_in, const int* in_sizes, int n_in,
                              void* d_out, int out_size, void* d_ws, size_t ws_size,
                              hipStream_t stream){
  const float* f_atoms = (const float*)d_in[0];
  const float* f_bonds = (const float*)d_in[1];
  const float* W_i     = (const float*)d_in[2];
  const float* W_h     = (const float*)d_in[3];
  const float* W_o     = (const float*)d_in[4];
  const float* b_o     = (const float*)d_in[5];
  const float* node_W  = (const float*)d_in[6];
  const float* node_b  = (const float*)d_in[7];
  const float* edge_W  = (const float*)d_in[8];
  const float* edge_b  = (const float*)d_in[9];
  const float* g_W1    = (const float*)d_in[10];
  const float* g_b1    = (const float*)d_in[11];
  const float* g_W2    = (const float*)d_in[12];
  const float* g_b2    = (const float*)d_in[13];
  const int* edge_index = (const int*)d_in[14];
  const int* atom_mol   = (const int*)d_in[16];

  float* out_node  = (float*)d_out;
  float* out_edge  = out_node + (size_t)NATOMS * AF;
  float* out_graph = out_edge + (size_t)(NEDGES / 2) * BFdim;

  char* p = (char*)d_ws;
  auto alloc = [&](size_t b) -> char* { char* r = p; p += (b + 255) & ~(size_t)255; return r; };
  ushort* B1 = (ushort*)alloc((size_t)NEDGES * 256 * 2);  // inp -> fa16
  ushort* B2 = (ushort*)alloc((size_t)NEDGES * 256 * 2);  // fb16 -> M1 -> M2
  ushort* B3 = (ushort*)alloc((size_t)NEDGES * 256 * 2);  // Y0 -> Y1
  ushort* N1 = (ushort*)alloc((size_t)NATOMS * 256 * 2);  // ah
  ushort* N2 = (ushort*)alloc((size_t)NATOMS * 256 * 2);  // amsg
  float*  proj  = (float*)alloc((size_t)NATOMS * 16 * 4);
  float*  gemb  = (float*)alloc((size_t)NMOLS * 256 * 4);
  float*  ghid  = (float*)alloc((size_t)NMOLS * 256 * 4);
  ushort* Wif   = (ushort*)alloc(160 * 256 * 2);
  ushort* Wof1  = (ushort*)alloc(160 * 256 * 2);
  ushort* Whf   = (ushort*)alloc(256 * 256 * 2);
  ushort* Wof2  = (ushort*)alloc(256 * 256 * 2);
  ushort* nWf   = (ushort*)alloc(256 * 144 * 2);
  ushort* eWf   = (ushort*)alloc(256 * 16 * 2);
  int* deg    = (int*)alloc(NATOMS * 4);
  int* offs   = (int*)alloc((NATOMS + 1) * 4);
  int* cursor = (int*)alloc(NATOMS * 4);
  int* elist  = (int*)alloc(NEDGES * 4);
  int* pos    = (int*)alloc(NEDGES * 4);
  int* revp   = (int*)alloc(NEDGES * 4);
  int* bsum   = (int*)alloc(1568 * 4);
  int* boff   = (int*)alloc(1568 * 4);
  int* molst  = (int*)alloc((NMOLS + 1) * 4);
  if ((size_t)(p - (char*)d_ws) > ws_size) return;

  const int* srci = edge_index;  // CSR over SRC

  hipMemsetAsync(deg, 0, NATOMS * 4, stream);
  k_prep_weights<<<992, 256, 0, stream>>>(W_i, W_h, W_o, node_W, edge_W,
                                          Wif, Wof1, Whf, Wof2, nWf, eWf);
  // src-CSR + rev map
  k_hist<<<3125, 256, 0, stream>>>(srci, deg);
  k_blocksum<<<NBLK, 256, 0, stream>>>(deg, bsum);
  k_scanblk<<<1, 1024, 0, stream>>>(bsum, boff);
  k_offs<<<NBLK, 256, 0, stream>>>(deg, boff, offs, cursor);
  k_fill<<<3125, 256, 0, stream>>>(srci, cursor, elist);
  k_pos<<<3125, 256, 0, stream>>>(elist, pos);
  k_maps<<<3125, 256, 0, stream>>>(elist, pos, revp);
  k_molstart<<<51, 256, 0, stream>>>(atom_mol, molst);

  // fb16 in src-sorted order -> B2
  k_cvtp<<<150000, 256, 0, stream>>>(f_bonds, elist, B2);
  // inp = fb16 @ W_i -> B1 ; Y0 = relu(inp) @ W_h -> B3 (one kernel)
  k_fused_inpY<<<12500, 256, 0, stream>>>(B2, Wif, Whf, B1, B3);
  // M1 = relu(inp + S0 - Y0[revp]) -> B2  (S0 in-register only)
  k_fsum2<<<50000, 256, 0, stream>>>(B3, B1, revp, offs, B2);
  // Y1 = M1 @ W_h -> B3 (Y0 dead)
  k_Y<<<12500, 256, 0, stream>>>(B2, Whf, B3);
  // M2 = relu(inp + S1 - Y1[revp]) -> B2 (M1 dead)
  k_fsum2<<<50000, 256, 0, stream>>>(B3, B1, revp, offs, B2);
  // amsg = segsum(M2) via revp gather -> N2
  k_segsum_rev<<<50000, 256, 0, stream>>>(B2, revp, offs, N2);
  // fa16 -> B1 (inp dead)
  k_cvt<<<75000, 256, 0, stream>>>(f_atoms, B1, NATOMS * 48, AF);
  // ah = relu(fa16 @ Wof1 + amsg @ Wof2 + b_o) -> N1
  k_ah<<<6250, 256, 0, stream>>>(B1, Wof1, N2, Wof2, b_o, N1);
  // heads
  k_pool<<<3250, 256, 0, stream>>>(N1, molst, gemb);
  k_nodeproj<<<6250, 256, 0, stream>>>(N1, nWf, eWf, node_b, out_node, proj);
  k_edge_out<<<25000, 256, 0, stream>>>(edge_index, proj, edge_b, out_edge);
  k_g1<<<813, 256, 0, stream>>>(gemb, g_W1, g_b1, ghid);
  k_g2<<<3250, 256, 0, stream>>>(ghid, g_W2, g_b2, out_graph);
}

// Round 9
// 2188.190 us; speedup vs baseline: 1.2996x; 1.0546x over previous
//
#include <hip/hip_runtime.h>

#define NATOMS 400000
#define NEDGES 800000
#define NMOLS  13000
#define AF 133
#define BFdim 14
#define BFD 147

typedef __attribute__((ext_vector_type(8))) short  s16x8;
typedef __attribute__((ext_vector_type(8))) __bf16 b16x8;
typedef __attribute__((ext_vector_type(4))) float  f32x4;

__device__ __forceinline__ float bf2f(unsigned short u){
  union { unsigned int i; float f; } v; v.i = ((unsigned int)u) << 16; return v.f;
}
__device__ __forceinline__ unsigned short f2bf(float f){
  union { float ff; unsigned int i; } v; v.ff = f;
  unsigned int b = v.i + 0x7fffu + ((v.i >> 16) & 1u);
  return (unsigned short)(b >> 16);
}
__device__ __forceinline__ unsigned int pk2(float a, float b){
  unsigned int r;
  asm("v_cvt_pk_bf16_f32 %0, %1, %2" : "=v"(r) : "v"(a), "v"(b));
  return r;
}
__device__ __forceinline__ f32x4 mfma16(s16x8 a, s16x8 b, f32x4 c){
  return __builtin_amdgcn_mfma_f32_16x16x32_bf16(
      __builtin_bit_cast(b16x8, a), __builtin_bit_cast(b16x8, b), c, 0, 0, 0);
}
__device__ __forceinline__ void gload_lds16(const void* g, void* lds){
  __builtin_amdgcn_global_load_lds(
      (const __attribute__((address_space(1))) void*)g,
      (__attribute__((address_space(3))) void*)lds, 16, 0, 0);
}

// ---------------- fp32 [rows][Kin] -> bf16 [rows][192] ----------------
__global__ void k_cvt(const float* __restrict__ src, ushort* __restrict__ dst,
                      int total, int Kin){
  int gid = blockIdx.x * 256 + threadIdx.x;
  if (gid >= total) return;
  int row = gid / 48;
  int c0 = (gid - row * 48) * 4;
  const float* sp = src + (size_t)row * Kin + c0;
  ushort4 o;
  o.x = (c0     < Kin) ? f2bf(sp[0]) : 0;
  o.y = (c0 + 1 < Kin) ? f2bf(sp[1]) : 0;
  o.z = (c0 + 2 < Kin) ? f2bf(sp[2]) : 0;
  o.w = (c0 + 3 < Kin) ? f2bf(sp[3]) : 0;
  *(ushort4*)(dst + (size_t)row * 192 + c0) = o;
}

// permuted bond cvt: dst row i = f_bonds[p[i]]
__global__ void k_cvtp(const float* __restrict__ src, const int* __restrict__ p,
                       ushort* __restrict__ dst){
  int gid = blockIdx.x * 256 + threadIdx.x;
  if (gid >= NEDGES * 48) return;
  int row = gid / 48;
  int c0 = (gid - row * 48) * 4;
  const float* sp = src + (size_t)p[row] * BFD + c0;
  ushort4 o;
  o.x = (c0     < BFD) ? f2bf(sp[0]) : 0;
  o.y = (c0 + 1 < BFD) ? f2bf(sp[1]) : 0;
  o.z = (c0 + 2 < BFD) ? f2bf(sp[2]) : 0;
  o.w = (c0 + 3 < BFD) ? f2bf(sp[3]) : 0;
  *(ushort4*)(dst + (size_t)row * 192 + c0) = o;
}

// ---------------- weight prep: fp32 -> bf16 fragment order ----------------
__global__ void k_prep_weights(const float* __restrict__ W_i, const float* __restrict__ W_h,
                               const float* __restrict__ W_o, const float* __restrict__ node_W,
                               const float* __restrict__ edge_W,
                               ushort* __restrict__ Wif, ushort* __restrict__ Wof1,
                               ushort* __restrict__ Whf, ushort* __restrict__ Wof2,
                               ushort* __restrict__ nWf, ushort* __restrict__ eWf){
  int gid = blockIdx.x * 256 + threadIdx.x;
  ushort* dst; const float* src; int KB, Kv, Ns, idx;
  if      (gid <  40960){ idx = gid;          dst = Wif;  src = W_i;          KB = 5; Kv = 147; Ns = 256; }
  else if (gid <  81920){ idx = gid -  40960; dst = Wof1; src = W_o;          KB = 5; Kv = 133; Ns = 256; }
  else if (gid < 147456){ idx = gid -  81920; dst = Whf;  src = W_h;          KB = 8; Kv = 256; Ns = 256; }
  else if (gid < 212992){ idx = gid - 147456; dst = Wof2; src = W_o + 133*256;KB = 8; Kv = 256; Ns = 256; }
  else if (gid < 249856){ idx = gid - 212992; dst = nWf;  src = node_W;       KB = 8; Kv = 256; Ns = 133; }
  else if (gid < 253952){ idx = gid - 249856; dst = eWf;  src = edge_W;       KB = 8; Kv = 256; Ns = 14;  }
  else return;
  int j = idx & 7, lane = (idx >> 3) & 63, fi = idx >> 9;
  int kb = fi % KB, nb = fi / KB;
  int k = kb * 32 + ((lane >> 4) << 3) + j;
  int n = nb * 16 + (lane & 15);
  float v = 0.f;
  if (k < Kv && n < Ns) v = src[(size_t)k * Ns + n];
  dst[idx] = f2bf(v);
}

// ---------------- CSR build over src ----------------
__global__ void k_hist(const int* __restrict__ key, int* __restrict__ deg){
  int e = blockIdx.x * 256 + threadIdx.x;
  if (e < NEDGES) atomicAdd(&deg[key[e]], 1);
}
__global__ void k_blocksum(const int* __restrict__ deg, int* __restrict__ bsum){
  __shared__ int s[256];
  int i = blockIdx.x * 256 + threadIdx.x;
  s[threadIdx.x] = (i < NATOMS) ? deg[i] : 0;
  __syncthreads();
  for (int st = 128; st > 0; st >>= 1){
    if (threadIdx.x < st) s[threadIdx.x] += s[threadIdx.x + st];
    __syncthreads();
  }
  if (threadIdx.x == 0) bsum[blockIdx.x] = s[0];
}
#define NBLK 1563
__global__ void k_scanblk(const int* __restrict__ bs, int* __restrict__ bo){
  __shared__ int s[2048];
  int t = threadIdx.x;
  s[2*t]   = (2*t   < NBLK) ? bs[2*t]   : 0;
  s[2*t+1] = (2*t+1 < NBLK) ? bs[2*t+1] : 0;
  int offset = 1;
  for (int d = 1024; d > 0; d >>= 1){
    __syncthreads();
    if (t < d){ int ai = offset*(2*t+1)-1, bi = offset*(2*t+2)-1; s[bi] += s[ai]; }
    offset <<= 1;
  }
  __syncthreads();
  if (t == 0) s[2047] = 0;
  for (int d = 1; d < 2048; d <<= 1){
    offset >>= 1;
    __syncthreads();
    if (t < d){ int ai = offset*(2*t+1)-1, bi = offset*(2*t+2)-1;
                int tmp = s[ai]; s[ai] = s[bi]; s[bi] += tmp; }
  }
  __syncthreads();
  if (2*t   < NBLK) bo[2*t]   = s[2*t];
  if (2*t+1 < NBLK) bo[2*t+1] = s[2*t+1];
}
__global__ void k_offs(const int* __restrict__ deg, const int* __restrict__ bo,
                       int* __restrict__ offs, int* __restrict__ cursor){
  __shared__ int s1[256], s2[256];
  int t = threadIdx.x;
  int i = blockIdx.x * 256 + t;
  int v = (i < NATOMS) ? deg[i] : 0;
  s1[t] = v;
  __syncthreads();
  int* rd = s1; int* wr = s2;
  for (int ofs = 1; ofs < 256; ofs <<= 1){
    wr[t] = rd[t] + ((t >= ofs) ? rd[t - ofs] : 0);
    __syncthreads();
    int* tmp = rd; rd = wr; wr = tmp;
  }
  if (i < NATOMS){
    int excl = rd[t] - v + bo[blockIdx.x];
    offs[i] = excl; cursor[i] = excl;
  }
  if (i == 0) offs[NATOMS] = NEDGES;
}
__global__ void k_fill(const int* __restrict__ key, int* __restrict__ cursor,
                       int* __restrict__ elist){
  int e = blockIdx.x * 256 + threadIdx.x;
  if (e < NEDGES){ int pos = atomicAdd(&cursor[key[e]], 1); elist[pos] = e; }
}
__global__ void k_pos(const int* __restrict__ elist, int* __restrict__ pos){
  int i = blockIdx.x * 256 + threadIdx.x;
  if (i < NEDGES) pos[elist[i]] = i;
}
__global__ void k_maps(const int* __restrict__ elist, const int* __restrict__ pos,
                       int* __restrict__ revp){
  int i = blockIdx.x * 256 + threadIdx.x;
  if (i < NEDGES) revp[i] = pos[elist[i] ^ 1];
}
__global__ void k_molstart(const int* __restrict__ atom_mol, int* __restrict__ molst){
  int m = blockIdx.x * 256 + threadIdx.x;
  if (m > NMOLS) return;
  int lo = 0, hi = NATOMS;
  while (lo < hi){ int mid = (lo + hi) >> 1; if (atom_mol[mid] < m) lo = mid + 1; else hi = mid; }
  molst[m] = lo;
}

// ---------------- fused: inp = fb16 @ W_i ; Y0 = relu(inp) @ W_h ----------------
__global__ __launch_bounds__(256) void k_fused_inpY(
    const ushort* __restrict__ A16, const ushort* __restrict__ Wif,
    const ushort* __restrict__ Whf, ushort* __restrict__ inp,
    ushort* __restrict__ Yout){
  __shared__ ushort At[64 * 256];
  const int t = threadIdx.x, w = t >> 6, l = t & 63;
  const long r0 = (long)blockIdx.x * 64;
  const char* Ab = (const char*)(A16 + r0 * 192);
  #pragma unroll
  for (int i = 0; i < 6; i++){
    int dbase = (i * 4 + w) * 1024;
    int d = dbase + l * 16;
    int row = d / 384;
    gload_lds16(Ab + (d ^ ((row & 7) << 4)), (char*)At + dbase);
  }
  __syncthreads();
  const int lr = l & 15, lg = l >> 4;
  f32x4 acc[4][4] = {};
  for (int kb = 0; kb < 5; kb++){
    s16x8 a[4], b[4];
    #pragma unroll
    for (int m = 0; m < 4; m++){
      int row = m * 16 + lr;
      int cb = (kb * 64 + (lg << 4)) ^ ((row & 7) << 4);
      a[m] = *(const s16x8*)((const char*)At + row * 384 + cb);
    }
    #pragma unroll
    for (int n = 0; n < 4; n++)
      b[n] = *(const s16x8*)(Wif + (size_t)(((w * 4 + n) * 5 + kb) * 64 + l) * 8);
    #pragma unroll
    for (int m = 0; m < 4; m++)
      #pragma unroll
      for (int n = 0; n < 4; n++)
        acc[m][n] = mfma16(a[m], b[n], acc[m][n]);
  }
  __syncthreads();
  #pragma unroll
  for (int m = 0; m < 4; m++){
    #pragma unroll
    for (int n = 0; n < 4; n++){
      int col = w * 64 + n * 16 + lr;
      long base = (r0 + m * 16 + lg * 4) * 256 + col;
      #pragma unroll
      for (int r = 0; r < 4; r++){
        float v = acc[m][n][r];
        inp[base + (long)r * 256] = f2bf(v);
        int row = m * 16 + lg * 4 + r;
        int byte = row * 512 + ((2 * col) ^ ((row & 7) << 4));
        *(ushort*)((char*)At + byte) = f2bf(v > 0.f ? v : 0.f);
      }
    }
  }
  __syncthreads();
  f32x4 acc2[4][4] = {};
  for (int kb = 0; kb < 8; kb++){
    s16x8 a[4], b[4];
    #pragma unroll
    for (int m = 0; m < 4; m++){
      int row = m * 16 + lr;
      int cb = (kb * 64 + (lg << 4)) ^ ((row & 7) << 4);
      a[m] = *(const s16x8*)((const char*)At + row * 512 + cb);
    }
    #pragma unroll
    for (int n = 0; n < 4; n++)
      b[n] = *(const s16x8*)(Whf + (size_t)(((w * 4 + n) * 8 + kb) * 64 + l) * 8);
    #pragma unroll
    for (int m = 0; m < 4; m++)
      #pragma unroll
      for (int n = 0; n < 4; n++)
        acc2[m][n] = mfma16(a[m], b[n], acc2[m][n]);
  }
  #pragma unroll
  for (int m = 0; m < 4; m++){
    #pragma unroll
    for (int n = 0; n < 4; n++){
      long base = (r0 + m * 16 + lg * 4) * 256 + (w * 64 + n * 16 + lr);
      #pragma unroll
      for (int r = 0; r < 4; r++)
        Yout[base + (long)r * 256] = f2bf(acc2[m][n][r]);
    }
  }
}

// ---------------- dense E-row GEMM: Y = A @ Whf (gload_lds staging) ----------------
__global__ __launch_bounds__(256) void k_Y(
    const ushort* __restrict__ A, const ushort* __restrict__ Whf,
    ushort* __restrict__ Yout){
  __shared__ ushort At[64 * 256];
  const int t = threadIdx.x, w = t >> 6, l = t & 63;
  const long e0 = (long)blockIdx.x * 64;
  const char* Ab = (const char*)(A + e0 * 256);
  #pragma unroll
  for (int i = 0; i < 8; i++){
    int dbase = (i * 4 + w) * 1024;
    int d = dbase + l * 16;
    int sw = ((d >> 9) & 7) << 4;
    gload_lds16(Ab + (d ^ sw), (char*)At + dbase);
  }
  __syncthreads();
  const int lr = l & 15, lg = l >> 4;
  f32x4 acc[4][4] = {};
  for (int kb = 0; kb < 8; kb++){
    s16x8 a[4], b[4];
    #pragma unroll
    for (int m = 0; m < 4; m++){
      int row = m * 16 + lr;
      int cb = (kb * 64 + (lg << 4)) ^ ((row & 7) << 4);
      a[m] = *(const s16x8*)((const char*)At + row * 512 + cb);
    }
    #pragma unroll
    for (int n = 0; n < 4; n++){
      int fi = (w * 4 + n) * 8 + kb;
      b[n] = *(const s16x8*)(Whf + (size_t)(fi * 64 + l) * 8);
    }
    #pragma unroll
    for (int m = 0; m < 4; m++)
      #pragma unroll
      for (int n = 0; n < 4; n++)
        acc[m][n] = mfma16(a[m], b[n], acc[m][n]);
  }
  #pragma unroll
  for (int m = 0; m < 4; m++){
    #pragma unroll
    for (int n = 0; n < 4; n++){
      long base = (e0 + m * 16 + lg * 4) * 256 + (w * 64 + n * 16 + lr);
      #pragma unroll
      for (int r = 0; r < 4; r++)
        Yout[base + (long)r * 256] = f2bf(acc[m][n][r]);
    }
  }
}

// ---------------- fused S+combine, single-pass register fast path ----------------
// per atom a (32-lane group, 8 atoms/block), src-run [beg,end):
//   S = sum_i Y[revp[i]] ; out row k = relu(inp[beg+k] + S - Y[revp[beg+k]])
//   write target: SCATTER ? revp[beg+k] (dst-order) : beg+k (src-order)
template<bool SCATTER>
__global__ __launch_bounds__(256) void k_fsum3(
    const ushort* __restrict__ Y, const ushort* __restrict__ inp,
    const int* __restrict__ revp, const int* __restrict__ offs,
    ushort* __restrict__ M){
  const int t = threadIdx.x, g = t >> 5, h = t & 31;
  const int a = blockIdx.x * 8 + g;
  const int beg = offs[a], end = offs[a + 1];
  const int deg = end - beg;
  if (deg == 0) return;
  if (deg <= 4){
    // single memory phase: all Y rows + inp rows in flight together
    int rv[4];
    #pragma unroll
    for (int k = 0; k < 4; k++) if (k < deg) rv[k] = revp[beg + k];
    s16x8 y[4], vi[4];
    #pragma unroll
    for (int k = 0; k < 4; k++) if (k < deg){
      y[k]  = *(const s16x8*)(Y   + (size_t)rv[k] * 256 + h * 8);
      vi[k] = *(const s16x8*)(inp + (size_t)(beg + k) * 256 + h * 8);
    }
    float acc[8] = {};
    #pragma unroll
    for (int k = 0; k < 4; k++) if (k < deg){
      #pragma unroll
      for (int j = 0; j < 8; j++) acc[j] += bf2f((ushort)y[k][j]);
    }
    #pragma unroll
    for (int k = 0; k < 4; k++) if (k < deg){
      float vv[8];
      #pragma unroll
      for (int j = 0; j < 8; j++){
        float v = bf2f((ushort)vi[k][j]) + acc[j] - bf2f((ushort)y[k][j]);
        vv[j] = v > 0.f ? v : 0.f;
      }
      uint4 o;
      o.x = pk2(vv[0], vv[1]); o.y = pk2(vv[2], vv[3]);
      o.z = pk2(vv[4], vv[5]); o.w = pk2(vv[6], vv[7]);
      long wrow = SCATTER ? (long)rv[k] : (long)(beg + k);
      *(uint4*)(M + wrow * 256 + h * 8) = o;
    }
  } else {
    // general two-pass path (rare)
    float acc[8] = {};
    for (int base = beg; base < end; base += 4){
      int n = end - base; if (n > 4) n = 4;
      int rv[4];
      #pragma unroll
      for (int k = 0; k < 4; k++) if (k < n) rv[k] = revp[base + k];
      s16x8 y[4];
      #pragma unroll
      for (int k = 0; k < 4; k++) if (k < n)
        y[k] = *(const s16x8*)(Y + (size_t)rv[k] * 256 + h * 8);
      #pragma unroll
      for (int k = 0; k < 4; k++) if (k < n){
        #pragma unroll
        for (int j = 0; j < 8; j++) acc[j] += bf2f((ushort)y[k][j]);
      }
    }
    for (int base = beg; base < end; base += 4){
      int n = end - base; if (n > 4) n = 4;
      int rv[4];
      #pragma unroll
      for (int k = 0; k < 4; k++) if (k < n) rv[k] = revp[base + k];
      s16x8 y[4], vi[4];
      #pragma unroll
      for (int k = 0; k < 4; k++) if (k < n){
        y[k]  = *(const s16x8*)(Y   + (size_t)rv[k] * 256 + h * 8);
        vi[k] = *(const s16x8*)(inp + (size_t)(base + k) * 256 + h * 8);
      }
      #pragma unroll
      for (int k = 0; k < 4; k++) if (k < n){
        float vv[8];
        #pragma unroll
        for (int j = 0; j < 8; j++){
          float v = bf2f((ushort)vi[k][j]) + acc[j] - bf2f((ushort)y[k][j]);
          vv[j] = v > 0.f ? v : 0.f;
        }
        uint4 o;
        o.x = pk2(vv[0], vv[1]); o.y = pk2(vv[2], vv[3]);
        o.z = pk2(vv[4], vv[5]); o.w = pk2(vv[6], vv[7]);
        long wrow = SCATTER ? (long)rv[k] : (long)(base + k);
        *(uint4*)(M + wrow * 256 + h * 8) = o;
      }
    }
  }
}

// ---------------- final aggregation: amsg[a] = sum of contiguous M_d rows ----------------
__global__ __launch_bounds__(256) void k_amsg_seq(
    const ushort* __restrict__ Md, const int* __restrict__ offs,
    ushort* __restrict__ amsg){
  const int t = threadIdx.x, g = t >> 5, h = t & 31;
  const int a = blockIdx.x * 8 + g;
  const int beg = offs[a], end = offs[a + 1];
  float acc[8] = {};
  for (int i = beg; i < end; i++){
    s16x8 v = *(const s16x8*)(Md + (size_t)i * 256 + h * 8);
    #pragma unroll
    for (int j = 0; j < 8; j++) acc[j] += bf2f((ushort)v[j]);
  }
  uint4 ov;
  ov.x = pk2(acc[0], acc[1]); ov.y = pk2(acc[2], acc[3]);
  ov.z = pk2(acc[4], acc[5]); ov.w = pk2(acc[6], acc[7]);
  *(uint4*)(amsg + (size_t)a * 256 + h * 8) = ov;
}

// ---------------- fused output transform: ah = relu(fa16 @ Wof1 + amsg @ Wof2 + b_o) ----------------
__global__ __launch_bounds__(256) void k_ah(
    const ushort* __restrict__ fa16, const ushort* __restrict__ Wof1,
    const ushort* __restrict__ amsg, const ushort* __restrict__ Wof2,
    const float* __restrict__ b_o, ushort* __restrict__ ah){
  __shared__ ushort At[64 * 192];
  const int t = threadIdx.x, w = t >> 6, l = t & 63;
  const long r0 = (long)blockIdx.x * 64;
  const char* Ab = (const char*)(fa16 + r0 * 192);
  #pragma unroll
  for (int i = 0; i < 6; i++){
    int dbase = (i * 4 + w) * 1024;
    int d = dbase + l * 16;
    int row = d / 384;
    gload_lds16(Ab + (d ^ ((row & 7) << 4)), (char*)At + dbase);
  }
  __syncthreads();
  const int lr = l & 15, lg = l >> 4;
  f32x4 acc[4][4] = {};
  for (int kb = 0; kb < 5; kb++){
    s16x8 a[4], b[4];
    #pragma unroll
    for (int m = 0; m < 4; m++){
      int row = m * 16 + lr;
      int cb = (kb * 64 + (lg << 4)) ^ ((row & 7) << 4);
      a[m] = *(const s16x8*)((const char*)At + row * 384 + cb);
    }
    #pragma unroll
    for (int n = 0; n < 4; n++)
      b[n] = *(const s16x8*)(Wof1 + (size_t)(((w * 4 + n) * 5 + kb) * 64 + l) * 8);
    #pragma unroll
    for (int m = 0; m < 4; m++)
      #pragma unroll
      for (int n = 0; n < 4; n++)
        acc[m][n] = mfma16(a[m], b[n], acc[m][n]);
  }
  for (int kb = 0; kb < 8; kb++){
    s16x8 a[4], b[4];
    #pragma unroll
    for (int m = 0; m < 4; m++)
      a[m] = *(const s16x8*)(amsg + (r0 + m * 16 + lr) * 256 + kb * 32 + lg * 8);
    #pragma unroll
    for (int n = 0; n < 4; n++)
      b[n] = *(const s16x8*)(Wof2 + (size_t)(((w * 4 + n) * 8 + kb) * 64 + l) * 8);
    #pragma unroll
    for (int m = 0; m < 4; m++)
      #pragma unroll
      for (int n = 0; n < 4; n++)
        acc[m][n] = mfma16(a[m], b[n], acc[m][n]);
  }
  #pragma unroll
  for (int m = 0; m < 4; m++){
    #pragma unroll
    for (int n = 0; n < 4; n++){
      int col = w * 64 + n * 16 + lr;
      float bo = b_o[col];
      long base = (r0 + m * 16 + lg * 4) * 256 + col;
      #pragma unroll
      for (int r = 0; r < 4; r++){
        float v = acc[m][n][r] + bo;
        ah[base + (long)r * 256] = f2bf(v > 0.f ? v : 0.f);
      }
    }
  }
}

// ---------------- fused node + edge-proj heads ----------------
__global__ __launch_bounds__(256) void k_nodeproj(
    const ushort* __restrict__ ah, const ushort* __restrict__ nWf,
    const ushort* __restrict__ eWf, const float* __restrict__ node_b,
    float* __restrict__ out_node, float* __restrict__ proj){
  const int t = threadIdx.x, w = t >> 6, l = t & 63, lr = l & 15, lg = l >> 4;
  const long r0 = (long)blockIdx.x * 64;
  f32x4 acc[4][3] = {};
  for (int kb = 0; kb < 8; kb++){
    s16x8 a[4];
    #pragma unroll
    for (int m = 0; m < 4; m++)
      a[m] = *(const s16x8*)(ah + (r0 + m * 16 + lr) * 256 + kb * 32 + lg * 8);
    s16x8 b[3];
    #pragma unroll
    for (int j = 0; j < 3; j++){
      int nt = w + 4 * j;
      int ntc = (nt <= 9) ? nt : 0;
      if (ntc == 9)
        b[j] = *(const s16x8*)(eWf + (size_t)(kb * 64 + l) * 8);
      else
        b[j] = *(const s16x8*)(nWf + (size_t)((ntc * 8 + kb) * 64 + l) * 8);
    }
    #pragma unroll
    for (int m = 0; m < 4; m++)
      #pragma unroll
      for (int j = 0; j < 3; j++)
        acc[m][j] = mfma16(a[m], b[j], acc[m][j]);
  }
  #pragma unroll
  for (int j = 0; j < 3; j++){
    int nt = w + 4 * j;
    if (nt > 9) continue;
    if (nt == 9){
      #pragma unroll
      for (int m = 0; m < 4; m++)
        #pragma unroll
        for (int r = 0; r < 4; r++)
          proj[(r0 + m * 16 + lg * 4 + r) * 16 + lr] = acc[m][j][r];
    } else {
      int col = nt * 16 + lr;
      if (col < AF){
        float nb = node_b[col];
        #pragma unroll
        for (int m = 0; m < 4; m++)
          #pragma unroll
          for (int r = 0; r < 4; r++)
            out_node[(r0 + m * 16 + lg * 4 + r) * AF + col] = acc[m][j][r] + nb;
      }
    }
  }
}

__global__ void k_edge_out(const int* __restrict__ edge_index, const float* __restrict__ proj,
                           const float* __restrict__ edge_b, float* __restrict__ out_edge){
  int gid = blockIdx.x * 256 + threadIdx.x;
  int i = gid >> 4, c = gid & 15;
  if (c < BFdim){
    int s = edge_index[2 * i];
    int d = edge_index[NEDGES + 2 * i];
    out_edge[(size_t)i * BFdim + c] =
        0.5f * (proj[(size_t)s * 16 + c] + proj[(size_t)d * 16 + c]) + edge_b[c];
  }
}

// ---------------- molecule pooling ----------------
__global__ __launch_bounds__(256) void k_pool(const ushort* __restrict__ ah,
                                              const int* __restrict__ molst,
                                              float* __restrict__ gemb){
  const int t = threadIdx.x, w = t >> 6, l = t & 63;
  const int m = blockIdx.x * 4 + w;
  const int beg = molst[m], end = molst[m + 1];
  float a0 = 0, a1 = 0, a2 = 0, a3 = 0;
  for (int i = beg; i < end; i++){
    const ushort4 v = *(const ushort4*)(ah + (size_t)i * 256 + l * 4);
    a0 += bf2f(v.x); a1 += bf2f(v.y); a2 += bf2f(v.z); a3 += bf2f(v.w);
  }
  f32x4 o = {a0, a1, a2, a3};
  *(f32x4*)(gemb + (size_t)m * 256 + l * 4) = o;
}

// ---------------- graph head (fp32) ----------------
__global__ __launch_bounds__(256) void k_g1(const float* __restrict__ gemb,
                                            const float* __restrict__ gW1,
                                            const float* __restrict__ gb1,
                                            float* __restrict__ ghid){
  __shared__ float s[16 * 256];
  const int t = threadIdx.x;
  const int r0 = blockIdx.x * 16;
  for (int i = 0; i < 16; i++){
    int r = r0 + i;
    s[i * 256 + t] = (r < NMOLS) ? gemb[(size_t)r * 256 + t] : 0.f;
  }
  __syncthreads();
  float acc[16] = {};
  for (int k = 0; k < 256; k++){
    float wv = gW1[(size_t)k * 256 + t];
    #pragma unroll
    for (int i = 0; i < 16; i++) acc[i] += s[i * 256 + k] * wv;
  }
  float b = gb1[t];
  for (int i = 0; i < 16; i++){
    int r = r0 + i;
    if (r < NMOLS){ float v = acc[i] + b; ghid[(size_t)r * 256 + t] = v > 0.f ? v : 0.f; }
  }
}
__global__ void k_g2(const float* __restrict__ ghid, const float* __restrict__ gW2,
                     const float* __restrict__ gb2, float* __restrict__ outg){
  const int t = threadIdx.x, w = t >> 6, l = t & 63;
  const int m = blockIdx.x * 4 + w;
  f32x4 v = *(const f32x4*)(ghid + (size_t)m * 256 + l * 4);
  const f32x4 wv = *(const f32x4*)(gW2 + l * 4);
  float acc = v[0] * wv[0] + v[1] * wv[1] + v[2] * wv[2] + v[3] * wv[3];
  for (int ofs = 32; ofs; ofs >>= 1) acc += __shfl_down(acc, ofs, 64);
  if (l == 0) outg[m] = acc + gb2[0];
}

extern "C" void kernel_launch(void* const* d_in, const int* in_sizes, int n_in,
                              void* d_out, int out_size, void* d_ws, size_t ws_size,
                              hipStream_t stream){
  const float* f_atoms = (const float*)d_in[0];
  const float* f_bonds = (const float*)d_in[1];
  const float* W_i     = (const float*)d_in[2];
  const float* W_h     = (const float*)d_in[3];
  const float* W_o     = (const float*)d_in[4];
  const float* b_o     = (const float*)d_in[5];
  const float* node_W  = (const float*)d_in[6];
  const float* node_b  = (const float*)d_in[7];
  const float* edge_W  = (const float*)d_in[8];
  const float* edge_b  = (const float*)d_in[9];
  const float* g_W1    = (const float*)d_in[10];
  const float* g_b1    = (const float*)d_in[11];
  const float* g_W2    = (const float*)d_in[12];
  const float* g_b2    = (const float*)d_in[13];
  const int* edge_index = (const int*)d_in[14];
  const int* atom_mol   = (const int*)d_in[16];

  float* out_node  = (float*)d_out;
  float* out_edge  = out_node + (size_t)NATOMS * AF;
  float* out_graph = out_edge + (size_t)(NEDGES / 2) * BFdim;

  char* p = (char*)d_ws;
  auto alloc = [&](size_t b) -> char* { char* r = p; p += (b + 255) & ~(size_t)255; return r; };
  ushort* B1 = (ushort*)alloc((size_t)NEDGES * 256 * 2);  // inp -> fa16
  ushort* B2 = (ushort*)alloc((size_t)NEDGES * 256 * 2);  // fb16 -> M1 -> M_d
  ushort* B3 = (ushort*)alloc((size_t)NEDGES * 256 * 2);  // Y0 -> Y1
  ushort* N1 = (ushort*)alloc((size_t)NATOMS * 256 * 2);  // ah
  ushort* N2 = (ushort*)alloc((size_t)NATOMS * 256 * 2);  // amsg
  float*  proj  = (float*)alloc((size_t)NATOMS * 16 * 4);
  float*  gemb  = (float*)alloc((size_t)NMOLS * 256 * 4);
  float*  ghid  = (float*)alloc((size_t)NMOLS * 256 * 4);
  ushort* Wif   = (ushort*)alloc(160 * 256 * 2);
  ushort* Wof1  = (ushort*)alloc(160 * 256 * 2);
  ushort* Whf   = (ushort*)alloc(256 * 256 * 2);
  ushort* Wof2  = (ushort*)alloc(256 * 256 * 2);
  ushort* nWf   = (ushort*)alloc(256 * 144 * 2);
  ushort* eWf   = (ushort*)alloc(256 * 16 * 2);
  int* deg    = (int*)alloc(NATOMS * 4);
  int* offs   = (int*)alloc((NATOMS + 1) * 4);
  int* cursor = (int*)alloc(NATOMS * 4);
  int* elist  = (int*)alloc(NEDGES * 4);
  int* pos    = (int*)alloc(NEDGES * 4);
  int* revp   = (int*)alloc(NEDGES * 4);
  int* bsum   = (int*)alloc(1568 * 4);
  int* boff   = (int*)alloc(1568 * 4);
  int* molst  = (int*)alloc((NMOLS + 1) * 4);
  if ((size_t)(p - (char*)d_ws) > ws_size) return;

  const int* srci = edge_index;  // CSR over SRC

  hipMemsetAsync(deg, 0, NATOMS * 4, stream);
  k_prep_weights<<<992, 256, 0, stream>>>(W_i, W_h, W_o, node_W, edge_W,
                                          Wif, Wof1, Whf, Wof2, nWf, eWf);
  // src-CSR + rev map
  k_hist<<<3125, 256, 0, stream>>>(srci, deg);
  k_blocksum<<<NBLK, 256, 0, stream>>>(deg, bsum);
  k_scanblk<<<1, 1024, 0, stream>>>(bsum, boff);
  k_offs<<<NBLK, 256, 0, stream>>>(deg, boff, offs, cursor);
  k_fill<<<3125, 256, 0, stream>>>(srci, cursor, elist);
  k_pos<<<3125, 256, 0, stream>>>(elist, pos);
  k_maps<<<3125, 256, 0, stream>>>(elist, pos, revp);
  k_molstart<<<51, 256, 0, stream>>>(atom_mol, molst);

  // fb16 in src-sorted order -> B2
  k_cvtp<<<150000, 256, 0, stream>>>(f_bonds, elist, B2);
  // inp = fb16 @ W_i -> B1 ; Y0 = relu(inp) @ W_h -> B3
  k_fused_inpY<<<12500, 256, 0, stream>>>(B2, Wif, Whf, B1, B3);
  // M1 = relu(inp + S0 - Y0[revp]) -> B2 (src-order, sequential write)
  k_fsum3<false><<<50000, 256, 0, stream>>>(B3, B1, revp, offs, B2);
  // Y1 = M1 @ W_h -> B3 (Y0 dead)
  k_Y<<<12500, 256, 0, stream>>>(B2, Whf, B3);
  // M_d[revp[i]] = relu(inp + S1 - Y1[revp]) -> B2 (dst-order, scatter write)
  k_fsum3<true><<<50000, 256, 0, stream>>>(B3, B1, revp, offs, B2);
  // amsg[a] = sum of contiguous M_d rows -> N2 (streaming)
  k_amsg_seq<<<50000, 256, 0, stream>>>(B2, offs, N2);
  // fa16 -> B1 (inp dead)
  k_cvt<<<75000, 256, 0, stream>>>(f_atoms, B1, NATOMS * 48, AF);
  // ah = relu(fa16 @ Wof1 + amsg @ Wof2 + b_o) -> N1
  k_ah<<<6250, 256, 0, stream>>>(B1, Wof1, N2, Wof2, b_o, N1);
  // heads
  k_pool<<<3250, 256, 0, stream>>>(N1, molst, gemb);
  k_nodeproj<<<6250, 256, 0, stream>>>(N1, nWf, eWf, node_b, out_node, proj);
  k_edge_out<<<25000, 256, 0, stream>>>(edge_index, proj, edge_b, out_edge);
  k_g1<<<813, 256, 0, stream>>>(gemb, g_W1, g_b1, ghid);
  k_g2<<<3250, 256, 0, stream>>>(ghid, g_W2, g_b2, out_graph);
}

// Round 10
// 2070.428 us; speedup vs baseline: 1.3736x; 1.0569x over previous
//
#include <hip/hip_runtime.h>

#define NATOMS 400000
#define NEDGES 800000
#define NMOLS  13000
#define AF 133
#define BFdim 14
#define BFD 147

typedef __attribute__((ext_vector_type(8))) short  s16x8;
typedef __attribute__((ext_vector_type(8))) __bf16 b16x8;
typedef __attribute__((ext_vector_type(4))) float  f32x4;

__device__ __forceinline__ float bf2f(unsigned short u){
  union { unsigned int i; float f; } v; v.i = ((unsigned int)u) << 16; return v.f;
}
__device__ __forceinline__ unsigned short f2bf(float f){
  union { float ff; unsigned int i; } v; v.ff = f;
  unsigned int b = v.i + 0x7fffu + ((v.i >> 16) & 1u);
  return (unsigned short)(b >> 16);
}
__device__ __forceinline__ unsigned int pk2(float a, float b){
  unsigned int r;
  asm("v_cvt_pk_bf16_f32 %0, %1, %2" : "=v"(r) : "v"(a), "v"(b));
  return r;
}
__device__ __forceinline__ f32x4 mfma16(s16x8 a, s16x8 b, f32x4 c){
  return __builtin_amdgcn_mfma_f32_16x16x32_bf16(
      __builtin_bit_cast(b16x8, a), __builtin_bit_cast(b16x8, b), c, 0, 0, 0);
}
__device__ __forceinline__ void gload_lds16(const void* g, void* lds){
  __builtin_amdgcn_global_load_lds(
      (const __attribute__((address_space(1))) void*)g,
      (__attribute__((address_space(3))) void*)lds, 16, 0, 0);
}

// ---------------- fp32 [rows][Kin] -> bf16 [rows][192] ----------------
__global__ void k_cvt(const float* __restrict__ src, ushort* __restrict__ dst,
                      int total, int Kin){
  int gid = blockIdx.x * 256 + threadIdx.x;
  if (gid >= total) return;
  int row = gid / 48;
  int c0 = (gid - row * 48) * 4;
  const float* sp = src + (size_t)row * Kin + c0;
  ushort4 o;
  o.x = (c0     < Kin) ? f2bf(sp[0]) : 0;
  o.y = (c0 + 1 < Kin) ? f2bf(sp[1]) : 0;
  o.z = (c0 + 2 < Kin) ? f2bf(sp[2]) : 0;
  o.w = (c0 + 3 < Kin) ? f2bf(sp[3]) : 0;
  *(ushort4*)(dst + (size_t)row * 192 + c0) = o;
}

// bond cvt with SCATTER write: dst row pos[e] = f_bonds[e] (seq read, random write)
__global__ void k_cvtp(const float* __restrict__ src, const int* __restrict__ pos,
                       ushort* __restrict__ dst){
  int gid = blockIdx.x * 256 + threadIdx.x;
  if (gid >= NEDGES * 48) return;
  int row = gid / 48;
  int c0 = (gid - row * 48) * 4;
  const float* sp = src + (size_t)row * BFD + c0;
  ushort4 o;
  o.x = (c0     < BFD) ? f2bf(sp[0]) : 0;
  o.y = (c0 + 1 < BFD) ? f2bf(sp[1]) : 0;
  o.z = (c0 + 2 < BFD) ? f2bf(sp[2]) : 0;
  o.w = (c0 + 3 < BFD) ? f2bf(sp[3]) : 0;
  *(ushort4*)(dst + (size_t)pos[row] * 192 + c0) = o;
}

// ---------------- weight prep: fp32 -> bf16 fragment order ----------------
__global__ void k_prep_weights(const float* __restrict__ W_i, const float* __restrict__ W_h,
                               const float* __restrict__ W_o, const float* __restrict__ node_W,
                               const float* __restrict__ edge_W,
                               ushort* __restrict__ Wif, ushort* __restrict__ Wof1,
                               ushort* __restrict__ Whf, ushort* __restrict__ Wof2,
                               ushort* __restrict__ nWf, ushort* __restrict__ eWf){
  int gid = blockIdx.x * 256 + threadIdx.x;
  ushort* dst; const float* src; int KB, Kv, Ns, idx;
  if      (gid <  40960){ idx = gid;          dst = Wif;  src = W_i;          KB = 5; Kv = 147; Ns = 256; }
  else if (gid <  81920){ idx = gid -  40960; dst = Wof1; src = W_o;          KB = 5; Kv = 133; Ns = 256; }
  else if (gid < 147456){ idx = gid -  81920; dst = Whf;  src = W_h;          KB = 8; Kv = 256; Ns = 256; }
  else if (gid < 212992){ idx = gid - 147456; dst = Wof2; src = W_o + 133*256;KB = 8; Kv = 256; Ns = 256; }
  else if (gid < 249856){ idx = gid - 212992; dst = nWf;  src = node_W;       KB = 8; Kv = 256; Ns = 133; }
  else if (gid < 253952){ idx = gid - 249856; dst = eWf;  src = edge_W;       KB = 8; Kv = 256; Ns = 14;  }
  else return;
  int j = idx & 7, lane = (idx >> 3) & 63, fi = idx >> 9;
  int kb = fi % KB, nb = fi / KB;
  int k = kb * 32 + ((lane >> 4) << 3) + j;
  int n = nb * 16 + (lane & 15);
  float v = 0.f;
  if (k < Kv && n < Ns) v = src[(size_t)k * Ns + n];
  dst[idx] = f2bf(v);
}

// ---------------- CSR build over src ----------------
__global__ void k_hist(const int* __restrict__ key, int* __restrict__ deg){
  int e = blockIdx.x * 256 + threadIdx.x;
  if (e < NEDGES) atomicAdd(&deg[key[e]], 1);
}
__global__ void k_blocksum(const int* __restrict__ deg, int* __restrict__ bsum){
  __shared__ int s[256];
  int i = blockIdx.x * 256 + threadIdx.x;
  s[threadIdx.x] = (i < NATOMS) ? deg[i] : 0;
  __syncthreads();
  for (int st = 128; st > 0; st >>= 1){
    if (threadIdx.x < st) s[threadIdx.x] += s[threadIdx.x + st];
    __syncthreads();
  }
  if (threadIdx.x == 0) bsum[blockIdx.x] = s[0];
}
#define NBLK 1563
__global__ void k_scanblk(const int* __restrict__ bs, int* __restrict__ bo){
  __shared__ int s[2048];
  int t = threadIdx.x;
  s[2*t]   = (2*t   < NBLK) ? bs[2*t]   : 0;
  s[2*t+1] = (2*t+1 < NBLK) ? bs[2*t+1] : 0;
  int offset = 1;
  for (int d = 1024; d > 0; d >>= 1){
    __syncthreads();
    if (t < d){ int ai = offset*(2*t+1)-1, bi = offset*(2*t+2)-1; s[bi] += s[ai]; }
    offset <<= 1;
  }
  __syncthreads();
  if (t == 0) s[2047] = 0;
  for (int d = 1; d < 2048; d <<= 1){
    offset >>= 1;
    __syncthreads();
    if (t < d){ int ai = offset*(2*t+1)-1, bi = offset*(2*t+2)-1;
                int tmp = s[ai]; s[ai] = s[bi]; s[bi] += tmp; }
  }
  __syncthreads();
  if (2*t   < NBLK) bo[2*t]   = s[2*t];
  if (2*t+1 < NBLK) bo[2*t+1] = s[2*t+1];
}
__global__ void k_offs(const int* __restrict__ deg, const int* __restrict__ bo,
                       int* __restrict__ offs, int* __restrict__ cursor){
  __shared__ int s1[256], s2[256];
  int t = threadIdx.x;
  int i = blockIdx.x * 256 + t;
  int v = (i < NATOMS) ? deg[i] : 0;
  s1[t] = v;
  __syncthreads();
  int* rd = s1; int* wr = s2;
  for (int ofs = 1; ofs < 256; ofs <<= 1){
    wr[t] = rd[t] + ((t >= ofs) ? rd[t - ofs] : 0);
    __syncthreads();
    int* tmp = rd; rd = wr; wr = tmp;
  }
  if (i < NATOMS){
    int excl = rd[t] - v + bo[blockIdx.x];
    offs[i] = excl; cursor[i] = excl;
  }
  if (i == 0) offs[NATOMS] = NEDGES;
}
__global__ void k_fill(const int* __restrict__ key, int* __restrict__ cursor,
                       int* __restrict__ elist){
  int e = blockIdx.x * 256 + threadIdx.x;
  if (e < NEDGES){ int pos = atomicAdd(&cursor[key[e]], 1); elist[pos] = e; }
}
__global__ void k_pos(const int* __restrict__ elist, int* __restrict__ pos){
  int i = blockIdx.x * 256 + threadIdx.x;
  if (i < NEDGES) pos[elist[i]] = i;
}
__global__ void k_maps(const int* __restrict__ elist, const int* __restrict__ pos,
                       int* __restrict__ revp){
  int i = blockIdx.x * 256 + threadIdx.x;
  if (i < NEDGES) revp[i] = pos[elist[i] ^ 1];
}
__global__ void k_molstart(const int* __restrict__ atom_mol, int* __restrict__ molst){
  int m = blockIdx.x * 256 + threadIdx.x;
  if (m > NMOLS) return;
  int lo = 0, hi = NATOMS;
  while (lo < hi){ int mid = (lo + hi) >> 1; if (atom_mol[mid] < m) lo = mid + 1; else hi = mid; }
  molst[m] = lo;
}

// ---------------- fused: inp = fb16 @ W_i ; Y0d[revp[j]] = relu(inp)[j] @ W_h ----------------
__global__ __launch_bounds__(256) void k_fused_inpY(
    const ushort* __restrict__ A16, const ushort* __restrict__ Wif,
    const ushort* __restrict__ Whf, const int* __restrict__ revp,
    ushort* __restrict__ inp, ushort* __restrict__ Yout){
  __shared__ ushort At[64 * 256];
  const int t = threadIdx.x, w = t >> 6, l = t & 63;
  const long r0 = (long)blockIdx.x * 64;
  const char* Ab = (const char*)(A16 + r0 * 192);
  #pragma unroll
  for (int i = 0; i < 6; i++){
    int dbase = (i * 4 + w) * 1024;
    int d = dbase + l * 16;
    int row = d / 384;
    gload_lds16(Ab + (d ^ ((row & 7) << 4)), (char*)At + dbase);
  }
  __syncthreads();
  const int lr = l & 15, lg = l >> 4;
  f32x4 acc[4][4] = {};
  for (int kb = 0; kb < 5; kb++){
    s16x8 a[4], b[4];
    #pragma unroll
    for (int m = 0; m < 4; m++){
      int row = m * 16 + lr;
      int cb = (kb * 64 + (lg << 4)) ^ ((row & 7) << 4);
      a[m] = *(const s16x8*)((const char*)At + row * 384 + cb);
    }
    #pragma unroll
    for (int n = 0; n < 4; n++)
      b[n] = *(const s16x8*)(Wif + (size_t)(((w * 4 + n) * 5 + kb) * 64 + l) * 8);
    #pragma unroll
    for (int m = 0; m < 4; m++)
      #pragma unroll
      for (int n = 0; n < 4; n++)
        acc[m][n] = mfma16(a[m], b[n], acc[m][n]);
  }
  __syncthreads();
  #pragma unroll
  for (int m = 0; m < 4; m++){
    #pragma unroll
    for (int n = 0; n < 4; n++){
      int col = w * 64 + n * 16 + lr;
      long base = (r0 + m * 16 + lg * 4) * 256 + col;
      #pragma unroll
      for (int r = 0; r < 4; r++){
        float v = acc[m][n][r];
        inp[base + (long)r * 256] = f2bf(v);
        int row = m * 16 + lg * 4 + r;
        int byte = row * 512 + ((2 * col) ^ ((row & 7) << 4));
        *(ushort*)((char*)At + byte) = f2bf(v > 0.f ? v : 0.f);
      }
    }
  }
  __syncthreads();
  f32x4 acc2[4][4] = {};
  for (int kb = 0; kb < 8; kb++){
    s16x8 a[4], b[4];
    #pragma unroll
    for (int m = 0; m < 4; m++){
      int row = m * 16 + lr;
      int cb = (kb * 64 + (lg << 4)) ^ ((row & 7) << 4);
      a[m] = *(const s16x8*)((const char*)At + row * 512 + cb);
    }
    #pragma unroll
    for (int n = 0; n < 4; n++)
      b[n] = *(const s16x8*)(Whf + (size_t)(((w * 4 + n) * 8 + kb) * 64 + l) * 8);
    #pragma unroll
    for (int m = 0; m < 4; m++)
      #pragma unroll
      for (int n = 0; n < 4; n++)
        acc2[m][n] = mfma16(a[m], b[n], acc2[m][n]);
  }
  #pragma unroll
  for (int m = 0; m < 4; m++){
    long dr[4];
    #pragma unroll
    for (int r = 0; r < 4; r++)
      dr[r] = (long)revp[r0 + m * 16 + lg * 4 + r] * 256;
    #pragma unroll
    for (int n = 0; n < 4; n++){
      int col = w * 64 + n * 16 + lr;
      #pragma unroll
      for (int r = 0; r < 4; r++)
        Yout[dr[r] + col] = f2bf(acc2[m][n][r]);
    }
  }
}

// ---------------- dense E-row GEMM with scatter: Yd[revp[j]] = (A @ Whf)[j] ----------------
__global__ __launch_bounds__(256) void k_Y(
    const ushort* __restrict__ A, const ushort* __restrict__ Whf,
    const int* __restrict__ revp, ushort* __restrict__ Yout){
  __shared__ ushort At[64 * 256];
  const int t = threadIdx.x, w = t >> 6, l = t & 63;
  const long e0 = (long)blockIdx.x * 64;
  const char* Ab = (const char*)(A + e0 * 256);
  #pragma unroll
  for (int i = 0; i < 8; i++){
    int dbase = (i * 4 + w) * 1024;
    int d = dbase + l * 16;
    int sw = ((d >> 9) & 7) << 4;
    gload_lds16(Ab + (d ^ sw), (char*)At + dbase);
  }
  __syncthreads();
  const int lr = l & 15, lg = l >> 4;
  f32x4 acc[4][4] = {};
  for (int kb = 0; kb < 8; kb++){
    s16x8 a[4], b[4];
    #pragma unroll
    for (int m = 0; m < 4; m++){
      int row = m * 16 + lr;
      int cb = (kb * 64 + (lg << 4)) ^ ((row & 7) << 4);
      a[m] = *(const s16x8*)((const char*)At + row * 512 + cb);
    }
    #pragma unroll
    for (int n = 0; n < 4; n++){
      int fi = (w * 4 + n) * 8 + kb;
      b[n] = *(const s16x8*)(Whf + (size_t)(fi * 64 + l) * 8);
    }
    #pragma unroll
    for (int m = 0; m < 4; m++)
      #pragma unroll
      for (int n = 0; n < 4; n++)
        acc[m][n] = mfma16(a[m], b[n], acc[m][n]);
  }
  #pragma unroll
  for (int m = 0; m < 4; m++){
    long dr[4];
    #pragma unroll
    for (int r = 0; r < 4; r++)
      dr[r] = (long)revp[e0 + m * 16 + lg * 4 + r] * 256;
    #pragma unroll
    for (int n = 0; n < 4; n++){
      int col = w * 64 + n * 16 + lr;
      #pragma unroll
      for (int r = 0; r < 4; r++)
        Yout[dr[r] + col] = f2bf(acc[m][n][r]);
    }
  }
}

// ---------------- fully-streaming combine ----------------
// Yd[i] = Y[revp[i]] (already scattered by producer). per atom a, run [beg,end):
//   S = sum_i Yd[i] ; M row = relu(inp[i] + S - Yd[i])
//   write: SCATTER ? revp[i] (dst-order, for streaming amsg) : i (src-order)
template<bool SCATTER>
__global__ __launch_bounds__(256) void k_comb(
    const ushort* __restrict__ Yd, const ushort* __restrict__ inp,
    const int* __restrict__ revp, const int* __restrict__ offs,
    ushort* __restrict__ M){
  const int t = threadIdx.x, g = t >> 5, h = t & 31;
  const int a = blockIdx.x * 8 + g;
  const int beg = offs[a], end = offs[a + 1];
  const int deg = end - beg;
  if (deg == 0) return;
  if (deg <= 4){
    s16x8 y[4], vi[4];
    #pragma unroll
    for (int k = 0; k < 4; k++) if (k < deg){
      y[k]  = *(const s16x8*)(Yd  + (size_t)(beg + k) * 256 + h * 8);
      vi[k] = *(const s16x8*)(inp + (size_t)(beg + k) * 256 + h * 8);
    }
    float acc[8] = {};
    #pragma unroll
    for (int k = 0; k < 4; k++) if (k < deg){
      #pragma unroll
      for (int j = 0; j < 8; j++) acc[j] += bf2f((ushort)y[k][j]);
    }
    #pragma unroll
    for (int k = 0; k < 4; k++) if (k < deg){
      float vv[8];
      #pragma unroll
      for (int j = 0; j < 8; j++){
        float v = bf2f((ushort)vi[k][j]) + acc[j] - bf2f((ushort)y[k][j]);
        vv[j] = v > 0.f ? v : 0.f;
      }
      uint4 o;
      o.x = pk2(vv[0], vv[1]); o.y = pk2(vv[2], vv[3]);
      o.z = pk2(vv[4], vv[5]); o.w = pk2(vv[6], vv[7]);
      long wrow = SCATTER ? (long)revp[beg + k] : (long)(beg + k);
      *(uint4*)(M + wrow * 256 + h * 8) = o;
    }
  } else {
    float acc[8] = {};
    for (int i = beg; i < end; i++){
      s16x8 y = *(const s16x8*)(Yd + (size_t)i * 256 + h * 8);
      #pragma unroll
      for (int j = 0; j < 8; j++) acc[j] += bf2f((ushort)y[j]);
    }
    for (int i = beg; i < end; i++){
      s16x8 y  = *(const s16x8*)(Yd  + (size_t)i * 256 + h * 8);
      s16x8 vi = *(const s16x8*)(inp + (size_t)i * 256 + h * 8);
      float vv[8];
      #pragma unroll
      for (int j = 0; j < 8; j++){
        float v = bf2f((ushort)vi[j]) + acc[j] - bf2f((ushort)y[j]);
        vv[j] = v > 0.f ? v : 0.f;
      }
      uint4 o;
      o.x = pk2(vv[0], vv[1]); o.y = pk2(vv[2], vv[3]);
      o.z = pk2(vv[4], vv[5]); o.w = pk2(vv[6], vv[7]);
      long wrow = SCATTER ? (long)revp[i] : (long)i;
      *(uint4*)(M + wrow * 256 + h * 8) = o;
    }
  }
}

// ---------------- final aggregation: amsg[a] = sum of contiguous M_d rows ----------------
__global__ __launch_bounds__(256) void k_amsg_seq(
    const ushort* __restrict__ Md, const int* __restrict__ offs,
    ushort* __restrict__ amsg){
  const int t = threadIdx.x, g = t >> 5, h = t & 31;
  const int a = blockIdx.x * 8 + g;
  const int beg = offs[a], end = offs[a + 1];
  float acc[8] = {};
  for (int i = beg; i < end; i++){
    s16x8 v = *(const s16x8*)(Md + (size_t)i * 256 + h * 8);
    #pragma unroll
    for (int j = 0; j < 8; j++) acc[j] += bf2f((ushort)v[j]);
  }
  uint4 ov;
  ov.x = pk2(acc[0], acc[1]); ov.y = pk2(acc[2], acc[3]);
  ov.z = pk2(acc[4], acc[5]); ov.w = pk2(acc[6], acc[7]);
  *(uint4*)(amsg + (size_t)a * 256 + h * 8) = ov;
}

// ---------------- fused output transform: ah = relu(fa16 @ Wof1 + amsg @ Wof2 + b_o) ----------------
__global__ __launch_bounds__(256) void k_ah(
    const ushort* __restrict__ fa16, const ushort* __restrict__ Wof1,
    const ushort* __restrict__ amsg, const ushort* __restrict__ Wof2,
    const float* __restrict__ b_o, ushort* __restrict__ ah){
  __shared__ ushort At[64 * 192];
  const int t = threadIdx.x, w = t >> 6, l = t & 63;
  const long r0 = (long)blockIdx.x * 64;
  const char* Ab = (const char*)(fa16 + r0 * 192);
  #pragma unroll
  for (int i = 0; i < 6; i++){
    int dbase = (i * 4 + w) * 1024;
    int d = dbase + l * 16;
    int row = d / 384;
    gload_lds16(Ab + (d ^ ((row & 7) << 4)), (char*)At + dbase);
  }
  __syncthreads();
  const int lr = l & 15, lg = l >> 4;
  f32x4 acc[4][4] = {};
  for (int kb = 0; kb < 5; kb++){
    s16x8 a[4], b[4];
    #pragma unroll
    for (int m = 0; m < 4; m++){
      int row = m * 16 + lr;
      int cb = (kb * 64 + (lg << 4)) ^ ((row & 7) << 4);
      a[m] = *(const s16x8*)((const char*)At + row * 384 + cb);
    }
    #pragma unroll
    for (int n = 0; n < 4; n++)
      b[n] = *(const s16x8*)(Wof1 + (size_t)(((w * 4 + n) * 5 + kb) * 64 + l) * 8);
    #pragma unroll
    for (int m = 0; m < 4; m++)
      #pragma unroll
      for (int n = 0; n < 4; n++)
        acc[m][n] = mfma16(a[m], b[n], acc[m][n]);
  }
  for (int kb = 0; kb < 8; kb++){
    s16x8 a[4], b[4];
    #pragma unroll
    for (int m = 0; m < 4; m++)
      a[m] = *(const s16x8*)(amsg + (r0 + m * 16 + lr) * 256 + kb * 32 + lg * 8);
    #pragma unroll
    for (int n = 0; n < 4; n++)
      b[n] = *(const s16x8*)(Wof2 + (size_t)(((w * 4 + n) * 8 + kb) * 64 + l) * 8);
    #pragma unroll
    for (int m = 0; m < 4; m++)
      #pragma unroll
      for (int n = 0; n < 4; n++)
        acc[m][n] = mfma16(a[m], b[n], acc[m][n]);
  }
  #pragma unroll
  for (int m = 0; m < 4; m++){
    #pragma unroll
    for (int n = 0; n < 4; n++){
      int col = w * 64 + n * 16 + lr;
      float bo = b_o[col];
      long base = (r0 + m * 16 + lg * 4) * 256 + col;
      #pragma unroll
      for (int r = 0; r < 4; r++){
        float v = acc[m][n][r] + bo;
        ah[base + (long)r * 256] = f2bf(v > 0.f ? v : 0.f);
      }
    }
  }
}

// ---------------- fused node + edge-proj heads ----------------
__global__ __launch_bounds__(256) void k_nodeproj(
    const ushort* __restrict__ ah, const ushort* __restrict__ nWf,
    const ushort* __restrict__ eWf, const float* __restrict__ node_b,
    float* __restrict__ out_node, float* __restrict__ proj){
  const int t = threadIdx.x, w = t >> 6, l = t & 63, lr = l & 15, lg = l >> 4;
  const long r0 = (long)blockIdx.x * 64;
  f32x4 acc[4][3] = {};
  for (int kb = 0; kb < 8; kb++){
    s16x8 a[4];
    #pragma unroll
    for (int m = 0; m < 4; m++)
      a[m] = *(const s16x8*)(ah + (r0 + m * 16 + lr) * 256 + kb * 32 + lg * 8);
    s16x8 b[3];
    #pragma unroll
    for (int j = 0; j < 3; j++){
      int nt = w + 4 * j;
      int ntc = (nt <= 9) ? nt : 0;
      if (ntc == 9)
        b[j] = *(const s16x8*)(eWf + (size_t)(kb * 64 + l) * 8);
      else
        b[j] = *(const s16x8*)(nWf + (size_t)((ntc * 8 + kb) * 64 + l) * 8);
    }
    #pragma unroll
    for (int m = 0; m < 4; m++)
      #pragma unroll
      for (int j = 0; j < 3; j++)
        acc[m][j] = mfma16(a[m], b[j], acc[m][j]);
  }
  #pragma unroll
  for (int j = 0; j < 3; j++){
    int nt = w + 4 * j;
    if (nt > 9) continue;
    if (nt == 9){
      #pragma unroll
      for (int m = 0; m < 4; m++)
        #pragma unroll
        for (int r = 0; r < 4; r++)
          proj[(r0 + m * 16 + lg * 4 + r) * 16 + lr] = acc[m][j][r];
    } else {
      int col = nt * 16 + lr;
      if (col < AF){
        float nb = node_b[col];
        #pragma unroll
        for (int m = 0; m < 4; m++)
          #pragma unroll
          for (int r = 0; r < 4; r++)
            out_node[(r0 + m * 16 + lg * 4 + r) * AF + col] = acc[m][j][r] + nb;
      }
    }
  }
}

__global__ void k_edge_out(const int* __restrict__ edge_index, const float* __restrict__ proj,
                           const float* __restrict__ edge_b, float* __restrict__ out_edge){
  int gid = blockIdx.x * 256 + threadIdx.x;
  int i = gid >> 4, c = gid & 15;
  if (c < BFdim){
    int s = edge_index[2 * i];
    int d = edge_index[NEDGES + 2 * i];
    out_edge[(size_t)i * BFdim + c] =
        0.5f * (proj[(size_t)s * 16 + c] + proj[(size_t)d * 16 + c]) + edge_b[c];
  }
}

// ---------------- molecule pooling ----------------
__global__ __launch_bounds__(256) void k_pool(const ushort* __restrict__ ah,
                                              const int* __restrict__ molst,
                                              float* __restrict__ gemb){
  const int t = threadIdx.x, w = t >> 6, l = t & 63;
  const int m = blockIdx.x * 4 + w;
  const int beg = molst[m], end = molst[m + 1];
  float a0 = 0, a1 = 0, a2 = 0, a3 = 0;
  for (int i = beg; i < end; i++){
    const ushort4 v = *(const ushort4*)(ah + (size_t)i * 256 + l * 4);
    a0 += bf2f(v.x); a1 += bf2f(v.y); a2 += bf2f(v.z); a3 += bf2f(v.w);
  }
  f32x4 o = {a0, a1, a2, a3};
  *(f32x4*)(gemb + (size_t)m * 256 + l * 4) = o;
}

// ---------------- graph head (fp32) ----------------
__global__ __launch_bounds__(256) void k_g1(const float* __restrict__ gemb,
                                            const float* __restrict__ gW1,
                                            const float* __restrict__ gb1,
                                            float* __restrict__ ghid){
  __shared__ float s[16 * 256];
  const int t = threadIdx.x;
  const int r0 = blockIdx.x * 16;
  for (int i = 0; i < 16; i++){
    int r = r0 + i;
    s[i * 256 + t] = (r < NMOLS) ? gemb[(size_t)r * 256 + t] : 0.f;
  }
  __syncthreads();
  float acc[16] = {};
  for (int k = 0; k < 256; k++){
    float wv = gW1[(size_t)k * 256 + t];
    #pragma unroll
    for (int i = 0; i < 16; i++) acc[i] += s[i * 256 + k] * wv;
  }
  float b = gb1[t];
  for (int i = 0; i < 16; i++){
    int r = r0 + i;
    if (r < NMOLS){ float v = acc[i] + b; ghid[(size_t)r * 256 + t] = v > 0.f ? v : 0.f; }
  }
}
__global__ void k_g2(const float* __restrict__ ghid, const float* __restrict__ gW2,
                     const float* __restrict__ gb2, float* __restrict__ outg){
  const int t = threadIdx.x, w = t >> 6, l = t & 63;
  const int m = blockIdx.x * 4 + w;
  f32x4 v = *(const f32x4*)(ghid + (size_t)m * 256 + l * 4);
  const f32x4 wv = *(const f32x4*)(gW2 + l * 4);
  float acc = v[0] * wv[0] + v[1] * wv[1] + v[2] * wv[2] + v[3] * wv[3];
  for (int ofs = 32; ofs; ofs >>= 1) acc += __shfl_down(acc, ofs, 64);
  if (l == 0) outg[m] = acc + gb2[0];
}

extern "C" void kernel_launch(void* const* d_in, const int* in_sizes, int n_in,
                              void* d_out, int out_size, void* d_ws, size_t ws_size,
                              hipStream_t stream){
  const float* f_atoms = (const float*)d_in[0];
  const float* f_bonds = (const float*)d_in[1];
  const float* W_i     = (const float*)d_in[2];
  const float* W_h     = (const float*)d_in[3];
  const float* W_o     = (const float*)d_in[4];
  const float* b_o     = (const float*)d_in[5];
  const float* node_W  = (const float*)d_in[6];
  const float* node_b  = (const float*)d_in[7];
  const float* edge_W  = (const float*)d_in[8];
  const float* edge_b  = (const float*)d_in[9];
  const float* g_W1    = (const float*)d_in[10];
  const float* g_b1    = (const float*)d_in[11];
  const float* g_W2    = (const float*)d_in[12];
  const float* g_b2    = (const float*)d_in[13];
  const int* edge_index = (const int*)d_in[14];
  const int* atom_mol   = (const int*)d_in[16];

  float* out_node  = (float*)d_out;
  float* out_edge  = out_node + (size_t)NATOMS * AF;
  float* out_graph = out_edge + (size_t)(NEDGES / 2) * BFdim;

  char* p = (char*)d_ws;
  auto alloc = [&](size_t b) -> char* { char* r = p; p += (b + 255) & ~(size_t)255; return r; };
  ushort* B1 = (ushort*)alloc((size_t)NEDGES * 256 * 2);  // inp -> fa16
  ushort* B2 = (ushort*)alloc((size_t)NEDGES * 256 * 2);  // fb16 -> M1 -> M2d
  ushort* B3 = (ushort*)alloc((size_t)NEDGES * 256 * 2);  // Y0d -> Y1d
  ushort* N1 = (ushort*)alloc((size_t)NATOMS * 256 * 2);  // ah
  ushort* N2 = (ushort*)alloc((size_t)NATOMS * 256 * 2);  // amsg
  float*  proj  = (float*)alloc((size_t)NATOMS * 16 * 4);
  float*  gemb  = (float*)alloc((size_t)NMOLS * 256 * 4);
  float*  ghid  = (float*)alloc((size_t)NMOLS * 256 * 4);
  ushort* Wif   = (ushort*)alloc(160 * 256 * 2);
  ushort* Wof1  = (ushort*)alloc(160 * 256 * 2);
  ushort* Whf   = (ushort*)alloc(256 * 256 * 2);
  ushort* Wof2  = (ushort*)alloc(256 * 256 * 2);
  ushort* nWf   = (ushort*)alloc(256 * 144 * 2);
  ushort* eWf   = (ushort*)alloc(256 * 16 * 2);
  int* deg    = (int*)alloc(NATOMS * 4);
  int* offs   = (int*)alloc((NATOMS + 1) * 4);
  int* cursor = (int*)alloc(NATOMS * 4);
  int* elist  = (int*)alloc(NEDGES * 4);
  int* pos    = (int*)alloc(NEDGES * 4);
  int* revp   = (int*)alloc(NEDGES * 4);
  int* bsum   = (int*)alloc(1568 * 4);
  int* boff   = (int*)alloc(1568 * 4);
  int* molst  = (int*)alloc((NMOLS + 1) * 4);
  if ((size_t)(p - (char*)d_ws) > ws_size) return;

  const int* srci = edge_index;  // CSR over SRC

  hipMemsetAsync(deg, 0, NATOMS * 4, stream);
  k_prep_weights<<<992, 256, 0, stream>>>(W_i, W_h, W_o, node_W, edge_W,
                                          Wif, Wof1, Whf, Wof2, nWf, eWf);
  // src-CSR + rev map
  k_hist<<<3125, 256, 0, stream>>>(srci, deg);
  k_blocksum<<<NBLK, 256, 0, stream>>>(deg, bsum);
  k_scanblk<<<1, 1024, 0, stream>>>(bsum, boff);
  k_offs<<<NBLK, 256, 0, stream>>>(deg, boff, offs, cursor);
  k_fill<<<3125, 256, 0, stream>>>(srci, cursor, elist);
  k_pos<<<3125, 256, 0, stream>>>(elist, pos);
  k_maps<<<3125, 256, 0, stream>>>(elist, pos, revp);
  k_molstart<<<51, 256, 0, stream>>>(atom_mol, molst);

  // fb16 in src-sorted order -> B2 (seq read, scatter write via pos)
  k_cvtp<<<150000, 256, 0, stream>>>(f_bonds, pos, B2);
  // inp -> B1 (seq) ; Y0d -> B3 (scatter via revp)
  k_fused_inpY<<<12500, 256, 0, stream>>>(B2, Wif, Whf, revp, B1, B3);
  // M1 = relu(inp + S0 - Y0d) -> B2 (all streams sequential)
  k_comb<false><<<50000, 256, 0, stream>>>(B3, B1, revp, offs, B2);
  // Y1d -> B3 (scatter via revp; Y0d dead)
  k_Y<<<12500, 256, 0, stream>>>(B2, Whf, revp, B3);
  // M2d = relu(inp + S1 - Y1d) scattered to dst-order -> B2 (M1 dead)
  k_comb<true><<<50000, 256, 0, stream>>>(B3, B1, revp, offs, B2);
  // amsg[a] = sum of contiguous M2d rows -> N2 (streaming)
  k_amsg_seq<<<50000, 256, 0, stream>>>(B2, offs, N2);
  // fa16 -> B1 (inp dead)
  k_cvt<<<75000, 256, 0, stream>>>(f_atoms, B1, NATOMS * 48, AF);
  // ah = relu(fa16 @ Wof1 + amsg @ Wof2 + b_o) -> N1
  k_ah<<<6250, 256, 0, stream>>>(B1, Wof1, N2, Wof2, b_o, N1);
  // heads
  k_pool<<<3250, 256, 0, stream>>>(N1, molst, gemb);
  k_nodeproj<<<6250, 256, 0, stream>>>(N1, nWf, eWf, node_b, out_node, proj);
  k_edge_out<<<25000, 256, 0, stream>>>(edge_index, proj, edge_b, out_edge);
  k_g1<<<813, 256, 0, stream>>>(gemb, g_W1, g_b1, ghid);
  k_g2<<<3250, 256, 0, stream>>>(ghid, g_W2, g_b2, out_graph);
}